// Round 1
// baseline (952.311 us; speedup 1.0000x reference)
//
#include <hip/hip_runtime.h>
#include <math.h>

#define Bsz 2
#define Ssz 1024
#define Dsz 1024
#define Hn 16
#define DHsz 64
#define QKV3 3072
#define SCALE 0.125f

// ---------------------------------------------------------------------------
// K1/K5: C[M,N] = A[M,K] @ Bw[N,K]^T   (fp32, 128x128 tile, BK=16, 8x8/thread)
// ---------------------------------------------------------------------------
__global__ __launch_bounds__(256) void gemm_nt(const float* __restrict__ A,
                                               const float* __restrict__ Bw,
                                               float* __restrict__ C,
                                               int M, int N, int K) {
  __shared__ float As[16][132];  // [k][m], +4 pad
  __shared__ float Bs[16][132];  // [k][n]
  const int tid = threadIdx.x;
  const int tx = tid & 15, ty = tid >> 4;
  const int m0 = blockIdx.y * 128, n0 = blockIdx.x * 128;

  float acc[8][8];
#pragma unroll
  for (int r = 0; r < 8; ++r)
#pragma unroll
    for (int c = 0; c < 8; ++c) acc[r][c] = 0.f;

  const int lrow = tid >> 1;       // 0..127
  const int lkc = (tid & 1) * 8;   // 0 or 8
  const float* Arow = A + (size_t)(m0 + lrow) * K + lkc;
  const float* Brow = Bw + (size_t)(n0 + lrow) * K + lkc;

  for (int kt = 0; kt < K; kt += 16) {
    float4 av0 = *(const float4*)(Arow + kt);
    float4 av1 = *(const float4*)(Arow + kt + 4);
    float4 bv0 = *(const float4*)(Brow + kt);
    float4 bv1 = *(const float4*)(Brow + kt + 4);
    __syncthreads();  // previous tile's compute done before overwrite
    As[lkc + 0][lrow] = av0.x; As[lkc + 1][lrow] = av0.y;
    As[lkc + 2][lrow] = av0.z; As[lkc + 3][lrow] = av0.w;
    As[lkc + 4][lrow] = av1.x; As[lkc + 5][lrow] = av1.y;
    As[lkc + 6][lrow] = av1.z; As[lkc + 7][lrow] = av1.w;
    Bs[lkc + 0][lrow] = bv0.x; Bs[lkc + 1][lrow] = bv0.y;
    Bs[lkc + 2][lrow] = bv0.z; Bs[lkc + 3][lrow] = bv0.w;
    Bs[lkc + 4][lrow] = bv1.x; Bs[lkc + 5][lrow] = bv1.y;
    Bs[lkc + 6][lrow] = bv1.z; Bs[lkc + 7][lrow] = bv1.w;
    __syncthreads();
#pragma unroll
    for (int k = 0; k < 16; ++k) {
      float4 a0 = *(const float4*)&As[k][ty * 8];
      float4 a1 = *(const float4*)&As[k][ty * 8 + 4];
      float4 b0 = *(const float4*)&Bs[k][tx * 8];
      float4 b1 = *(const float4*)&Bs[k][tx * 8 + 4];
      float am[8] = {a0.x, a0.y, a0.z, a0.w, a1.x, a1.y, a1.z, a1.w};
      float bm[8] = {b0.x, b0.y, b0.z, b0.w, b1.x, b1.y, b1.z, b1.w};
#pragma unroll
      for (int r = 0; r < 8; ++r)
#pragma unroll
        for (int c = 0; c < 8; ++c) acc[r][c] += am[r] * bm[c];
    }
  }
#pragma unroll
  for (int r = 0; r < 8; ++r) {
    float* crow = C + (size_t)(m0 + ty * 8 + r) * N + n0 + tx * 8;
    *(float4*)crow = make_float4(acc[r][0], acc[r][1], acc[r][2], acc[r][3]);
    *(float4*)(crow + 4) = make_float4(acc[r][4], acc[r][5], acc[r][6], acc[r][7]);
  }
}

// ---------------------------------------------------------------------------
// K2: scores[h,i,j] = SCALE * q[b,h,i,:] . k[b,h,j,:]   (per batch b)
// 64x64 tile per block, K = DH = 64 in one LDS load
// ---------------------------------------------------------------------------
__global__ __launch_bounds__(256) void qk_scores(const float* __restrict__ qkv,
                                                 float* __restrict__ scores,
                                                 int b) {
  const int tid = threadIdx.x;
  const int h = blockIdx.z;
  const int i0 = blockIdx.y * 64, j0 = blockIdx.x * 64;
  __shared__ float Qs[64][68];
  __shared__ float Ks[64][68];
  const float* qb = qkv + (size_t)b * Ssz * QKV3 + h * DHsz;
#pragma unroll
  for (int r = 0; r < 4; ++r) {
    int idx = tid + r * 256;
    int row = idx >> 4;
    int c4 = (idx & 15) * 4;
    *(float4*)&Qs[row][c4] = *(const float4*)(qb + (size_t)(i0 + row) * QKV3 + c4);
    *(float4*)&Ks[row][c4] = *(const float4*)(qb + 1024 + (size_t)(j0 + row) * QKV3 + c4);
  }
  __syncthreads();
  const int tx = tid & 15, ty = tid >> 4;
  float acc[4][4];
#pragma unroll
  for (int r = 0; r < 4; ++r)
#pragma unroll
    for (int c = 0; c < 4; ++c) acc[r][c] = 0.f;
#pragma unroll
  for (int k4 = 0; k4 < 16; ++k4) {
    float4 q[4], kk[4];
#pragma unroll
    for (int r = 0; r < 4; ++r) q[r] = *(const float4*)&Qs[ty * 4 + r][k4 * 4];
#pragma unroll
    for (int c = 0; c < 4; ++c) kk[c] = *(const float4*)&Ks[tx * 4 + c][k4 * 4];
#pragma unroll
    for (int r = 0; r < 4; ++r)
#pragma unroll
      for (int c = 0; c < 4; ++c)
        acc[r][c] += q[r].x * kk[c].x + q[r].y * kk[c].y + q[r].z * kk[c].z + q[r].w * kk[c].w;
  }
  float* dst = scores + ((size_t)h * Ssz + i0 + ty * 4) * Ssz + j0 + tx * 4;
#pragma unroll
  for (int r = 0; r < 4; ++r) {
    *(float4*)(dst + (size_t)r * Ssz) = make_float4(
        acc[r][0] * SCALE, acc[r][1] * SCALE, acc[r][2] * SCALE, acc[r][3] * SCALE);
  }
}

// ---------------------------------------------------------------------------
// K3: per (i): kerple bias + DAPE MLP + softmax, in-place on scores [H,S,S].
// One block per query row i; all 16 heads' score rows live in 64KB LDS.
// ---------------------------------------------------------------------------
__device__ __forceinline__ float gelu_exact(float x) {
  return 0.5f * x * (1.0f + erff(x * 0.70710678118654752f));
}

__global__ __launch_bounds__(256, 2) void dape_softmax(float* __restrict__ scores,
                                                       const float* __restrict__ bias_p,
                                                       const float* __restrict__ bias_a,
                                                       const float* __restrict__ w1,
                                                       const float* __restrict__ b1,
                                                       const float* __restrict__ w2,
                                                       const float* __restrict__ b2) {
  const int i = blockIdx.x;
  const int tid = threadIdx.x;
  __shared__ float sm[Hn][Ssz];  // 64 KB
  __shared__ float W1[Hn][32];
  __shared__ float W2[Hn][16];
  __shared__ float PP[Hn], PA[Hn], Bb1[Hn], Bb2[Hn];
  float* base = scores + (size_t)i * Ssz;
#pragma unroll
  for (int h = 0; h < Hn; ++h)
    ((float4*)sm[h])[tid] = ((const float4*)(base + (size_t)h * Ssz * Ssz))[tid];
  for (int t = tid; t < 512; t += 256) W1[t >> 5][t & 31] = w1[t];
  W2[tid >> 4][tid & 15] = w2[tid];
  if (tid < Hn) {
    PP[tid] = fmaxf(bias_p[tid], 0.01f);
    PA[tid] = fmaxf(bias_a[tid], 0.01f);
    Bb1[tid] = b1[tid];
    Bb2[tid] = b2[tid];
  }
  __syncthreads();

  // 2 groups of 2 j's per thread (register pressure: 3*2*16 = 96 floats live)
#pragma unroll
  for (int g = 0; g < 2; ++g) {
    float zs[2][16], kb[2][16], hdn[2][16];
#pragma unroll
    for (int jj = 0; jj < 2; ++jj) {
      const int j = (g * 2 + jj) * 256 + tid;
      const float dist = fabsf((float)(i - j));
#pragma unroll
      for (int h = 0; h < 16; ++h) {
        zs[jj][h] = sm[h][j];
        kb[jj][h] = -PP[h] * log1pf(PA[h] * dist);
      }
    }
#pragma unroll
    for (int h2 = 0; h2 < 16; ++h2) {
      float a0 = Bb1[h2], a1 = Bb1[h2];
#pragma unroll
      for (int c4 = 0; c4 < 4; ++c4) {
        const float4 w = *(const float4*)&W1[h2][c4 * 4];
        a0 += zs[0][c4 * 4 + 0] * w.x + zs[0][c4 * 4 + 1] * w.y +
              zs[0][c4 * 4 + 2] * w.z + zs[0][c4 * 4 + 3] * w.w;
        a1 += zs[1][c4 * 4 + 0] * w.x + zs[1][c4 * 4 + 1] * w.y +
              zs[1][c4 * 4 + 2] * w.z + zs[1][c4 * 4 + 3] * w.w;
      }
#pragma unroll
      for (int c4 = 0; c4 < 4; ++c4) {
        const float4 w = *(const float4*)&W1[h2][16 + c4 * 4];
        a0 += kb[0][c4 * 4 + 0] * w.x + kb[0][c4 * 4 + 1] * w.y +
              kb[0][c4 * 4 + 2] * w.z + kb[0][c4 * 4 + 3] * w.w;
        a1 += kb[1][c4 * 4 + 0] * w.x + kb[1][c4 * 4 + 1] * w.y +
              kb[1][c4 * 4 + 2] * w.z + kb[1][c4 * 4 + 3] * w.w;
      }
      hdn[0][h2] = gelu_exact(a0);
      hdn[1][h2] = gelu_exact(a1);
    }
#pragma unroll
    for (int h = 0; h < 16; ++h) {
      float r0 = Bb2[h], r1 = Bb2[h];
#pragma unroll
      for (int c4 = 0; c4 < 4; ++c4) {
        const float4 w = *(const float4*)&W2[h][c4 * 4];
        r0 += hdn[0][c4 * 4 + 0] * w.x + hdn[0][c4 * 4 + 1] * w.y +
              hdn[0][c4 * 4 + 2] * w.z + hdn[0][c4 * 4 + 3] * w.w;
        r1 += hdn[1][c4 * 4 + 0] * w.x + hdn[1][c4 * 4 + 1] * w.y +
              hdn[1][c4 * 4 + 2] * w.z + hdn[1][c4 * 4 + 3] * w.w;
      }
      // disjoint j per thread: safe without barrier
      sm[h][(g * 2 + 0) * 256 + tid] = zs[0][h] + kb[0][h] + r0;
      sm[h][(g * 2 + 1) * 256 + tid] = zs[1][h] + kb[1][h] + r1;
    }
  }
  __syncthreads();

  // softmax: wave w handles heads 4w..4w+3; write attn in-place
  const int lane = tid & 63;
  const int wv = tid >> 6;
#pragma unroll
  for (int hh = 0; hh < 4; ++hh) {
    const int h = wv * 4 + hh;
    float m = -3.0e38f;
#pragma unroll
    for (int t = 0; t < 16; ++t) m = fmaxf(m, sm[h][t * 64 + lane]);
#pragma unroll
    for (int off = 32; off > 0; off >>= 1) m = fmaxf(m, __shfl_xor(m, off, 64));
    float ssum = 0.f;
#pragma unroll
    for (int t = 0; t < 16; ++t) {
      const float e = expf(sm[h][t * 64 + lane] - m);
      sm[h][t * 64 + lane] = e;
      ssum += e;
    }
#pragma unroll
    for (int off = 32; off > 0; off >>= 1) ssum += __shfl_xor(ssum, off, 64);
    const float inv = 1.f / ssum;
    float* dst = base + (size_t)h * Ssz * Ssz;
#pragma unroll
    for (int t = 0; t < 16; ++t) dst[t * 64 + lane] = sm[h][t * 64 + lane] * inv;
  }
}

// ---------------------------------------------------------------------------
// K4: aout[b,i,h*64+d] = sum_j attn[h,i,j] * v[b,j,h,d]   (per batch b)
// ---------------------------------------------------------------------------
__global__ __launch_bounds__(256) void attn_v(const float* __restrict__ attn,
                                              const float* __restrict__ qkv,
                                              float* __restrict__ aout,
                                              int b) {
  const int tid = threadIdx.x;
  const int h = blockIdx.y;
  const int i0 = blockIdx.x * 64;
  __shared__ float At[64][68];
  __shared__ float Vt[64][68];
  const float* arow = attn + ((size_t)h * Ssz + i0) * Ssz;
  const float* vbase = qkv + (size_t)b * Ssz * QKV3 + 2048 + h * DHsz;
  float acc[4][4];
#pragma unroll
  for (int r = 0; r < 4; ++r)
#pragma unroll
    for (int c = 0; c < 4; ++c) acc[r][c] = 0.f;
  const int tx = tid & 15, ty = tid >> 4;
  for (int kt = 0; kt < Ssz; kt += 64) {
    float4 aldv[4], vldv[4];
#pragma unroll
    for (int r = 0; r < 4; ++r) {
      int idx = tid + r * 256;
      int row = idx >> 4, c4 = (idx & 15) * 4;
      aldv[r] = *(const float4*)(arow + (size_t)row * Ssz + kt + c4);
      vldv[r] = *(const float4*)(vbase + (size_t)(kt + row) * QKV3 + c4);
    }
    __syncthreads();
#pragma unroll
    for (int r = 0; r < 4; ++r) {
      int idx = tid + r * 256;
      int row = idx >> 4, c4 = (idx & 15) * 4;
      *(float4*)&At[row][c4] = aldv[r];
      *(float4*)&Vt[row][c4] = vldv[r];
    }
    __syncthreads();
#pragma unroll
    for (int k4 = 0; k4 < 16; ++k4) {
      float4 a4[4], v4[4];
#pragma unroll
      for (int r = 0; r < 4; ++r) a4[r] = *(const float4*)&At[ty * 4 + r][k4 * 4];
#pragma unroll
      for (int t = 0; t < 4; ++t) v4[t] = *(const float4*)&Vt[k4 * 4 + t][tx * 4];
#pragma unroll
      for (int r = 0; r < 4; ++r) {
        const float a_[4] = {a4[r].x, a4[r].y, a4[r].z, a4[r].w};
#pragma unroll
        for (int t = 0; t < 4; ++t) {
          const float v_[4] = {v4[t].x, v4[t].y, v4[t].z, v4[t].w};
#pragma unroll
          for (int c = 0; c < 4; ++c) acc[r][c] += a_[t] * v_[c];
        }
      }
    }
  }
#pragma unroll
  for (int r = 0; r < 4; ++r)
    *(float4*)(aout + (size_t)(b * Ssz + i0 + ty * 4 + r) * 1024 + h * DHsz + tx * 4) =
        make_float4(acc[r][0], acc[r][1], acc[r][2], acc[r][3]);
}

// ---------------------------------------------------------------------------
extern "C" void kernel_launch(void* const* d_in, const int* in_sizes, int n_in,
                              void* d_out, int out_size, void* d_ws, size_t ws_size,
                              hipStream_t stream) {
  const float* x      = (const float*)d_in[0];
  const float* qkv_w  = (const float*)d_in[1];
  const float* out_w  = (const float*)d_in[2];
  const float* bias_p = (const float*)d_in[3];
  const float* bias_a = (const float*)d_in[4];
  const float* w1     = (const float*)d_in[5];
  const float* b1     = (const float*)d_in[6];
  const float* w2     = (const float*)d_in[7];
  const float* b2     = (const float*)d_in[8];
  float* out = (float*)d_out;

  char* ws = (char*)d_ws;
  float* qkv    = (float*)ws;                    // 2048*3072 f = 25165824 B
  float* scores = (float*)(ws + 25165824ull);    // 16*1024*1024 f = 67108864 B (per batch)
  float* aout   = (float*)(ws + 92274688ull);    // 2048*1024 f = 8388608 B
  // total ws use: 100663296 B (96 MiB)

  // K1: qkv = x @ qkv_w^T   [2048,3072]
  gemm_nt<<<dim3(QKV3 / 128, (Bsz * Ssz) / 128), 256, 0, stream>>>(
      x, qkv_w, qkv, Bsz * Ssz, QKV3, Dsz);

  for (int b = 0; b < Bsz; ++b) {
    // K2: scores[h,i,j]
    qk_scores<<<dim3(Ssz / 64, Ssz / 64, Hn), 256, 0, stream>>>(qkv, scores, b);
    // K3: kerple + DAPE MLP + softmax (in place)
    dape_softmax<<<dim3(Ssz), 256, 0, stream>>>(scores, bias_p, bias_a, w1, b1, w2, b2);
    // K4: aout = attn @ v
    attn_v<<<dim3(Ssz / 64, Hn), 256, 0, stream>>>(scores, qkv, aout, b);
  }

  // K5: out = aout @ out_w^T   [2048,1024]
  gemm_nt<<<dim3(Dsz / 128, (Bsz * Ssz) / 128), 256, 0, stream>>>(
      aout, out_w, out, Bsz * Ssz, Dsz, Dsz);
}

// Round 2
// 424.094 us; speedup vs baseline: 2.2455x; 2.2455x over previous
//
#include <hip/hip_runtime.h>
#include <math.h>

#define Bsz 2
#define Ssz 1024
#define Dsz 1024
#define Hn 16
#define DHsz 64
#define QKV3 3072
#define SCALE 0.125f

typedef __bf16 bf16;
typedef bf16 bf16x8 __attribute__((ext_vector_type(8)));
typedef bf16 bf16x4 __attribute__((ext_vector_type(4)));
typedef float f32x4 __attribute__((ext_vector_type(4)));

#define MFMA(a, b, c) __builtin_amdgcn_mfma_f32_16x16x32_bf16(a, b, c, 0, 0, 0)
// LDS row stride for 64-wide K tiles: 72 bf16 = 144 B rows -> 16B-aligned,
// bank rotate 4/row -> 2 lanes/bank on b128 frag reads (free per m136).
#define LDT 72

// ---------------------------------------------------------------------------
// cast fp32 -> bf16 hi + bf16 lo residual (x = hi + lo to ~16 mantissa bits)
// ---------------------------------------------------------------------------
__global__ void cast_hilo(const float* __restrict__ src, bf16* __restrict__ hi,
                          bf16* __restrict__ lo, int n) {
  int idx = (blockIdx.x * 256 + threadIdx.x) * 4;
  if (idx >= n) return;
  float4 v = *(const float4*)(src + idx);
  bf16 h0 = (bf16)v.x, h1 = (bf16)v.y, h2 = (bf16)v.z, h3 = (bf16)v.w;
  bf16x4 hv = {h0, h1, h2, h3};
  bf16x4 lv = {(bf16)(v.x - (float)h0), (bf16)(v.y - (float)h1),
               (bf16)(v.z - (float)h2), (bf16)(v.w - (float)h3)};
  *(bf16x4*)(hi + idx) = hv;
  *(bf16x4*)(lo + idx) = lv;
}

// kbt[h][d] = -clip(p_h)*log1p(clip(a_h)*d), d = |i-j| in [0,1024)
__global__ void kb_table(const float* __restrict__ bias_p, const float* __restrict__ bias_a,
                         float* __restrict__ kbt) {
  int idx = blockIdx.x * 256 + threadIdx.x;  // 16384
  int h = idx >> 10, d = idx & 1023;
  float p = fmaxf(bias_p[h], 0.01f), a = fmaxf(bias_a[h], 0.01f);
  kbt[idx] = -p * log1pf(a * (float)d);
}

// ---------------------------------------------------------------------------
// K1: qkv_bf = bf16( (x_h+x_l) @ (w_h+w_l)^T )  3-term MFMA, M=2048,N=3072,K=1024
// ---------------------------------------------------------------------------
__global__ __launch_bounds__(256, 2) void k1_qkv(const bf16* __restrict__ Ah,
                                                 const bf16* __restrict__ Al,
                                                 const bf16* __restrict__ Bh,
                                                 const bf16* __restrict__ Bl,
                                                 bf16* __restrict__ C) {
  __shared__ __align__(16) bf16 sAh[128 * LDT], sAl[128 * LDT];
  __shared__ __align__(16) bf16 sBh[128 * LDT], sBl[128 * LDT];
  const int tid = threadIdx.x;
  const int lane = tid & 63, wv = tid >> 6;
  const int wr = wv >> 1, wc = wv & 1;
  const int l15 = lane & 15, q8 = (lane >> 4) << 3, q4 = (lane >> 4) << 2;
  const int m0 = blockIdx.y * 128, n0 = blockIdx.x * 128;
  const int r0 = tid >> 3, c8 = (tid & 7) << 3;

  f32x4 acc[4][4];
#pragma unroll
  for (int t = 0; t < 4; ++t)
#pragma unroll
    for (int u = 0; u < 4; ++u)
#pragma unroll
      for (int r = 0; r < 4; ++r) acc[t][u][r] = 0.f;

  bf16x8 rAh[4], rAl[4], rBh[4], rBl[4];
#define K1_LOAD(kt)                                                   \
  {                                                                   \
    _Pragma("unroll") for (int c = 0; c < 4; ++c) {                   \
      int row = c * 32 + r0;                                          \
      rAh[c] = *(const bf16x8*)(Ah + (size_t)(m0 + row) * Dsz + (kt) + c8); \
      rAl[c] = *(const bf16x8*)(Al + (size_t)(m0 + row) * Dsz + (kt) + c8); \
      rBh[c] = *(const bf16x8*)(Bh + (size_t)(n0 + row) * Dsz + (kt) + c8); \
      rBl[c] = *(const bf16x8*)(Bl + (size_t)(n0 + row) * Dsz + (kt) + c8); \
    }                                                                 \
  }

  K1_LOAD(0)
  for (int kt = 0; kt < Dsz; kt += 64) {
    __syncthreads();
#pragma unroll
    for (int c = 0; c < 4; ++c) {
      int row = c * 32 + r0;
      *(bf16x8*)&sAh[row * LDT + c8] = rAh[c];
      *(bf16x8*)&sAl[row * LDT + c8] = rAl[c];
      *(bf16x8*)&sBh[row * LDT + c8] = rBh[c];
      *(bf16x8*)&sBl[row * LDT + c8] = rBl[c];
    }
    __syncthreads();
    if (kt + 64 < Dsz) K1_LOAD(kt + 64)
#pragma unroll
    for (int ks = 0; ks < 64; ks += 32) {
      bf16x8 fah[4], fal[4], fbh[4], fbl[4];
#pragma unroll
      for (int t = 0; t < 4; ++t) {
        int m = wr * 64 + t * 16 + l15;
        fah[t] = *(const bf16x8*)&sAh[m * LDT + ks + q8];
        fal[t] = *(const bf16x8*)&sAl[m * LDT + ks + q8];
      }
#pragma unroll
      for (int u = 0; u < 4; ++u) {
        int n = wc * 64 + u * 16 + l15;
        fbh[u] = *(const bf16x8*)&sBh[n * LDT + ks + q8];
        fbl[u] = *(const bf16x8*)&sBl[n * LDT + ks + q8];
      }
#pragma unroll
      for (int t = 0; t < 4; ++t)
#pragma unroll
        for (int u = 0; u < 4; ++u) {
          acc[t][u] = MFMA(fah[t], fbh[u], acc[t][u]);
          acc[t][u] = MFMA(fah[t], fbl[u], acc[t][u]);
          acc[t][u] = MFMA(fal[t], fbh[u], acc[t][u]);
        }
    }
  }
#pragma unroll
  for (int t = 0; t < 4; ++t)
#pragma unroll
    for (int u = 0; u < 4; ++u) {
      int col = n0 + wc * 64 + u * 16 + l15;
#pragma unroll
      for (int r = 0; r < 4; ++r) {
        int row = m0 + wr * 64 + t * 16 + q4 + r;
        C[(size_t)row * QKV3 + col] = (bf16)acc[t][u][r];
      }
    }
#undef K1_LOAD
}

// ---------------------------------------------------------------------------
// pack V transposed: v_t[b][h][d][j] = qkv_bf[b*1024+j][2048+h*64+d]
// ---------------------------------------------------------------------------
__global__ void pack_vt(const bf16* __restrict__ qkv, bf16* __restrict__ vt) {
  __shared__ __align__(16) bf16 T[64 * LDT];
  const int tid = threadIdx.x;
  const int bh = blockIdx.y, b = bh >> 4, h = bh & 15;
  const int j0 = blockIdx.x * 64;
#pragma unroll
  for (int c = 0; c < 2; ++c) {
    int lin = c * 256 + tid;
    int jr = lin >> 3, d8 = (lin & 7) << 3;
    bf16x8 v = *(const bf16x8*)(qkv + (size_t)(b * Ssz + j0 + jr) * QKV3 + 2048 + h * DHsz + d8);
#pragma unroll
    for (int e = 0; e < 8; ++e) T[(d8 + e) * LDT + jr] = v[e];
  }
  __syncthreads();
#pragma unroll
  for (int c = 0; c < 2; ++c) {
    int lin = c * 256 + tid;
    int d = lin >> 3, j8 = (lin & 7) << 3;
    bf16x8 o = *(const bf16x8*)&T[d * LDT + j8];
    *(bf16x8*)(vt + ((size_t)(b * Hn + h) * DHsz + d) * Ssz + j0 + j8) = o;
  }
}

// ---------------------------------------------------------------------------
// K2: scores_bf[h][i][j] = bf16( SCALE * Q_bf @ K_bf^T )   K=64, single tile
// ---------------------------------------------------------------------------
__global__ __launch_bounds__(256, 3) void k2_qk(const bf16* __restrict__ qkv,
                                                bf16* __restrict__ scores, int b) {
  __shared__ __align__(16) bf16 sA[128 * LDT], sB[128 * LDT];
  const int tid = threadIdx.x;
  const int lane = tid & 63, wv = tid >> 6;
  const int wr = wv >> 1, wc = wv & 1;
  const int l15 = lane & 15, q8 = (lane >> 4) << 3, q4 = (lane >> 4) << 2;
  const int h = blockIdx.z, i0 = blockIdx.y * 128, j0 = blockIdx.x * 128;
  const bf16* Ab = qkv + (size_t)b * Ssz * QKV3 + h * DHsz;
  const bf16* Bb = Ab + Ssz;  // K at column offset 1024
  const int r0 = tid >> 3, c8 = (tid & 7) << 3;
#pragma unroll
  for (int c = 0; c < 4; ++c) {
    int row = c * 32 + r0;
    *(bf16x8*)&sA[row * LDT + c8] = *(const bf16x8*)(Ab + (size_t)(i0 + row) * QKV3 + c8);
    *(bf16x8*)&sB[row * LDT + c8] = *(const bf16x8*)(Bb + (size_t)(j0 + row) * QKV3 + c8);
  }
  __syncthreads();
  f32x4 acc[4][4];
#pragma unroll
  for (int t = 0; t < 4; ++t)
#pragma unroll
    for (int u = 0; u < 4; ++u)
#pragma unroll
      for (int r = 0; r < 4; ++r) acc[t][u][r] = 0.f;
#pragma unroll
  for (int ks = 0; ks < 64; ks += 32) {
    bf16x8 fa[4], fb[4];
#pragma unroll
    for (int t = 0; t < 4; ++t) fa[t] = *(const bf16x8*)&sA[(wr * 64 + t * 16 + l15) * LDT + ks + q8];
#pragma unroll
    for (int u = 0; u < 4; ++u) fb[u] = *(const bf16x8*)&sB[(wc * 64 + u * 16 + l15) * LDT + ks + q8];
#pragma unroll
    for (int t = 0; t < 4; ++t)
#pragma unroll
      for (int u = 0; u < 4; ++u) acc[t][u] = MFMA(fa[t], fb[u], acc[t][u]);
  }
#pragma unroll
  for (int t = 0; t < 4; ++t)
#pragma unroll
    for (int u = 0; u < 4; ++u) {
      int col = j0 + wc * 64 + u * 16 + l15;
#pragma unroll
      for (int r = 0; r < 4; ++r) {
        int row = i0 + wr * 64 + t * 16 + q4 + r;
        scores[((size_t)h * Ssz + row) * Ssz + col] = (bf16)(acc[t][u][r] * SCALE);
      }
    }
}

// ---------------------------------------------------------------------------
// K3: per query row i: DAPE MLP + kerple (table) + softmax, in-place bf16.
// ---------------------------------------------------------------------------
__device__ __forceinline__ float gelu_exact(float x) {
  return 0.5f * x * (1.0f + erff(x * 0.70710678118654752f));
}

__global__ __launch_bounds__(256, 2) void dape_softmax(bf16* __restrict__ scores,
                                                       const float* __restrict__ kbt,
                                                       const float* __restrict__ w1,
                                                       const float* __restrict__ b1,
                                                       const float* __restrict__ w2,
                                                       const float* __restrict__ b2) {
  const int i = blockIdx.x;
  const int tid = threadIdx.x;
  __shared__ float sm[Hn][Ssz];  // 64 KB
  __shared__ float W1[Hn][32];
  __shared__ float W2[Hn][16];
  __shared__ float Bb1[Hn], Bb2[Hn];
  bf16* base = scores + (size_t)i * Ssz;
#pragma unroll
  for (int h = 0; h < Hn; ++h) {
    bf16x4 v = *(const bf16x4*)(base + ((size_t)h << 20) + tid * 4);
#pragma unroll
    for (int e = 0; e < 4; ++e) sm[h][tid * 4 + e] = (float)v[e];
  }
  for (int t = tid; t < 512; t += 256) W1[t >> 5][t & 31] = w1[t];
  W2[tid >> 4][tid & 15] = w2[tid];
  if (tid < Hn) {
    Bb1[tid] = b1[tid];
    Bb2[tid] = b2[tid];
  }
  __syncthreads();

#pragma unroll
  for (int g = 0; g < 2; ++g) {
    float zs[2][16], kb[2][16], hdn[2][16];
#pragma unroll
    for (int jj = 0; jj < 2; ++jj) {
      const int j = (g * 2 + jj) * 256 + tid;
      int di = i - j; if (di < 0) di = -di;
#pragma unroll
      for (int h = 0; h < 16; ++h) {
        zs[jj][h] = sm[h][j];
        kb[jj][h] = kbt[(h << 10) + di];
      }
    }
#pragma unroll
    for (int h2 = 0; h2 < 16; ++h2) {
      float a0 = Bb1[h2], a1 = Bb1[h2];
#pragma unroll
      for (int c4 = 0; c4 < 4; ++c4) {
        const float4 w = *(const float4*)&W1[h2][c4 * 4];
        a0 += zs[0][c4 * 4 + 0] * w.x + zs[0][c4 * 4 + 1] * w.y +
              zs[0][c4 * 4 + 2] * w.z + zs[0][c4 * 4 + 3] * w.w;
        a1 += zs[1][c4 * 4 + 0] * w.x + zs[1][c4 * 4 + 1] * w.y +
              zs[1][c4 * 4 + 2] * w.z + zs[1][c4 * 4 + 3] * w.w;
      }
#pragma unroll
      for (int c4 = 0; c4 < 4; ++c4) {
        const float4 w = *(const float4*)&W1[h2][16 + c4 * 4];
        a0 += kb[0][c4 * 4 + 0] * w.x + kb[0][c4 * 4 + 1] * w.y +
              kb[0][c4 * 4 + 2] * w.z + kb[0][c4 * 4 + 3] * w.w;
        a1 += kb[1][c4 * 4 + 0] * w.x + kb[1][c4 * 4 + 1] * w.y +
              kb[1][c4 * 4 + 2] * w.z + kb[1][c4 * 4 + 3] * w.w;
      }
      hdn[0][h2] = gelu_exact(a0);
      hdn[1][h2] = gelu_exact(a1);
    }
#pragma unroll
    for (int h = 0; h < 16; ++h) {
      float r0 = Bb2[h], r1 = Bb2[h];
#pragma unroll
      for (int c4 = 0; c4 < 4; ++c4) {
        const float4 w = *(const float4*)&W2[h][c4 * 4];
        r0 += hdn[0][c4 * 4 + 0] * w.x + hdn[0][c4 * 4 + 1] * w.y +
              hdn[0][c4 * 4 + 2] * w.z + hdn[0][c4 * 4 + 3] * w.w;
        r1 += hdn[1][c4 * 4 + 0] * w.x + hdn[1][c4 * 4 + 1] * w.y +
              hdn[1][c4 * 4 + 2] * w.z + hdn[1][c4 * 4 + 3] * w.w;
      }
      sm[h][(g * 2 + 0) * 256 + tid] = zs[0][h] + kb[0][h] + r0;
      sm[h][(g * 2 + 1) * 256 + tid] = zs[1][h] + kb[1][h] + r1;
    }
  }
  __syncthreads();

  const int lane = tid & 63;
  const int wv = tid >> 6;
#pragma unroll
  for (int hh = 0; hh < 4; ++hh) {
    const int h = wv * 4 + hh;
    float m = -3.0e38f;
#pragma unroll
    for (int t = 0; t < 16; ++t) m = fmaxf(m, sm[h][t * 64 + lane]);
#pragma unroll
    for (int off = 32; off > 0; off >>= 1) m = fmaxf(m, __shfl_xor(m, off, 64));
    float ssum = 0.f;
#pragma unroll
    for (int t = 0; t < 16; ++t) {
      const float e = expf(sm[h][t * 64 + lane] - m);
      sm[h][t * 64 + lane] = e;
      ssum += e;
    }
#pragma unroll
    for (int off = 32; off > 0; off >>= 1) ssum += __shfl_xor(ssum, off, 64);
    const float inv = 1.f / ssum;
    bf16* dst = base + ((size_t)h << 20);
#pragma unroll
    for (int t = 0; t < 16; ++t) dst[t * 64 + lane] = (bf16)(sm[h][t * 64 + lane] * inv);
  }
}

// ---------------------------------------------------------------------------
// K4: aout_bf[b*1024+i][h*64+d] = attn_bf @ v_t[h]^T-style  M=1024,N=64,K=1024
// block: 64 i x 64 d per (i-tile, h); waves 2x2 of 32x32
// ---------------------------------------------------------------------------
__global__ __launch_bounds__(256, 4) void k4_av(const bf16* __restrict__ attn,
                                                const bf16* __restrict__ vt,
                                                bf16* __restrict__ aout, int b) {
  __shared__ __align__(16) bf16 sA[64 * LDT], sB[64 * LDT];
  const int tid = threadIdx.x;
  const int lane = tid & 63, wv = tid >> 6;
  const int wr = wv >> 1, wc = wv & 1;
  const int l15 = lane & 15, q8 = (lane >> 4) << 3, q4 = (lane >> 4) << 2;
  const int i0 = blockIdx.x * 64, h = blockIdx.y;
  const bf16* Ab = attn + ((size_t)h * Ssz + i0) * Ssz;
  const bf16* Bb = vt + (size_t)(b * Hn + h) * DHsz * Ssz;
  const int r0 = tid >> 3, c8 = (tid & 7) << 3;
  f32x4 acc[2][2];
#pragma unroll
  for (int t = 0; t < 2; ++t)
#pragma unroll
    for (int u = 0; u < 2; ++u)
#pragma unroll
      for (int r = 0; r < 4; ++r) acc[t][u][r] = 0.f;
  bf16x8 rA[2], rB[2];
#define K4_LOAD(kt)                                               \
  {                                                               \
    _Pragma("unroll") for (int c = 0; c < 2; ++c) {               \
      int row = c * 32 + r0;                                      \
      rA[c] = *(const bf16x8*)(Ab + (size_t)row * Ssz + (kt) + c8); \
      rB[c] = *(const bf16x8*)(Bb + (size_t)row * Ssz + (kt) + c8); \
    }                                                             \
  }
  K4_LOAD(0)
  for (int kt = 0; kt < Ssz; kt += 64) {
    __syncthreads();
#pragma unroll
    for (int c = 0; c < 2; ++c) {
      int row = c * 32 + r0;
      *(bf16x8*)&sA[row * LDT + c8] = rA[c];
      *(bf16x8*)&sB[row * LDT + c8] = rB[c];
    }
    __syncthreads();
    if (kt + 64 < Ssz) K4_LOAD(kt + 64)
#pragma unroll
    for (int ks = 0; ks < 64; ks += 32) {
      bf16x8 fa[2], fb[2];
#pragma unroll
      for (int t = 0; t < 2; ++t) fa[t] = *(const bf16x8*)&sA[(wr * 32 + t * 16 + l15) * LDT + ks + q8];
#pragma unroll
      for (int u = 0; u < 2; ++u) fb[u] = *(const bf16x8*)&sB[(wc * 32 + u * 16 + l15) * LDT + ks + q8];
#pragma unroll
      for (int t = 0; t < 2; ++t)
#pragma unroll
        for (int u = 0; u < 2; ++u) acc[t][u] = MFMA(fa[t], fb[u], acc[t][u]);
    }
  }
#pragma unroll
  for (int t = 0; t < 2; ++t)
#pragma unroll
    for (int u = 0; u < 2; ++u) {
      int d = wc * 32 + u * 16 + l15;
#pragma unroll
      for (int r = 0; r < 4; ++r) {
        int row = i0 + wr * 32 + t * 16 + q4 + r;
        aout[(size_t)(b * Ssz + row) * Dsz + h * DHsz + d] = (bf16)acc[t][u][r];
      }
    }
#undef K4_LOAD
}

// ---------------------------------------------------------------------------
// K5: out = aout_bf @ (ow_h+ow_l)^T  2-term, M=2048,N=1024,K=1024, fp32 out
// ---------------------------------------------------------------------------
__global__ __launch_bounds__(256, 2) void k5_out(const bf16* __restrict__ A,
                                                 const bf16* __restrict__ Bh,
                                                 const bf16* __restrict__ Bl,
                                                 float* __restrict__ C) {
  __shared__ __align__(16) bf16 sA[128 * LDT], sBh[128 * LDT], sBl[128 * LDT];
  const int tid = threadIdx.x;
  const int lane = tid & 63, wv = tid >> 6;
  const int wr = wv >> 1, wc = wv & 1;
  const int l15 = lane & 15, q8 = (lane >> 4) << 3, q4 = (lane >> 4) << 2;
  const int m0 = blockIdx.y * 128, n0 = blockIdx.x * 128;
  const int r0 = tid >> 3, c8 = (tid & 7) << 3;
  f32x4 acc[4][4];
#pragma unroll
  for (int t = 0; t < 4; ++t)
#pragma unroll
    for (int u = 0; u < 4; ++u)
#pragma unroll
      for (int r = 0; r < 4; ++r) acc[t][u][r] = 0.f;
  bf16x8 rA[4], rBh[4], rBl[4];
#define K5_LOAD(kt)                                                   \
  {                                                                   \
    _Pragma("unroll") for (int c = 0; c < 4; ++c) {                   \
      int row = c * 32 + r0;                                          \
      rA[c] = *(const bf16x8*)(A + (size_t)(m0 + row) * Dsz + (kt) + c8);   \
      rBh[c] = *(const bf16x8*)(Bh + (size_t)(n0 + row) * Dsz + (kt) + c8); \
      rBl[c] = *(const bf16x8*)(Bl + (size_t)(n0 + row) * Dsz + (kt) + c8); \
    }                                                                 \
  }
  K5_LOAD(0)
  for (int kt = 0; kt < Dsz; kt += 64) {
    __syncthreads();
#pragma unroll
    for (int c = 0; c < 4; ++c) {
      int row = c * 32 + r0;
      *(bf16x8*)&sA[row * LDT + c8] = rA[c];
      *(bf16x8*)&sBh[row * LDT + c8] = rBh[c];
      *(bf16x8*)&sBl[row * LDT + c8] = rBl[c];
    }
    __syncthreads();
    if (kt + 64 < Dsz) K5_LOAD(kt + 64)
#pragma unroll
    for (int ks = 0; ks < 64; ks += 32) {
      bf16x8 fa[4], fbh[4], fbl[4];
#pragma unroll
      for (int t = 0; t < 4; ++t) fa[t] = *(const bf16x8*)&sA[(wr * 64 + t * 16 + l15) * LDT + ks + q8];
#pragma unroll
      for (int u = 0; u < 4; ++u) {
        int n = wc * 64 + u * 16 + l15;
        fbh[u] = *(const bf16x8*)&sBh[n * LDT + ks + q8];
        fbl[u] = *(const bf16x8*)&sBl[n * LDT + ks + q8];
      }
#pragma unroll
      for (int t = 0; t < 4; ++t)
#pragma unroll
        for (int u = 0; u < 4; ++u) {
          acc[t][u] = MFMA(fa[t], fbh[u], acc[t][u]);
          acc[t][u] = MFMA(fa[t], fbl[u], acc[t][u]);
        }
    }
  }
#pragma unroll
  for (int t = 0; t < 4; ++t)
#pragma unroll
    for (int u = 0; u < 4; ++u) {
      int col = n0 + wc * 64 + u * 16 + l15;
#pragma unroll
      for (int r = 0; r < 4; ++r) {
        int row = m0 + wr * 64 + t * 16 + q4 + r;
        C[(size_t)row * Dsz + col] = acc[t][u][r];
      }
    }
#undef K5_LOAD
}

// ---------------------------------------------------------------------------
extern "C" void kernel_launch(void* const* d_in, const int* in_sizes, int n_in,
                              void* d_out, int out_size, void* d_ws, size_t ws_size,
                              hipStream_t stream) {
  const float* x      = (const float*)d_in[0];
  const float* qkv_w  = (const float*)d_in[1];
  const float* out_w  = (const float*)d_in[2];
  const float* bias_p = (const float*)d_in[3];
  const float* bias_a = (const float*)d_in[4];
  const float* w1     = (const float*)d_in[5];
  const float* b1     = (const float*)d_in[6];
  const float* w2     = (const float*)d_in[7];
  const float* b2     = (const float*)d_in[8];
  float* out = (float*)d_out;

  char* ws = (char*)d_ws;
  const size_t MB = 1ull << 20;
  bf16* x_h    = (bf16*)(ws + 0 * MB);   // 4 MB
  bf16* x_l    = (bf16*)(ws + 4 * MB);   // 4 MB
  bf16* w_h    = (bf16*)(ws + 8 * MB);   // 6 MB
  bf16* w_l    = (bf16*)(ws + 14 * MB);  // 6 MB
  bf16* ow_h   = (bf16*)(ws + 20 * MB);  // 2 MB
  bf16* ow_l   = (bf16*)(ws + 22 * MB);  // 2 MB
  bf16* qkv_bf = (bf16*)(ws + 24 * MB);  // 12 MB
  bf16* v_t    = (bf16*)(ws + 36 * MB);  // 4 MB
  bf16* sc_bf  = (bf16*)(ws + 40 * MB);  // 32 MB (per-batch scores/attn, in place)
  bf16* aout   = (bf16*)(ws + 72 * MB);  // 4 MB
  float* kbt   = (float*)(ws + 76 * MB); // 64 KB    total 76.1 MB

  cast_hilo<<<2048, 256, 0, stream>>>(x, x_h, x_l, Bsz * Ssz * Dsz);
  cast_hilo<<<3072, 256, 0, stream>>>(qkv_w, w_h, w_l, QKV3 * Dsz);
  cast_hilo<<<1024, 256, 0, stream>>>(out_w, ow_h, ow_l, Dsz * Dsz);
  kb_table<<<64, 256, 0, stream>>>(bias_p, bias_a, kbt);

  k1_qkv<<<dim3(QKV3 / 128, (Bsz * Ssz) / 128), 256, 0, stream>>>(x_h, x_l, w_h, w_l, qkv_bf);
  pack_vt<<<dim3(Ssz / 64, Bsz * Hn), 256, 0, stream>>>(qkv_bf, v_t);

  for (int b = 0; b < Bsz; ++b) {
    k2_qk<<<dim3(Ssz / 128, Ssz / 128, Hn), 256, 0, stream>>>(qkv_bf, sc_bf, b);
    dape_softmax<<<Ssz, 256, 0, stream>>>(sc_bf, kbt, w1, b1, w2, b2);
    k4_av<<<dim3(Ssz / 64, Hn), 256, 0, stream>>>(sc_bf, v_t, aout, b);
  }

  k5_out<<<dim3(Dsz / 128, (Bsz * Ssz) / 128), 256, 0, stream>>>(aout, ow_h, ow_l, out);
}

// Round 3
// 375.156 us; speedup vs baseline: 2.5384x; 1.1304x over previous
//
#include <hip/hip_runtime.h>
#include <math.h>

#define Bsz 2
#define Ssz 1024
#define Dsz 1024
#define Hn 16
#define DHsz 64
#define QKV3 3072
#define SCALE 0.125f

typedef __bf16 bf16;
typedef bf16 bf16x8 __attribute__((ext_vector_type(8)));
typedef bf16 bf16x4 __attribute__((ext_vector_type(4)));
typedef float f32x4 __attribute__((ext_vector_type(4)));

#define MFMA(a, b, c) __builtin_amdgcn_mfma_f32_16x16x32_bf16(a, b, c, 0, 0, 0)
#define LDT 72

// ---------------------------------------------------------------------------
// cast fp32 -> bf16 hi + bf16 lo residual
// ---------------------------------------------------------------------------
__global__ void cast_hilo(const float* __restrict__ src, bf16* __restrict__ hi,
                          bf16* __restrict__ lo, int n) {
  int idx = (blockIdx.x * 256 + threadIdx.x) * 4;
  if (idx >= n) return;
  float4 v = *(const float4*)(src + idx);
  bf16 h0 = (bf16)v.x, h1 = (bf16)v.y, h2 = (bf16)v.z, h3 = (bf16)v.w;
  bf16x4 hv = {h0, h1, h2, h3};
  bf16x4 lv = {(bf16)(v.x - (float)h0), (bf16)(v.y - (float)h1),
               (bf16)(v.z - (float)h2), (bf16)(v.w - (float)h3)};
  *(bf16x4*)(hi + idx) = hv;
  *(bf16x4*)(lo + idx) = lv;
}

// kbt[h][d] = -clip(p_h)*log1p(clip(a_h)*d)
__global__ void kb_table(const float* __restrict__ bias_p, const float* __restrict__ bias_a,
                         float* __restrict__ kbt) {
  int idx = blockIdx.x * 256 + threadIdx.x;  // 16384
  int h = idx >> 10, d = idx & 1023;
  float p = fmaxf(bias_p[h], 0.01f), a = fmaxf(bias_a[h], 0.01f);
  kbt[idx] = -p * log1pf(a * (float)d);
}

// t1[n][d] = b1[n] + sum_h w1[n][16+h] * kbt[h][d]   (kerple folded thru layer1, fp32)
__global__ void t1_table(const float* __restrict__ kbt, const float* __restrict__ w1,
                         const float* __restrict__ b1, float* __restrict__ t1) {
  int idx = blockIdx.x * 256 + threadIdx.x;  // 16384
  int n = idx >> 10, d = idx & 1023;
  float acc = b1[n];
#pragma unroll
  for (int h = 0; h < 16; ++h) acc += w1[n * 32 + 16 + h] * kbt[(h << 10) + d];
  t1[idx] = acc;
}

// ---------------------------------------------------------------------------
// K1: qkv_bf = bf16( (x_h+x_l) @ (w_h+w_l)^T )  3-term MFMA
// ---------------------------------------------------------------------------
__global__ __launch_bounds__(256, 2) void k1_qkv(const bf16* __restrict__ Ah,
                                                 const bf16* __restrict__ Al,
                                                 const bf16* __restrict__ Bh,
                                                 const bf16* __restrict__ Bl,
                                                 bf16* __restrict__ C) {
  __shared__ __align__(16) bf16 sAh[128 * LDT], sAl[128 * LDT];
  __shared__ __align__(16) bf16 sBh[128 * LDT], sBl[128 * LDT];
  const int tid = threadIdx.x;
  const int lane = tid & 63, wv = tid >> 6;
  const int wr = wv >> 1, wc = wv & 1;
  const int l15 = lane & 15, q8 = (lane >> 4) << 3, q4 = (lane >> 4) << 2;
  const int m0 = blockIdx.y * 128, n0 = blockIdx.x * 128;
  const int r0 = tid >> 3, c8 = (tid & 7) << 3;

  f32x4 acc[4][4];
#pragma unroll
  for (int t = 0; t < 4; ++t)
#pragma unroll
    for (int u = 0; u < 4; ++u)
#pragma unroll
      for (int r = 0; r < 4; ++r) acc[t][u][r] = 0.f;

  bf16x8 rAh[4], rAl[4], rBh[4], rBl[4];
#define K1_LOAD(kt)                                                   \
  {                                                                   \
    _Pragma("unroll") for (int c = 0; c < 4; ++c) {                   \
      int row = c * 32 + r0;                                          \
      rAh[c] = *(const bf16x8*)(Ah + (size_t)(m0 + row) * Dsz + (kt) + c8); \
      rAl[c] = *(const bf16x8*)(Al + (size_t)(m0 + row) * Dsz + (kt) + c8); \
      rBh[c] = *(const bf16x8*)(Bh + (size_t)(n0 + row) * Dsz + (kt) + c8); \
      rBl[c] = *(const bf16x8*)(Bl + (size_t)(n0 + row) * Dsz + (kt) + c8); \
    }                                                                 \
  }

  K1_LOAD(0)
  for (int kt = 0; kt < Dsz; kt += 64) {
    __syncthreads();
#pragma unroll
    for (int c = 0; c < 4; ++c) {
      int row = c * 32 + r0;
      *(bf16x8*)&sAh[row * LDT + c8] = rAh[c];
      *(bf16x8*)&sAl[row * LDT + c8] = rAl[c];
      *(bf16x8*)&sBh[row * LDT + c8] = rBh[c];
      *(bf16x8*)&sBl[row * LDT + c8] = rBl[c];
    }
    __syncthreads();
    if (kt + 64 < Dsz) K1_LOAD(kt + 64)
#pragma unroll
    for (int ks = 0; ks < 64; ks += 32) {
      bf16x8 fah[4], fal[4], fbh[4], fbl[4];
#pragma unroll
      for (int t = 0; t < 4; ++t) {
        int m = wr * 64 + t * 16 + l15;
        fah[t] = *(const bf16x8*)&sAh[m * LDT + ks + q8];
        fal[t] = *(const bf16x8*)&sAl[m * LDT + ks + q8];
      }
#pragma unroll
      for (int u = 0; u < 4; ++u) {
        int n = wc * 64 + u * 16 + l15;
        fbh[u] = *(const bf16x8*)&sBh[n * LDT + ks + q8];
        fbl[u] = *(const bf16x8*)&sBl[n * LDT + ks + q8];
      }
#pragma unroll
      for (int t = 0; t < 4; ++t)
#pragma unroll
        for (int u = 0; u < 4; ++u) {
          acc[t][u] = MFMA(fah[t], fbh[u], acc[t][u]);
          acc[t][u] = MFMA(fah[t], fbl[u], acc[t][u]);
          acc[t][u] = MFMA(fal[t], fbh[u], acc[t][u]);
        }
    }
  }
#pragma unroll
  for (int t = 0; t < 4; ++t)
#pragma unroll
    for (int u = 0; u < 4; ++u) {
      int col = n0 + wc * 64 + u * 16 + l15;
#pragma unroll
      for (int r = 0; r < 4; ++r) {
        int row = m0 + wr * 64 + t * 16 + q4 + r;
        C[(size_t)row * QKV3 + col] = (bf16)acc[t][u][r];
      }
    }
#undef K1_LOAD
}

// ---------------------------------------------------------------------------
// pack V transposed: v_t[b][h][d][j]
// ---------------------------------------------------------------------------
__global__ void pack_vt(const bf16* __restrict__ qkv, bf16* __restrict__ vt) {
  __shared__ __align__(16) bf16 T[64 * LDT];
  const int tid = threadIdx.x;
  const int bh = blockIdx.y, b = bh >> 4, h = bh & 15;
  const int j0 = blockIdx.x * 64;
#pragma unroll
  for (int c = 0; c < 2; ++c) {
    int lin = c * 256 + tid;
    int jr = lin >> 3, d8 = (lin & 7) << 3;
    bf16x8 v = *(const bf16x8*)(qkv + (size_t)(b * Ssz + j0 + jr) * QKV3 + 2048 + h * DHsz + d8);
#pragma unroll
    for (int e = 0; e < 8; ++e) T[(d8 + e) * LDT + jr] = v[e];
  }
  __syncthreads();
#pragma unroll
  for (int c = 0; c < 2; ++c) {
    int lin = c * 256 + tid;
    int d = lin >> 3, j8 = (lin & 7) << 3;
    bf16x8 o = *(const bf16x8*)&T[d * LDT + j8];
    *(bf16x8*)(vt + ((size_t)(b * Hn + h) * DHsz + d) * Ssz + j0 + j8) = o;
  }
}

// ---------------------------------------------------------------------------
// K2: scores_bf[h][i][j] = bf16( SCALE * Q @ K^T )
// ---------------------------------------------------------------------------
__global__ __launch_bounds__(256, 3) void k2_qk(const bf16* __restrict__ qkv,
                                                bf16* __restrict__ scores, int b) {
  __shared__ __align__(16) bf16 sA[128 * LDT], sB[128 * LDT];
  const int tid = threadIdx.x;
  const int lane = tid & 63, wv = tid >> 6;
  const int wr = wv >> 1, wc = wv & 1;
  const int l15 = lane & 15, q8 = (lane >> 4) << 3, q4 = (lane >> 4) << 2;
  const int h = blockIdx.z, i0 = blockIdx.y * 128, j0 = blockIdx.x * 128;
  const bf16* Ab = qkv + (size_t)b * Ssz * QKV3 + h * DHsz;
  const bf16* Bb = Ab + Ssz;
  const int r0 = tid >> 3, c8 = (tid & 7) << 3;
#pragma unroll
  for (int c = 0; c < 4; ++c) {
    int row = c * 32 + r0;
    *(bf16x8*)&sA[row * LDT + c8] = *(const bf16x8*)(Ab + (size_t)(i0 + row) * QKV3 + c8);
    *(bf16x8*)&sB[row * LDT + c8] = *(const bf16x8*)(Bb + (size_t)(j0 + row) * QKV3 + c8);
  }
  __syncthreads();
  f32x4 acc[4][4];
#pragma unroll
  for (int t = 0; t < 4; ++t)
#pragma unroll
    for (int u = 0; u < 4; ++u)
#pragma unroll
      for (int r = 0; r < 4; ++r) acc[t][u][r] = 0.f;
#pragma unroll
  for (int ks = 0; ks < 64; ks += 32) {
    bf16x8 fa[4], fb[4];
#pragma unroll
    for (int t = 0; t < 4; ++t) fa[t] = *(const bf16x8*)&sA[(wr * 64 + t * 16 + l15) * LDT + ks + q8];
#pragma unroll
    for (int u = 0; u < 4; ++u) fb[u] = *(const bf16x8*)&sB[(wc * 64 + u * 16 + l15) * LDT + ks + q8];
#pragma unroll
    for (int t = 0; t < 4; ++t)
#pragma unroll
      for (int u = 0; u < 4; ++u) acc[t][u] = MFMA(fa[t], fb[u], acc[t][u]);
  }
#pragma unroll
  for (int t = 0; t < 4; ++t)
#pragma unroll
    for (int u = 0; u < 4; ++u) {
      int col = j0 + wc * 64 + u * 16 + l15;
#pragma unroll
      for (int r = 0; r < 4; ++r) {
        int row = i0 + wr * 64 + t * 16 + q4 + r;
        scores[((size_t)h * Ssz + row) * Ssz + col] = (bf16)(acc[t][u][r] * SCALE);
      }
    }
}

// ---------------------------------------------------------------------------
// K3: DAPE MLP via MFMA + kerple(fp32, folded in t1) + softmax. In-place bf16.
// Block = one (batch-local) query row i. 4 waves x 256 j each, tiles of 16 j.
// Layer1: A = scores[j,k=h<16 pad32] (global scalar u16), B = w1s hi/lo -> 2 mfma
// Layer2: A = hdn hi/lo via LDS transpose, B = w2 hi/lo -> 3 mfma
// ---------------------------------------------------------------------------
__device__ __forceinline__ float gelu_exact(float x) {
  return 0.5f * x * (1.0f + erff(x * 0.70710678118654752f));
}

__global__ __launch_bounds__(256, 2) void dape_softmax(bf16* scores,
                                                       const float* __restrict__ t1,
                                                       const float* __restrict__ kbt,
                                                       const float* __restrict__ w1,
                                                       const float* __restrict__ w2,
                                                       const float* __restrict__ b2) {
  const int i = blockIdx.x;
  const int tid = threadIdx.x;
  const int lane = tid & 63, wv = tid >> 6;
  const int l15 = lane & 15, q = lane >> 4;
  const int q8 = q << 3, q4 = q << 2;

  __shared__ float lgt[Hn][1028];                    // 65792 B (stride 1028: 16B-align + bank spread)
  __shared__ __align__(16) bf16 hdnS[4][2][16][40];  // 10240 B per-wave transpose scratch

  // ---- weight fragments (B-operand layout: lane=n, k=q8+e), hi/lo split ----
  bf16x8 w1h = {}, w1l = {}, w2h = {}, w2l = {};
  if (q < 2) {
#pragma unroll
    for (int e = 0; e < 8; ++e) {
      float wa = w1[l15 * 32 + q8 + e];  // w1s: first 16 input features (scores)
      bf16 ha = (bf16)wa;
      w1h[e] = ha; w1l[e] = (bf16)(wa - (float)ha);
      float wb = w2[l15 * 16 + q8 + e];
      bf16 hb = (bf16)wb;
      w2h[e] = hb; w2l[e] = (bf16)(wb - (float)hb);
    }
  }
  const float bias2 = b2[l15];

  // zero the k=16..31 pad region of this wave's hdn scratch (lanes 0..31)
  if (lane < 32) {
    *(bf16x8*)&hdnS[wv][q][l15][16] = (bf16x8){};
    *(bf16x8*)&hdnS[wv][q][l15][24] = (bf16x8){};
  }

  const bf16* srow = scores + (size_t)i * Ssz;  // + h*2^20 + j

  for (int jt = 0; jt < 16; ++jt) {
    const int j0 = wv * 256 + jt * 16;
    // ---- layer 1: A-frag from global scores (k = h for quads 0,1; zero pad) ----
    bf16x8 a1 = {};
    if (q < 2) {
#pragma unroll
      for (int e = 0; e < 8; ++e)
        a1[e] = srow[((size_t)(q8 + e) << 20) + (j0 + l15)];
    }
    f32x4 c1 = {0.f, 0.f, 0.f, 0.f};
    c1 = MFMA(a1, w1h, c1);
    c1 = MFMA(a1, w1l, c1);
    // + t1 (bias + kerple path, fp32), gelu, hi/lo pack into LDS transpose buf
#pragma unroll
    for (int r = 0; r < 4; ++r) {
      int j = j0 + q4 + r;
      int d = i - j; if (d < 0) d = -d;
      float g = gelu_exact(c1[r] + t1[(l15 << 10) + d]);
      bf16 gh = (bf16)g;
      hdnS[wv][0][q4 + r][l15] = gh;
      hdnS[wv][1][q4 + r][l15] = (bf16)(g - (float)gh);
    }
    // ---- layer 2 ----
    bf16x8 a2h = *(const bf16x8*)&hdnS[wv][0][l15][q8];
    bf16x8 a2l = *(const bf16x8*)&hdnS[wv][1][l15][q8];
    f32x4 c2 = {bias2, bias2, bias2, bias2};
    c2 = MFMA(a2h, w2h, c2);
    c2 = MFMA(a2h, w2l, c2);
    c2 = MFMA(a2l, w2h, c2);
    // ---- logits = score + kb + refine (fp32) ----
#pragma unroll
    for (int r = 0; r < 4; ++r) {
      int j = j0 + q4 + r;
      int d = i - j; if (d < 0) d = -d;
      float sc = (float)srow[((size_t)l15 << 20) + j];
      lgt[l15][j] = sc + kbt[(l15 << 10) + d] + c2[r];
    }
  }
  __syncthreads();

  // ---- softmax: wave wv handles heads 4wv..4wv+3; write attn in-place ----
#pragma unroll
  for (int hh = 0; hh < 4; ++hh) {
    const int h = wv * 4 + hh;
    f32x4 v[4];
    float m = -3.0e38f;
#pragma unroll
    for (int t = 0; t < 4; ++t) {
      v[t] = *(const f32x4*)&lgt[h][t * 256 + lane * 4];
#pragma unroll
      for (int e = 0; e < 4; ++e) m = fmaxf(m, v[t][e]);
    }
#pragma unroll
    for (int off = 32; off > 0; off >>= 1) m = fmaxf(m, __shfl_xor(m, off, 64));
    float s = 0.f;
#pragma unroll
    for (int t = 0; t < 4; ++t)
#pragma unroll
      for (int e = 0; e < 4; ++e) {
        float ex = __expf(v[t][e] - m);
        v[t][e] = ex;
        s += ex;
      }
#pragma unroll
    for (int off = 32; off > 0; off >>= 1) s += __shfl_xor(s, off, 64);
    const float inv = 1.f / s;
    bf16* dst = scores + ((size_t)h << 20) + (size_t)i * Ssz;
#pragma unroll
    for (int t = 0; t < 4; ++t) {
      bf16x4 pv = {(bf16)(v[t][0] * inv), (bf16)(v[t][1] * inv),
                   (bf16)(v[t][2] * inv), (bf16)(v[t][3] * inv)};
      *(bf16x4*)(dst + t * 256 + lane * 4) = pv;
    }
  }
}

// ---------------------------------------------------------------------------
// K4: aout = attn @ V   (via v_t), per (i-tile, h)
// ---------------------------------------------------------------------------
__global__ __launch_bounds__(256, 4) void k4_av(const bf16* __restrict__ attn,
                                                const bf16* __restrict__ vt,
                                                bf16* __restrict__ aout, int b) {
  __shared__ __align__(16) bf16 sA[64 * LDT], sB[64 * LDT];
  const int tid = threadIdx.x;
  const int lane = tid & 63, wv = tid >> 6;
  const int wr = wv >> 1, wc = wv & 1;
  const int l15 = lane & 15, q8 = (lane >> 4) << 3, q4 = (lane >> 4) << 2;
  const int i0 = blockIdx.x * 64, h = blockIdx.y;
  const bf16* Ab = attn + ((size_t)h * Ssz + i0) * Ssz;
  const bf16* Bb = vt + (size_t)(b * Hn + h) * DHsz * Ssz;
  const int r0 = tid >> 3, c8 = (tid & 7) << 3;
  f32x4 acc[2][2];
#pragma unroll
  for (int t = 0; t < 2; ++t)
#pragma unroll
    for (int u = 0; u < 2; ++u)
#pragma unroll
      for (int r = 0; r < 4; ++r) acc[t][u][r] = 0.f;
  bf16x8 rA[2], rB[2];
#define K4_LOAD(kt)                                               \
  {                                                               \
    _Pragma("unroll") for (int c = 0; c < 2; ++c) {               \
      int row = c * 32 + r0;                                      \
      rA[c] = *(const bf16x8*)(Ab + (size_t)row * Ssz + (kt) + c8); \
      rB[c] = *(const bf16x8*)(Bb + (size_t)row * Ssz + (kt) + c8); \
    }                                                             \
  }
  K4_LOAD(0)
  for (int kt = 0; kt < Ssz; kt += 64) {
    __syncthreads();
#pragma unroll
    for (int c = 0; c < 2; ++c) {
      int row = c * 32 + r0;
      *(bf16x8*)&sA[row * LDT + c8] = rA[c];
      *(bf16x8*)&sB[row * LDT + c8] = rB[c];
    }
    __syncthreads();
    if (kt + 64 < Ssz) K4_LOAD(kt + 64)
#pragma unroll
    for (int ks = 0; ks < 64; ks += 32) {
      bf16x8 fa[2], fb[2];
#pragma unroll
      for (int t = 0; t < 2; ++t) fa[t] = *(const bf16x8*)&sA[(wr * 32 + t * 16 + l15) * LDT + ks + q8];
#pragma unroll
      for (int u = 0; u < 2; ++u) fb[u] = *(const bf16x8*)&sB[(wc * 32 + u * 16 + l15) * LDT + ks + q8];
#pragma unroll
      for (int t = 0; t < 2; ++t)
#pragma unroll
        for (int u = 0; u < 2; ++u) acc[t][u] = MFMA(fa[t], fb[u], acc[t][u]);
    }
  }
#pragma unroll
  for (int t = 0; t < 2; ++t)
#pragma unroll
    for (int u = 0; u < 2; ++u) {
      int d = wc * 32 + u * 16 + l15;
#pragma unroll
      for (int r = 0; r < 4; ++r) {
        int row = i0 + wr * 32 + t * 16 + q4 + r;
        aout[(size_t)(b * Ssz + row) * Dsz + h * DHsz + d] = (bf16)acc[t][u][r];
      }
    }
#undef K4_LOAD
}

// ---------------------------------------------------------------------------
// K5: out = aout_bf @ (ow_h+ow_l)^T  2-term, fp32 out
// ---------------------------------------------------------------------------
__global__ __launch_bounds__(256, 2) void k5_out(const bf16* __restrict__ A,
                                                 const bf16* __restrict__ Bh,
                                                 const bf16* __restrict__ Bl,
                                                 float* __restrict__ C) {
  __shared__ __align__(16) bf16 sA[128 * LDT], sBh[128 * LDT], sBl[128 * LDT];
  const int tid = threadIdx.x;
  const int lane = tid & 63, wv = tid >> 6;
  const int wr = wv >> 1, wc = wv & 1;
  const int l15 = lane & 15, q8 = (lane >> 4) << 3, q4 = (lane >> 4) << 2;
  const int m0 = blockIdx.y * 128, n0 = blockIdx.x * 128;
  const int r0 = tid >> 3, c8 = (tid & 7) << 3;
  f32x4 acc[4][4];
#pragma unroll
  for (int t = 0; t < 4; ++t)
#pragma unroll
    for (int u = 0; u < 4; ++u)
#pragma unroll
      for (int r = 0; r < 4; ++r) acc[t][u][r] = 0.f;
  bf16x8 rA[4], rBh[4], rBl[4];
#define K5_LOAD(kt)                                                   \
  {                                                                   \
    _Pragma("unroll") for (int c = 0; c < 4; ++c) {                   \
      int row = c * 32 + r0;                                          \
      rA[c] = *(const bf16x8*)(A + (size_t)(m0 + row) * Dsz + (kt) + c8);   \
      rBh[c] = *(const bf16x8*)(Bh + (size_t)(n0 + row) * Dsz + (kt) + c8); \
      rBl[c] = *(const bf16x8*)(Bl + (size_t)(n0 + row) * Dsz + (kt) + c8); \
    }                                                                 \
  }
  K5_LOAD(0)
  for (int kt = 0; kt < Dsz; kt += 64) {
    __syncthreads();
#pragma unroll
    for (int c = 0; c < 4; ++c) {
      int row = c * 32 + r0;
      *(bf16x8*)&sA[row * LDT + c8] = rA[c];
      *(bf16x8*)&sBh[row * LDT + c8] = rBh[c];
      *(bf16x8*)&sBl[row * LDT + c8] = rBl[c];
    }
    __syncthreads();
    if (kt + 64 < Dsz) K5_LOAD(kt + 64)
#pragma unroll
    for (int ks = 0; ks < 64; ks += 32) {
      bf16x8 fa[4], fbh[4], fbl[4];
#pragma unroll
      for (int t = 0; t < 4; ++t) fa[t] = *(const bf16x8*)&sA[(wr * 64 + t * 16 + l15) * LDT + ks + q8];
#pragma unroll
      for (int u = 0; u < 4; ++u) {
        int n = wc * 64 + u * 16 + l15;
        fbh[u] = *(const bf16x8*)&sBh[n * LDT + ks + q8];
        fbl[u] = *(const bf16x8*)&sBl[n * LDT + ks + q8];
      }
#pragma unroll
      for (int t = 0; t < 4; ++t)
#pragma unroll
        for (int u = 0; u < 4; ++u) {
          acc[t][u] = MFMA(fa[t], fbh[u], acc[t][u]);
          acc[t][u] = MFMA(fa[t], fbl[u], acc[t][u]);
        }
    }
  }
#pragma unroll
  for (int t = 0; t < 4; ++t)
#pragma unroll
    for (int u = 0; u < 4; ++u) {
      int col = n0 + wc * 64 + u * 16 + l15;
#pragma unroll
      for (int r = 0; r < 4; ++r) {
        int row = m0 + wr * 64 + t * 16 + q4 + r;
        C[(size_t)row * Dsz + col] = acc[t][u][r];
      }
    }
#undef K5_LOAD
}

// ---------------------------------------------------------------------------
extern "C" void kernel_launch(void* const* d_in, const int* in_sizes, int n_in,
                              void* d_out, int out_size, void* d_ws, size_t ws_size,
                              hipStream_t stream) {
  const float* x      = (const float*)d_in[0];
  const float* qkv_w  = (const float*)d_in[1];
  const float* out_w  = (const float*)d_in[2];
  const float* bias_p = (const float*)d_in[3];
  const float* bias_a = (const float*)d_in[4];
  const float* w1     = (const float*)d_in[5];
  const float* b1     = (const float*)d_in[6];
  const float* w2     = (const float*)d_in[7];
  const float* b2     = (const float*)d_in[8];
  float* out = (float*)d_out;

  char* ws = (char*)d_ws;
  const size_t MB = 1ull << 20;
  bf16* x_h    = (bf16*)(ws + 0 * MB);   // 4 MB
  bf16* x_l    = (bf16*)(ws + 4 * MB);   // 4 MB
  bf16* w_h    = (bf16*)(ws + 8 * MB);   // 6 MB
  bf16* w_l    = (bf16*)(ws + 14 * MB);  // 6 MB
  bf16* ow_h   = (bf16*)(ws + 20 * MB);  // 2 MB
  bf16* ow_l   = (bf16*)(ws + 22 * MB);  // 2 MB
  bf16* qkv_bf = (bf16*)(ws + 24 * MB);  // 12 MB
  bf16* v_t    = (bf16*)(ws + 36 * MB);  // 4 MB
  bf16* sc_bf  = (bf16*)(ws + 40 * MB);  // 32 MB (per-batch scores/attn, in place)
  bf16* aout   = (bf16*)(ws + 72 * MB);  // 4 MB
  float* kbt   = (float*)(ws + 76 * MB); // 64 KB
  float* t1    = (float*)(ws + 76 * MB + 65536); // 64 KB

  cast_hilo<<<2048, 256, 0, stream>>>(x, x_h, x_l, Bsz * Ssz * Dsz);
  cast_hilo<<<3072, 256, 0, stream>>>(qkv_w, w_h, w_l, QKV3 * Dsz);
  cast_hilo<<<1024, 256, 0, stream>>>(out_w, ow_h, ow_l, Dsz * Dsz);
  kb_table<<<64, 256, 0, stream>>>(bias_p, bias_a, kbt);
  t1_table<<<64, 256, 0, stream>>>(kbt, w1, b1, t1);

  k1_qkv<<<dim3(QKV3 / 128, (Bsz * Ssz) / 128), 256, 0, stream>>>(x_h, x_l, w_h, w_l, qkv_bf);
  pack_vt<<<dim3(Ssz / 64, Bsz * Hn), 256, 0, stream>>>(qkv_bf, v_t);

  for (int b = 0; b < Bsz; ++b) {
    k2_qk<<<dim3(Ssz / 128, Ssz / 128, Hn), 256, 0, stream>>>(qkv_bf, sc_bf, b);
    dape_softmax<<<Ssz, 256, 0, stream>>>(sc_bf, t1, kbt, w1, w2, b2);
    k4_av<<<dim3(Ssz / 64, Hn), 256, 0, stream>>>(sc_bf, v_t, aout, b);
  }

  k5_out<<<dim3(Dsz / 128, (Bsz * Ssz) / 128), 256, 0, stream>>>(aout, ow_h, ow_l, out);
}

// Round 4
// 321.551 us; speedup vs baseline: 2.9616x; 1.1667x over previous
//
#include <hip/hip_runtime.h>
#include <math.h>

#define Bsz 2
#define Ssz 1024
#define Dsz 1024
#define Hn 16
#define DHsz 64
#define QKV3 3072
#define SCALE 0.125f

typedef __bf16 bf16;
typedef bf16 bf16x8 __attribute__((ext_vector_type(8)));
typedef bf16 bf16x4 __attribute__((ext_vector_type(4)));
typedef float f32x4 __attribute__((ext_vector_type(4)));

#define MFMA(a, b, c) __builtin_amdgcn_mfma_f32_16x16x32_bf16(a, b, c, 0, 0, 0)
#define LDT 72

// ---------------------------------------------------------------------------
// cast fp32 -> bf16 hi + bf16 lo residual
// ---------------------------------------------------------------------------
__global__ void cast_hilo(const float* __restrict__ src, bf16* __restrict__ hi,
                          bf16* __restrict__ lo, int n) {
  int idx = (blockIdx.x * 256 + threadIdx.x) * 4;
  if (idx >= n) return;
  float4 v = *(const float4*)(src + idx);
  bf16 h0 = (bf16)v.x, h1 = (bf16)v.y, h2 = (bf16)v.z, h3 = (bf16)v.w;
  bf16x4 hv = {h0, h1, h2, h3};
  bf16x4 lv = {(bf16)(v.x - (float)h0), (bf16)(v.y - (float)h1),
               (bf16)(v.z - (float)h2), (bf16)(v.w - (float)h3)};
  *(bf16x4*)(hi + idx) = hv;
  *(bf16x4*)(lo + idx) = lv;
}

// kbtt[d][h] = -clip(p_h)*log1p(clip(a_h)*d)   (transposed: h contiguous)
__global__ void kb_table(const float* __restrict__ bias_p, const float* __restrict__ bias_a,
                         float* __restrict__ kbtt) {
  int idx = blockIdx.x * 256 + threadIdx.x;  // 16384
  int d = idx >> 4, h = idx & 15;
  float p = fmaxf(bias_p[h], 0.01f), a = fmaxf(bias_a[h], 0.01f);
  kbtt[idx] = -p * log1pf(a * (float)d);
}

// t1t[d][n] = b1[n] + sum_h w1[n][16+h] * kbtt[d][h]   (kerple folded thru layer1)
__global__ void t1_table(const float* __restrict__ kbtt, const float* __restrict__ w1,
                         const float* __restrict__ b1, float* __restrict__ t1t) {
  int idx = blockIdx.x * 256 + threadIdx.x;  // 16384
  int d = idx >> 4, n = idx & 15;
  float acc = b1[n];
#pragma unroll
  for (int h = 0; h < 16; ++h) acc += w1[n * 32 + 16 + h] * kbtt[d * 16 + h];
  t1t[idx] = acc;
}

// ---------------------------------------------------------------------------
// K1: qkv_bf = bf16( (x_h+x_l) @ (w_h+w_l)^T )  3-term MFMA
// ---------------------------------------------------------------------------
__global__ __launch_bounds__(256, 2) void k1_qkv(const bf16* __restrict__ Ah,
                                                 const bf16* __restrict__ Al,
                                                 const bf16* __restrict__ Bh,
                                                 const bf16* __restrict__ Bl,
                                                 bf16* __restrict__ C) {
  __shared__ __align__(16) bf16 sAh[128 * LDT], sAl[128 * LDT];
  __shared__ __align__(16) bf16 sBh[128 * LDT], sBl[128 * LDT];
  const int tid = threadIdx.x;
  const int lane = tid & 63, wv = tid >> 6;
  const int wr = wv >> 1, wc = wv & 1;
  const int l15 = lane & 15, q8 = (lane >> 4) << 3, q4 = (lane >> 4) << 2;
  const int m0 = blockIdx.y * 128, n0 = blockIdx.x * 128;
  const int r0 = tid >> 3, c8 = (tid & 7) << 3;

  f32x4 acc[4][4];
#pragma unroll
  for (int t = 0; t < 4; ++t)
#pragma unroll
    for (int u = 0; u < 4; ++u)
#pragma unroll
      for (int r = 0; r < 4; ++r) acc[t][u][r] = 0.f;

  bf16x8 rAh[4], rAl[4], rBh[4], rBl[4];
#define K1_LOAD(kt)                                                   \
  {                                                                   \
    _Pragma("unroll") for (int c = 0; c < 4; ++c) {                   \
      int row = c * 32 + r0;                                          \
      rAh[c] = *(const bf16x8*)(Ah + (size_t)(m0 + row) * Dsz + (kt) + c8); \
      rAl[c] = *(const bf16x8*)(Al + (size_t)(m0 + row) * Dsz + (kt) + c8); \
      rBh[c] = *(const bf16x8*)(Bh + (size_t)(n0 + row) * Dsz + (kt) + c8); \
      rBl[c] = *(const bf16x8*)(Bl + (size_t)(n0 + row) * Dsz + (kt) + c8); \
    }                                                                 \
  }

  K1_LOAD(0)
  for (int kt = 0; kt < Dsz; kt += 64) {
    __syncthreads();
#pragma unroll
    for (int c = 0; c < 4; ++c) {
      int row = c * 32 + r0;
      *(bf16x8*)&sAh[row * LDT + c8] = rAh[c];
      *(bf16x8*)&sAl[row * LDT + c8] = rAl[c];
      *(bf16x8*)&sBh[row * LDT + c8] = rBh[c];
      *(bf16x8*)&sBl[row * LDT + c8] = rBl[c];
    }
    __syncthreads();
    if (kt + 64 < Dsz) K1_LOAD(kt + 64)
#pragma unroll
    for (int ks = 0; ks < 64; ks += 32) {
      bf16x8 fah[4], fal[4], fbh[4], fbl[4];
#pragma unroll
      for (int t = 0; t < 4; ++t) {
        int m = wr * 64 + t * 16 + l15;
        fah[t] = *(const bf16x8*)&sAh[m * LDT + ks + q8];
        fal[t] = *(const bf16x8*)&sAl[m * LDT + ks + q8];
      }
#pragma unroll
      for (int u = 0; u < 4; ++u) {
        int n = wc * 64 + u * 16 + l15;
        fbh[u] = *(const bf16x8*)&sBh[n * LDT + ks + q8];
        fbl[u] = *(const bf16x8*)&sBl[n * LDT + ks + q8];
      }
#pragma unroll
      for (int t = 0; t < 4; ++t)
#pragma unroll
        for (int u = 0; u < 4; ++u) {
          acc[t][u] = MFMA(fah[t], fbh[u], acc[t][u]);
          acc[t][u] = MFMA(fah[t], fbl[u], acc[t][u]);
          acc[t][u] = MFMA(fal[t], fbh[u], acc[t][u]);
        }
    }
  }
#pragma unroll
  for (int t = 0; t < 4; ++t)
#pragma unroll
    for (int u = 0; u < 4; ++u) {
      int col = n0 + wc * 64 + u * 16 + l15;
#pragma unroll
      for (int r = 0; r < 4; ++r) {
        int row = m0 + wr * 64 + t * 16 + q4 + r;
        C[(size_t)row * QKV3 + col] = (bf16)acc[t][u][r];
      }
    }
#undef K1_LOAD
}

// ---------------------------------------------------------------------------
// pack V transposed: v_t[b][h][d][j]
// ---------------------------------------------------------------------------
__global__ void pack_vt(const bf16* __restrict__ qkv, bf16* __restrict__ vt) {
  __shared__ __align__(16) bf16 T[64 * LDT];
  const int tid = threadIdx.x;
  const int bh = blockIdx.y, b = bh >> 4, h = bh & 15;
  const int j0 = blockIdx.x * 64;
#pragma unroll
  for (int c = 0; c < 2; ++c) {
    int lin = c * 256 + tid;
    int jr = lin >> 3, d8 = (lin & 7) << 3;
    bf16x8 v = *(const bf16x8*)(qkv + (size_t)(b * Ssz + j0 + jr) * QKV3 + 2048 + h * DHsz + d8);
#pragma unroll
    for (int e = 0; e < 8; ++e) T[(d8 + e) * LDT + jr] = v[e];
  }
  __syncthreads();
#pragma unroll
  for (int c = 0; c < 2; ++c) {
    int lin = c * 256 + tid;
    int d = lin >> 3, j8 = (lin & 7) << 3;
    bf16x8 o = *(const bf16x8*)&T[d * LDT + j8];
    *(bf16x8*)(vt + ((size_t)(b * Hn + h) * DHsz + d) * Ssz + j0 + j8) = o;
  }
}

// ---------------------------------------------------------------------------
// K2: scores_bf[h][i][j] = bf16( SCALE * Q @ K^T )
// ---------------------------------------------------------------------------
__global__ __launch_bounds__(256, 3) void k2_qk(const bf16* __restrict__ qkv,
                                                bf16* __restrict__ scores, int b) {
  __shared__ __align__(16) bf16 sA[128 * LDT], sB[128 * LDT];
  const int tid = threadIdx.x;
  const int lane = tid & 63, wv = tid >> 6;
  const int wr = wv >> 1, wc = wv & 1;
  const int l15 = lane & 15, q8 = (lane >> 4) << 3, q4 = (lane >> 4) << 2;
  const int h = blockIdx.z, i0 = blockIdx.y * 128, j0 = blockIdx.x * 128;
  const bf16* Ab = qkv + (size_t)b * Ssz * QKV3 + h * DHsz;
  const bf16* Bb = Ab + Ssz;
  const int r0 = tid >> 3, c8 = (tid & 7) << 3;
#pragma unroll
  for (int c = 0; c < 4; ++c) {
    int row = c * 32 + r0;
    *(bf16x8*)&sA[row * LDT + c8] = *(const bf16x8*)(Ab + (size_t)(i0 + row) * QKV3 + c8);
    *(bf16x8*)&sB[row * LDT + c8] = *(const bf16x8*)(Bb + (size_t)(j0 + row) * QKV3 + c8);
  }
  __syncthreads();
  f32x4 acc[4][4];
#pragma unroll
  for (int t = 0; t < 4; ++t)
#pragma unroll
    for (int u = 0; u < 4; ++u)
#pragma unroll
      for (int r = 0; r < 4; ++r) acc[t][u][r] = 0.f;
#pragma unroll
  for (int ks = 0; ks < 64; ks += 32) {
    bf16x8 fa[4], fb[4];
#pragma unroll
    for (int t = 0; t < 4; ++t) fa[t] = *(const bf16x8*)&sA[(wr * 64 + t * 16 + l15) * LDT + ks + q8];
#pragma unroll
    for (int u = 0; u < 4; ++u) fb[u] = *(const bf16x8*)&sB[(wc * 64 + u * 16 + l15) * LDT + ks + q8];
#pragma unroll
    for (int t = 0; t < 4; ++t)
#pragma unroll
      for (int u = 0; u < 4; ++u) acc[t][u] = MFMA(fa[t], fb[u], acc[t][u]);
  }
#pragma unroll
  for (int t = 0; t < 4; ++t)
#pragma unroll
    for (int u = 0; u < 4; ++u) {
      int col = j0 + wc * 64 + u * 16 + l15;
#pragma unroll
      for (int r = 0; r < 4; ++r) {
        int row = i0 + wr * 64 + t * 16 + q4 + r;
        scores[((size_t)h * Ssz + row) * Ssz + col] = (bf16)(acc[t][u][r] * SCALE);
      }
    }
}

// ---------------------------------------------------------------------------
// K3: DAPE MLP via MFMA, all operands staged/gathered through LDS. In-place bf16.
// Block = one query row i. Wave wv owns j in [wv*256, wv*256+256).
// Stage: scores rows (coalesced bf16) -> lgt[h][j] fp32.
// Layer1: A from lgt gather (2-way banks) -> 2 mfma; +t1t (bias+kerple, fp32); gelu
// Layer2: A = hdn hi/lo via per-wave LDS transpose -> 3 mfma
// Logits: lgt[h][j] += kbtt + refine  (per-lane b128 RMW)
// ---------------------------------------------------------------------------
__device__ __forceinline__ float gelu_exact(float x) {
  return 0.5f * x * (1.0f + erff(x * 0.70710678118654752f));
}

__global__ __launch_bounds__(256, 2) void dape_softmax(bf16* scores,
                                                       const float* __restrict__ t1t,
                                                       const float* __restrict__ kbtt,
                                                       const float* __restrict__ w1,
                                                       const float* __restrict__ w2,
                                                       const float* __restrict__ b2) {
  const int i = blockIdx.x;
  const int tid = threadIdx.x;
  const int lane = tid & 63, wv = tid >> 6;
  const int l15 = lane & 15, q = lane >> 4;
  const int q8 = q << 3, q4 = q << 2;

  __shared__ float lgt[Hn][1028];                    // 65792 B
  __shared__ __align__(16) bf16 hdnS[4][2][16][40];  // 10240 B per-wave scratch

  // ---- weight fragments (B-layout: lane=n, k=q8+e), hi/lo split ----
  bf16x8 w1h = {}, w1l = {}, w2h = {}, w2l = {};
  if (q < 2) {
#pragma unroll
    for (int e = 0; e < 8; ++e) {
      float wa = w1[l15 * 32 + q8 + e];  // first 16 inputs = scores path
      bf16 ha = (bf16)wa;
      w1h[e] = ha; w1l[e] = (bf16)(wa - (float)ha);
      float wb = w2[l15 * 16 + q8 + e];
      bf16 hb = (bf16)wb;
      w2h[e] = hb; w2l[e] = (bf16)(wb - (float)hb);
    }
  }
  const float bias2 = b2[l15];

  // zero the k=16..31 pad region of this wave's hdn scratch
  if (lane < 32) {
    *(bf16x8*)&hdnS[wv][q][l15][16] = (bf16x8){};
    *(bf16x8*)&hdnS[wv][q][l15][24] = (bf16x8){};
  }

  // ---- stage: this wave's 256-j slice of all 16 head rows, coalesced ----
  const bf16* srow = scores + (size_t)i * Ssz;
  const int jw = wv * 256;
#pragma unroll
  for (int h = 0; h < Hn; ++h) {
    bf16x4 v = *(const bf16x4*)(srow + ((size_t)h << 20) + jw + lane * 4);
    f32x4 f = {(float)v[0], (float)v[1], (float)v[2], (float)v[3]};
    *(f32x4*)&lgt[h][jw + lane * 4] = f;
  }
  // no barrier: each wave only touches its own j-columns until softmax

  for (int jt = 0; jt < 16; ++jt) {
    const int j0 = jw + jt * 16;
    // ---- layer 1 A-frag: gather scores from lgt (banks 2-way: free) ----
    bf16x8 a1 = {};
    if (q < 2) {
#pragma unroll
      for (int e = 0; e < 8; ++e) a1[e] = (bf16)lgt[q8 + e][j0 + l15];
    }
    f32x4 c1 = {0.f, 0.f, 0.f, 0.f};
    c1 = MFMA(a1, w1h, c1);
    c1 = MFMA(a1, w1l, c1);
    // + t1t (bias + kerple path, fp32, coalesced), gelu, hi/lo into scratch
#pragma unroll
    for (int r = 0; r < 4; ++r) {
      int j = j0 + q4 + r;
      int d = i - j; if (d < 0) d = -d;
      float g = gelu_exact(c1[r] + t1t[d * 16 + l15]);
      bf16 gh = (bf16)g;
      hdnS[wv][0][q4 + r][l15] = gh;
      hdnS[wv][1][q4 + r][l15] = (bf16)(g - (float)gh);
    }
    // ---- layer 2 ----
    bf16x8 a2h = *(const bf16x8*)&hdnS[wv][0][l15][q8];
    bf16x8 a2l = *(const bf16x8*)&hdnS[wv][1][l15][q8];
    f32x4 c2 = {bias2, bias2, bias2, bias2};
    c2 = MFMA(a2h, w2h, c2);
    c2 = MFMA(a2h, w2l, c2);
    c2 = MFMA(a2l, w2h, c2);
    // ---- logits: lane owns h=l15, j=j0+q4+0..3 -> single b128 RMW ----
    f32x4 old = *(const f32x4*)&lgt[l15][j0 + q4];
#pragma unroll
    for (int w = 0; w < 4; ++w) {
      int j = j0 + q4 + w;
      int d = i - j; if (d < 0) d = -d;
      old[w] += kbtt[d * 16 + l15] + c2[w];
    }
    *(f32x4*)&lgt[l15][j0 + q4] = old;
  }
  __syncthreads();

  // ---- softmax: wave wv handles heads 4wv..4wv+3; write attn in-place ----
#pragma unroll
  for (int hh = 0; hh < 4; ++hh) {
    const int h = wv * 4 + hh;
    f32x4 v[4];
    float m = -3.0e38f;
#pragma unroll
    for (int t = 0; t < 4; ++t) {
      v[t] = *(const f32x4*)&lgt[h][t * 256 + lane * 4];
#pragma unroll
      for (int e = 0; e < 4; ++e) m = fmaxf(m, v[t][e]);
    }
#pragma unroll
    for (int off = 32; off > 0; off >>= 1) m = fmaxf(m, __shfl_xor(m, off, 64));
    float s = 0.f;
#pragma unroll
    for (int t = 0; t < 4; ++t)
#pragma unroll
      for (int e = 0; e < 4; ++e) {
        float ex = __expf(v[t][e] - m);
        v[t][e] = ex;
        s += ex;
      }
#pragma unroll
    for (int off = 32; off > 0; off >>= 1) s += __shfl_xor(s, off, 64);
    const float inv = 1.f / s;
    bf16* dst = scores + ((size_t)h << 20) + (size_t)i * Ssz;
#pragma unroll
    for (int t = 0; t < 4; ++t) {
      bf16x4 pv = {(bf16)(v[t][0] * inv), (bf16)(v[t][1] * inv),
                   (bf16)(v[t][2] * inv), (bf16)(v[t][3] * inv)};
      *(bf16x4*)(dst + t * 256 + lane * 4) = pv;
    }
  }
}

// ---------------------------------------------------------------------------
// K4: aout = attn @ V   (via v_t), per (i-tile, h)
// ---------------------------------------------------------------------------
__global__ __launch_bounds__(256, 4) void k4_av(const bf16* __restrict__ attn,
                                                const bf16* __restrict__ vt,
                                                bf16* __restrict__ aout, int b) {
  __shared__ __align__(16) bf16 sA[64 * LDT], sB[64 * LDT];
  const int tid = threadIdx.x;
  const int lane = tid & 63, wv = tid >> 6;
  const int wr = wv >> 1, wc = wv & 1;
  const int l15 = lane & 15, q8 = (lane >> 4) << 3, q4 = (lane >> 4) << 2;
  const int i0 = blockIdx.x * 64, h = blockIdx.y;
  const bf16* Ab = attn + ((size_t)h * Ssz + i0) * Ssz;
  const bf16* Bb = vt + (size_t)(b * Hn + h) * DHsz * Ssz;
  const int r0 = tid >> 3, c8 = (tid & 7) << 3;
  f32x4 acc[2][2];
#pragma unroll
  for (int t = 0; t < 2; ++t)
#pragma unroll
    for (int u = 0; u < 2; ++u)
#pragma unroll
      for (int r = 0; r < 4; ++r) acc[t][u][r] = 0.f;
  bf16x8 rA[2], rB[2];
#define K4_LOAD(kt)                                               \
  {                                                               \
    _Pragma("unroll") for (int c = 0; c < 2; ++c) {               \
      int row = c * 32 + r0;                                      \
      rA[c] = *(const bf16x8*)(Ab + (size_t)row * Ssz + (kt) + c8); \
      rB[c] = *(const bf16x8*)(Bb + (size_t)row * Ssz + (kt) + c8); \
    }                                                             \
  }
  K4_LOAD(0)
  for (int kt = 0; kt < Ssz; kt += 64) {
    __syncthreads();
#pragma unroll
    for (int c = 0; c < 2; ++c) {
      int row = c * 32 + r0;
      *(bf16x8*)&sA[row * LDT + c8] = rA[c];
      *(bf16x8*)&sB[row * LDT + c8] = rB[c];
    }
    __syncthreads();
    if (kt + 64 < Ssz) K4_LOAD(kt + 64)
#pragma unroll
    for (int ks = 0; ks < 64; ks += 32) {
      bf16x8 fa[2], fb[2];
#pragma unroll
      for (int t = 0; t < 2; ++t) fa[t] = *(const bf16x8*)&sA[(wr * 32 + t * 16 + l15) * LDT + ks + q8];
#pragma unroll
      for (int u = 0; u < 2; ++u) fb[u] = *(const bf16x8*)&sB[(wc * 32 + u * 16 + l15) * LDT + ks + q8];
#pragma unroll
      for (int t = 0; t < 2; ++t)
#pragma unroll
        for (int u = 0; u < 2; ++u) acc[t][u] = MFMA(fa[t], fb[u], acc[t][u]);
    }
  }
#pragma unroll
  for (int t = 0; t < 2; ++t)
#pragma unroll
    for (int u = 0; u < 2; ++u) {
      int d = wc * 32 + u * 16 + l15;
#pragma unroll
      for (int r = 0; r < 4; ++r) {
        int row = i0 + wr * 32 + t * 16 + q4 + r;
        aout[(size_t)(b * Ssz + row) * Dsz + h * DHsz + d] = (bf16)acc[t][u][r];
      }
    }
#undef K4_LOAD
}

// ---------------------------------------------------------------------------
// K5: out = aout_bf @ (ow_h+ow_l)^T  2-term, fp32 out
// ---------------------------------------------------------------------------
__global__ __launch_bounds__(256, 2) void k5_out(const bf16* __restrict__ A,
                                                 const bf16* __restrict__ Bh,
                                                 const bf16* __restrict__ Bl,
                                                 float* __restrict__ C) {
  __shared__ __align__(16) bf16 sA[128 * LDT], sBh[128 * LDT], sBl[128 * LDT];
  const int tid = threadIdx.x;
  const int lane = tid & 63, wv = tid >> 6;
  const int wr = wv >> 1, wc = wv & 1;
  const int l15 = lane & 15, q8 = (lane >> 4) << 3, q4 = (lane >> 4) << 2;
  const int m0 = blockIdx.y * 128, n0 = blockIdx.x * 128;
  const int r0 = tid >> 3, c8 = (tid & 7) << 3;
  f32x4 acc[4][4];
#pragma unroll
  for (int t = 0; t < 4; ++t)
#pragma unroll
    for (int u = 0; u < 4; ++u)
#pragma unroll
      for (int r = 0; r < 4; ++r) acc[t][u][r] = 0.f;
  bf16x8 rA[4], rBh[4], rBl[4];
#define K5_LOAD(kt)                                                   \
  {                                                                   \
    _Pragma("unroll") for (int c = 0; c < 4; ++c) {                   \
      int row = c * 32 + r0;                                          \
      rA[c] = *(const bf16x8*)(A + (size_t)(m0 + row) * Dsz + (kt) + c8);   \
      rBh[c] = *(const bf16x8*)(Bh + (size_t)(n0 + row) * Dsz + (kt) + c8); \
      rBl[c] = *(const bf16x8*)(Bl + (size_t)(n0 + row) * Dsz + (kt) + c8); \
    }                                                                 \
  }
  K5_LOAD(0)
  for (int kt = 0; kt < Dsz; kt += 64) {
    __syncthreads();
#pragma unroll
    for (int c = 0; c < 4; ++c) {
      int row = c * 32 + r0;
      *(bf16x8*)&sA[row * LDT + c8] = rA[c];
      *(bf16x8*)&sBh[row * LDT + c8] = rBh[c];
      *(bf16x8*)&sBl[row * LDT + c8] = rBl[c];
    }
    __syncthreads();
    if (kt + 64 < Dsz) K5_LOAD(kt + 64)
#pragma unroll
    for (int ks = 0; ks < 64; ks += 32) {
      bf16x8 fa[4], fbh[4], fbl[4];
#pragma unroll
      for (int t = 0; t < 4; ++t) fa[t] = *(const bf16x8*)&sA[(wr * 64 + t * 16 + l15) * LDT + ks + q8];
#pragma unroll
      for (int u = 0; u < 4; ++u) {
        int n = wc * 64 + u * 16 + l15;
        fbh[u] = *(const bf16x8*)&sBh[n * LDT + ks + q8];
        fbl[u] = *(const bf16x8*)&sBl[n * LDT + ks + q8];
      }
#pragma unroll
      for (int t = 0; t < 4; ++t)
#pragma unroll
        for (int u = 0; u < 4; ++u) {
          acc[t][u] = MFMA(fa[t], fbh[u], acc[t][u]);
          acc[t][u] = MFMA(fa[t], fbl[u], acc[t][u]);
        }
    }
  }
#pragma unroll
  for (int t = 0; t < 4; ++t)
#pragma unroll
    for (int u = 0; u < 4; ++u) {
      int col = n0 + wc * 64 + u * 16 + l15;
#pragma unroll
      for (int r = 0; r < 4; ++r) {
        int row = m0 + wr * 64 + t * 16 + q4 + r;
        C[(size_t)row * Dsz + col] = acc[t][u][r];
      }
    }
#undef K5_LOAD
}

// ---------------------------------------------------------------------------
extern "C" void kernel_launch(void* const* d_in, const int* in_sizes, int n_in,
                              void* d_out, int out_size, void* d_ws, size_t ws_size,
                              hipStream_t stream) {
  const float* x      = (const float*)d_in[0];
  const float* qkv_w  = (const float*)d_in[1];
  const float* out_w  = (const float*)d_in[2];
  const float* bias_p = (const float*)d_in[3];
  const float* bias_a = (const float*)d_in[4];
  const float* w1     = (const float*)d_in[5];
  const float* b1     = (const float*)d_in[6];
  const float* w2     = (const float*)d_in[7];
  const float* b2     = (const float*)d_in[8];
  float* out = (float*)d_out;

  char* ws = (char*)d_ws;
  const size_t MB = 1ull << 20;
  bf16* x_h    = (bf16*)(ws + 0 * MB);   // 4 MB
  bf16* x_l    = (bf16*)(ws + 4 * MB);   // 4 MB
  bf16* w_h    = (bf16*)(ws + 8 * MB);   // 6 MB
  bf16* w_l    = (bf16*)(ws + 14 * MB);  // 6 MB
  bf16* ow_h   = (bf16*)(ws + 20 * MB);  // 2 MB
  bf16* ow_l   = (bf16*)(ws + 22 * MB);  // 2 MB
  bf16* qkv_bf = (bf16*)(ws + 24 * MB);  // 12 MB
  bf16* v_t    = (bf16*)(ws + 36 * MB);  // 4 MB
  bf16* sc_bf  = (bf16*)(ws + 40 * MB);  // 32 MB (per-batch scores/attn, in place)
  bf16* aout   = (bf16*)(ws + 72 * MB);  // 4 MB
  float* kbtt  = (float*)(ws + 76 * MB); // 64 KB  [d][h]
  float* t1t   = (float*)(ws + 76 * MB + 65536); // 64 KB  [d][n]

  cast_hilo<<<2048, 256, 0, stream>>>(x, x_h, x_l, Bsz * Ssz * Dsz);
  cast_hilo<<<3072, 256, 0, stream>>>(qkv_w, w_h, w_l, QKV3 * Dsz);
  cast_hilo<<<1024, 256, 0, stream>>>(out_w, ow_h, ow_l, Dsz * Dsz);
  kb_table<<<64, 256, 0, stream>>>(bias_p, bias_a, kbtt);
  t1_table<<<64, 256, 0, stream>>>(kbtt, w1, b1, t1t);

  k1_qkv<<<dim3(QKV3 / 128, (Bsz * Ssz) / 128), 256, 0, stream>>>(x_h, x_l, w_h, w_l, qkv_bf);
  pack_vt<<<dim3(Ssz / 64, Bsz * Hn), 256, 0, stream>>>(qkv_bf, v_t);

  for (int b = 0; b < Bsz; ++b) {
    k2_qk<<<dim3(Ssz / 128, Ssz / 128, Hn), 256, 0, stream>>>(qkv_bf, sc_bf, b);
    dape_softmax<<<Ssz, 256, 0, stream>>>(sc_bf, t1t, kbtt, w1, w2, b2);
    k4_av<<<dim3(Ssz / 64, Hn), 256, 0, stream>>>(sc_bf, v_t, aout, b);
  }

  k5_out<<<dim3(Dsz / 128, (Bsz * Ssz) / 128), 256, 0, stream>>>(aout, ow_h, ow_l, out);
}

// Round 5
// 298.558 us; speedup vs baseline: 3.1897x; 1.0770x over previous
//
#include <hip/hip_runtime.h>
#include <math.h>

#define Bsz 2
#define Ssz 1024
#define Dsz 1024
#define Hn 16
#define DHsz 64
#define QKV3 3072
#define SCALE 0.125f

typedef __bf16 bf16;
typedef bf16 bf16x8 __attribute__((ext_vector_type(8)));
typedef bf16 bf16x4 __attribute__((ext_vector_type(4)));
typedef float f32x4 __attribute__((ext_vector_type(4)));

#define MFMA(a, b, c) __builtin_amdgcn_mfma_f32_16x16x32_bf16(a, b, c, 0, 0, 0)
#define LDT 72

// ---------------------------------------------------------------------------
// cast fp32 -> bf16 hi + bf16 lo residual
// ---------------------------------------------------------------------------
__global__ void cast_hilo(const float* __restrict__ src, bf16* __restrict__ hi,
                          bf16* __restrict__ lo, int n) {
  int idx = (blockIdx.x * 256 + threadIdx.x) * 4;
  if (idx >= n) return;
  float4 v = *(const float4*)(src + idx);
  bf16 h0 = (bf16)v.x, h1 = (bf16)v.y, h2 = (bf16)v.z, h3 = (bf16)v.w;
  bf16x4 hv = {h0, h1, h2, h3};
  bf16x4 lv = {(bf16)(v.x - (float)h0), (bf16)(v.y - (float)h1),
               (bf16)(v.z - (float)h2), (bf16)(v.w - (float)h3)};
  *(bf16x4*)(hi + idx) = hv;
  *(bf16x4*)(lo + idx) = lv;
}

// kbtt[d][h] = -clip(p_h)*log1p(clip(a_h)*d)   (transposed: h contiguous)
__global__ void kb_table(const float* __restrict__ bias_p, const float* __restrict__ bias_a,
                         float* __restrict__ kbtt) {
  int idx = blockIdx.x * 256 + threadIdx.x;  // 16384
  int d = idx >> 4, h = idx & 15;
  float p = fmaxf(bias_p[h], 0.01f), a = fmaxf(bias_a[h], 0.01f);
  kbtt[idx] = -p * log1pf(a * (float)d);
}

// t1t[d][n] = b1[n] + sum_h w1[n][16+h] * kbtt[d][h]
__global__ void t1_table(const float* __restrict__ kbtt, const float* __restrict__ w1,
                         const float* __restrict__ b1, float* __restrict__ t1t) {
  int idx = blockIdx.x * 256 + threadIdx.x;  // 16384
  int d = idx >> 4, n = idx & 15;
  float acc = b1[n];
#pragma unroll
  for (int h = 0; h < 16; ++h) acc += w1[n * 32 + 16 + h] * kbtt[d * 16 + h];
  t1t[idx] = acc;
}

// ---------------------------------------------------------------------------
// K1: qkv_bf = bf16( (x_h+x_l) @ (w_h+w_l)^T )  3-term MFMA
// ---------------------------------------------------------------------------
__global__ __launch_bounds__(256, 2) void k1_qkv(const bf16* __restrict__ Ah,
                                                 const bf16* __restrict__ Al,
                                                 const bf16* __restrict__ Bh,
                                                 const bf16* __restrict__ Bl,
                                                 bf16* __restrict__ C) {
  __shared__ __align__(16) bf16 sAh[128 * LDT], sAl[128 * LDT];
  __shared__ __align__(16) bf16 sBh[128 * LDT], sBl[128 * LDT];
  const int tid = threadIdx.x;
  const int lane = tid & 63, wv = tid >> 6;
  const int wr = wv >> 1, wc = wv & 1;
  const int l15 = lane & 15, q8 = (lane >> 4) << 3, q4 = (lane >> 4) << 2;
  const int m0 = blockIdx.y * 128, n0 = blockIdx.x * 128;
  const int r0 = tid >> 3, c8 = (tid & 7) << 3;

  f32x4 acc[4][4];
#pragma unroll
  for (int t = 0; t < 4; ++t)
#pragma unroll
    for (int u = 0; u < 4; ++u)
#pragma unroll
      for (int r = 0; r < 4; ++r) acc[t][u][r] = 0.f;

  bf16x8 rAh[4], rAl[4], rBh[4], rBl[4];
#define K1_LOAD(kt)                                                   \
  {                                                                   \
    _Pragma("unroll") for (int c = 0; c < 4; ++c) {                   \
      int row = c * 32 + r0;                                          \
      rAh[c] = *(const bf16x8*)(Ah + (size_t)(m0 + row) * Dsz + (kt) + c8); \
      rAl[c] = *(const bf16x8*)(Al + (size_t)(m0 + row) * Dsz + (kt) + c8); \
      rBh[c] = *(const bf16x8*)(Bh + (size_t)(n0 + row) * Dsz + (kt) + c8); \
      rBl[c] = *(const bf16x8*)(Bl + (size_t)(n0 + row) * Dsz + (kt) + c8); \
    }                                                                 \
  }

  K1_LOAD(0)
  for (int kt = 0; kt < Dsz; kt += 64) {
    __syncthreads();
#pragma unroll
    for (int c = 0; c < 4; ++c) {
      int row = c * 32 + r0;
      *(bf16x8*)&sAh[row * LDT + c8] = rAh[c];
      *(bf16x8*)&sAl[row * LDT + c8] = rAl[c];
      *(bf16x8*)&sBh[row * LDT + c8] = rBh[c];
      *(bf16x8*)&sBl[row * LDT + c8] = rBl[c];
    }
    __syncthreads();
    if (kt + 64 < Dsz) K1_LOAD(kt + 64)
#pragma unroll
    for (int ks = 0; ks < 64; ks += 32) {
      bf16x8 fah[4], fal[4], fbh[4], fbl[4];
#pragma unroll
      for (int t = 0; t < 4; ++t) {
        int m = wr * 64 + t * 16 + l15;
        fah[t] = *(const bf16x8*)&sAh[m * LDT + ks + q8];
        fal[t] = *(const bf16x8*)&sAl[m * LDT + ks + q8];
      }
#pragma unroll
      for (int u = 0; u < 4; ++u) {
        int n = wc * 64 + u * 16 + l15;
        fbh[u] = *(const bf16x8*)&sBh[n * LDT + ks + q8];
        fbl[u] = *(const bf16x8*)&sBl[n * LDT + ks + q8];
      }
#pragma unroll
      for (int t = 0; t < 4; ++t)
#pragma unroll
        for (int u = 0; u < 4; ++u) {
          acc[t][u] = MFMA(fah[t], fbh[u], acc[t][u]);
          acc[t][u] = MFMA(fah[t], fbl[u], acc[t][u]);
          acc[t][u] = MFMA(fal[t], fbh[u], acc[t][u]);
        }
    }
  }
#pragma unroll
  for (int t = 0; t < 4; ++t)
#pragma unroll
    for (int u = 0; u < 4; ++u) {
      int col = n0 + wc * 64 + u * 16 + l15;
#pragma unroll
      for (int r = 0; r < 4; ++r) {
        int row = m0 + wr * 64 + t * 16 + q4 + r;
        C[(size_t)row * QKV3 + col] = (bf16)acc[t][u][r];
      }
    }
#undef K1_LOAD
}

// ---------------------------------------------------------------------------
// pack V transposed: v_t[b][h][d][j]
// ---------------------------------------------------------------------------
__global__ void pack_vt(const bf16* __restrict__ qkv, bf16* __restrict__ vt) {
  __shared__ __align__(16) bf16 T[64 * LDT];
  const int tid = threadIdx.x;
  const int bh = blockIdx.y, b = bh >> 4, h = bh & 15;
  const int j0 = blockIdx.x * 64;
#pragma unroll
  for (int c = 0; c < 2; ++c) {
    int lin = c * 256 + tid;
    int jr = lin >> 3, d8 = (lin & 7) << 3;
    bf16x8 v = *(const bf16x8*)(qkv + (size_t)(b * Ssz + j0 + jr) * QKV3 + 2048 + h * DHsz + d8);
#pragma unroll
    for (int e = 0; e < 8; ++e) T[(d8 + e) * LDT + jr] = v[e];
  }
  __syncthreads();
#pragma unroll
  for (int c = 0; c < 2; ++c) {
    int lin = c * 256 + tid;
    int d = lin >> 3, j8 = (lin & 7) << 3;
    bf16x8 o = *(const bf16x8*)&T[d * LDT + j8];
    *(bf16x8*)(vt + ((size_t)(b * Hn + h) * DHsz + d) * Ssz + j0 + j8) = o;
  }
}

// ---------------------------------------------------------------------------
// K2: scores_bf[h][i][j] = bf16( SCALE * Q @ K^T )
// ---------------------------------------------------------------------------
__global__ __launch_bounds__(256, 3) void k2_qk(const bf16* __restrict__ qkv,
                                                bf16* __restrict__ scores, int b) {
  __shared__ __align__(16) bf16 sA[128 * LDT], sB[128 * LDT];
  const int tid = threadIdx.x;
  const int lane = tid & 63, wv = tid >> 6;
  const int wr = wv >> 1, wc = wv & 1;
  const int l15 = lane & 15, q8 = (lane >> 4) << 3, q4 = (lane >> 4) << 2;
  const int h = blockIdx.z, i0 = blockIdx.y * 128, j0 = blockIdx.x * 128;
  const bf16* Ab = qkv + (size_t)b * Ssz * QKV3 + h * DHsz;
  const bf16* Bb = Ab + Ssz;
  const int r0 = tid >> 3, c8 = (tid & 7) << 3;
#pragma unroll
  for (int c = 0; c < 4; ++c) {
    int row = c * 32 + r0;
    *(bf16x8*)&sA[row * LDT + c8] = *(const bf16x8*)(Ab + (size_t)(i0 + row) * QKV3 + c8);
    *(bf16x8*)&sB[row * LDT + c8] = *(const bf16x8*)(Bb + (size_t)(j0 + row) * QKV3 + c8);
  }
  __syncthreads();
  f32x4 acc[4][4];
#pragma unroll
  for (int t = 0; t < 4; ++t)
#pragma unroll
    for (int u = 0; u < 4; ++u)
#pragma unroll
      for (int r = 0; r < 4; ++r) acc[t][u][r] = 0.f;
#pragma unroll
  for (int ks = 0; ks < 64; ks += 32) {
    bf16x8 fa[4], fb[4];
#pragma unroll
    for (int t = 0; t < 4; ++t) fa[t] = *(const bf16x8*)&sA[(wr * 64 + t * 16 + l15) * LDT + ks + q8];
#pragma unroll
    for (int u = 0; u < 4; ++u) fb[u] = *(const bf16x8*)&sB[(wc * 64 + u * 16 + l15) * LDT + ks + q8];
#pragma unroll
    for (int t = 0; t < 4; ++t)
#pragma unroll
      for (int u = 0; u < 4; ++u) acc[t][u] = MFMA(fa[t], fb[u], acc[t][u]);
  }
#pragma unroll
  for (int t = 0; t < 4; ++t)
#pragma unroll
    for (int u = 0; u < 4; ++u) {
      int col = j0 + wc * 64 + u * 16 + l15;
#pragma unroll
      for (int r = 0; r < 4; ++r) {
        int row = i0 + wr * 64 + t * 16 + q4 + r;
        scores[((size_t)h * Ssz + row) * Ssz + col] = (bf16)(acc[t][u][r] * SCALE);
      }
    }
}

// ---------------------------------------------------------------------------
// K3: DAPE MLP via packed-k MFMA + kerple + UNNORMALIZED exp. In-place bf16.
// Block = (chunk c of 512 j, query row i). Wave wv owns 128 j.
// Layer1: A = [score|score] dup, B = [w1h|w1l]      -> 1 mfma (C preloaded w/ t1t)
// Layer2: A = [g_hi|g_lo],  B = [w2h|w2h],[w2l|0]   -> 2 mfma
// Writes p_un = exp(logit) bf16 (no max-sub; logits bounded) + partial sums;
// normalization (1/(s0+s1)) folded into K4 epilogue.
// ---------------------------------------------------------------------------
__device__ __forceinline__ float gelu_exact(float x) {
  return 0.5f * x * (1.0f + erff(x * 0.70710678118654752f));
}

#define LGS 520  // lgt row stride (fp32): 8-bank rotate/row -> RMW 4-way

__global__ __launch_bounds__(256, 4) void dape_softmax(bf16* scores,
                                                       const float* __restrict__ t1t,
                                                       const float* __restrict__ kbtt,
                                                       const float* __restrict__ w1,
                                                       const float* __restrict__ w2,
                                                       const float* __restrict__ b2,
                                                       float* __restrict__ sums) {
  const int c = blockIdx.x;   // chunk 0/1
  const int i = blockIdx.y;   // query row
  const int tid = threadIdx.x;
  const int lane = tid & 63, wv = tid >> 6;
  const int l15 = lane & 15, q = lane >> 4;
  const int q8 = q << 3, q4 = q << 2;

  __shared__ float lgt[Hn][LGS];                 // 16*520*4 = 33280 B
  __shared__ __align__(16) bf16 hdnS[4][16][40]; // 5120 B (k: 0..15 hi, 16..31 lo)

  // ---- weight fragments (B-layout: n=l15, k=q8+e) ----
  bf16x8 w1d, w2a, w2b;
#pragma unroll
  for (int e = 0; e < 8; ++e) {
    int k = q8 + e;
    if (k < 16) {
      w1d[e] = (bf16)w1[l15 * 32 + k];
    } else {
      float w = w1[l15 * 32 + k - 16];
      w1d[e] = (bf16)(w - (float)(bf16)w);
    }
    float v2 = w2[l15 * 16 + (k & 15)];
    bf16 h2 = (bf16)v2;
    w2a[e] = h2;
    w2b[e] = (k < 16) ? (bf16)(v2 - (float)h2) : (bf16)0.f;
  }
  const float bias2 = b2[l15];

  // ---- stage this wave's 128-j slice of all 16 head rows (coalesced) ----
  const int jwc = wv * 128;  // chunk-local wave base
  const bf16* srow = scores + (size_t)i * Ssz + c * 512;
#pragma unroll
  for (int t = 0; t < 8; ++t) {
    int lin = t * 256 + lane * 4;  // 0..2047
    int h = lin >> 7, jo = lin & 127;
    bf16x4 v = *(const bf16x4*)(srow + ((size_t)h << 20) + jwc + jo);
    f32x4 f = {(float)v[0], (float)v[1], (float)v[2], (float)v[3]};
    *(f32x4*)&lgt[h][jwc + jo] = f;
  }
  // no barrier: each wave touches only its own j-columns until the exp phase

  const int k8 = (q & 1) << 3;
  for (int jt = 0; jt < 8; ++jt) {
    const int j0c = jwc + jt * 16;   // chunk-local
    const int j0g = c * 512 + j0c;   // global j
    // layer-1 A: score duplicated into both k-halves
    bf16x8 a1;
#pragma unroll
    for (int e = 0; e < 8; ++e) a1[e] = (bf16)lgt[k8 + e][j0c + l15];
    f32x4 c1;
#pragma unroll
    for (int r = 0; r < 4; ++r) {
      int j = j0g + q4 + r;
      int d = i - j; if (d < 0) d = -d;
      c1[r] = t1t[d * 16 + l15];  // bias1 + kerple folded, fp32
    }
    c1 = MFMA(a1, w1d, c1);
    // gelu, hi/lo pack into per-wave scratch
#pragma unroll
    for (int r = 0; r < 4; ++r) {
      float g = gelu_exact(c1[r]);
      bf16 gh = (bf16)g;
      hdnS[wv][q4 + r][l15] = gh;
      hdnS[wv][q4 + r][16 + l15] = (bf16)(g - (float)gh);
    }
    // layer 2
    bf16x8 a2 = *(const bf16x8*)&hdnS[wv][l15][q8];
    f32x4 c2 = {bias2, bias2, bias2, bias2};
    c2 = MFMA(a2, w2a, c2);
    c2 = MFMA(a2, w2b, c2);
    // logits RMW: lane owns h=l15, j=j0c+q4..+3
    f32x4 old = *(const f32x4*)&lgt[l15][j0c + q4];
#pragma unroll
    for (int w = 0; w < 4; ++w) {
      int j = j0g + q4 + w;
      int d = i - j; if (d < 0) d = -d;
      old[w] += kbtt[d * 16 + l15] + c2[w];
    }
    *(f32x4*)&lgt[l15][j0c + q4] = old;
  }
  __syncthreads();

  // ---- exp (no max-sub) + partial sums; wave wv handles heads 4wv..4wv+3 ----
#pragma unroll
  for (int hh = 0; hh < 4; ++hh) {
    const int h = wv * 4 + hh;
    f32x4 v0 = *(const f32x4*)&lgt[h][lane * 4];
    f32x4 v1 = *(const f32x4*)&lgt[h][256 + lane * 4];
    float s = 0.f;
#pragma unroll
    for (int e = 0; e < 4; ++e) { v0[e] = __expf(v0[e]); s += v0[e]; }
#pragma unroll
    for (int e = 0; e < 4; ++e) { v1[e] = __expf(v1[e]); s += v1[e]; }
#pragma unroll
    for (int off = 32; off > 0; off >>= 1) s += __shfl_xor(s, off, 64);
    bf16* dst = scores + ((size_t)h << 20) + (size_t)i * Ssz + c * 512;
    bf16x4 p0 = {(bf16)v0[0], (bf16)v0[1], (bf16)v0[2], (bf16)v0[3]};
    bf16x4 p1 = {(bf16)v1[0], (bf16)v1[1], (bf16)v1[2], (bf16)v1[3]};
    *(bf16x4*)(dst + lane * 4) = p0;
    *(bf16x4*)(dst + 256 + lane * 4) = p1;
    if (lane == 0) sums[((i << 4) + h) * 2 + c] = s;
  }
}

// ---------------------------------------------------------------------------
// K4: aout = (P_un @ V) * (1/(s0+s1))   (via v_t), per (i-tile, h)
// ---------------------------------------------------------------------------
__global__ __launch_bounds__(256, 4) void k4_av(const bf16* __restrict__ attn,
                                                const bf16* __restrict__ vt,
                                                const float* __restrict__ sums,
                                                bf16* __restrict__ aout, int b) {
  __shared__ __align__(16) bf16 sA[64 * LDT], sB[64 * LDT];
  const int tid = threadIdx.x;
  const int lane = tid & 63, wv = tid >> 6;
  const int wr = wv >> 1, wc = wv & 1;
  const int l15 = lane & 15, q8 = (lane >> 4) << 3, q4 = (lane >> 4) << 2;
  const int i0 = blockIdx.x * 64, h = blockIdx.y;
  const bf16* Ab = attn + ((size_t)h * Ssz + i0) * Ssz;
  const bf16* Bb = vt + (size_t)(b * Hn + h) * DHsz * Ssz;
  const int r0 = tid >> 3, c8 = (tid & 7) << 3;
  f32x4 acc[2][2];
#pragma unroll
  for (int t = 0; t < 2; ++t)
#pragma unroll
    for (int u = 0; u < 2; ++u)
#pragma unroll
      for (int r = 0; r < 4; ++r) acc[t][u][r] = 0.f;
  bf16x8 rA[2], rB[2];
#define K4_LOAD(kt)                                               \
  {                                                               \
    _Pragma("unroll") for (int c = 0; c < 2; ++c) {               \
      int row = c * 32 + r0;                                      \
      rA[c] = *(const bf16x8*)(Ab + (size_t)row * Ssz + (kt) + c8); \
      rB[c] = *(const bf16x8*)(Bb + (size_t)row * Ssz + (kt) + c8); \
    }                                                             \
  }
  K4_LOAD(0)
  for (int kt = 0; kt < Ssz; kt += 64) {
    __syncthreads();
#pragma unroll
    for (int c = 0; c < 2; ++c) {
      int row = c * 32 + r0;
      *(bf16x8*)&sA[row * LDT + c8] = rA[c];
      *(bf16x8*)&sB[row * LDT + c8] = rB[c];
    }
    __syncthreads();
    if (kt + 64 < Ssz) K4_LOAD(kt + 64)
#pragma unroll
    for (int ks = 0; ks < 64; ks += 32) {
      bf16x8 fa[2], fb[2];
#pragma unroll
      for (int t = 0; t < 2; ++t) fa[t] = *(const bf16x8*)&sA[(wr * 32 + t * 16 + l15) * LDT + ks + q8];
#pragma unroll
      for (int u = 0; u < 2; ++u) fb[u] = *(const bf16x8*)&sB[(wc * 32 + u * 16 + l15) * LDT + ks + q8];
#pragma unroll
      for (int t = 0; t < 2; ++t)
#pragma unroll
        for (int u = 0; u < 2; ++u) acc[t][u] = MFMA(fa[t], fb[u], acc[t][u]);
    }
  }
#pragma unroll
  for (int t = 0; t < 2; ++t)
#pragma unroll
    for (int r = 0; r < 4; ++r) {
      int row = i0 + wr * 32 + t * 16 + q4 + r;
      float sden = sums[((row << 4) + h) * 2] + sums[((row << 4) + h) * 2 + 1];
      float inv = 1.f / sden;
#pragma unroll
      for (int u = 0; u < 2; ++u) {
        int d = wc * 32 + u * 16 + l15;
        aout[(size_t)(b * Ssz + row) * Dsz + h * DHsz + d] = (bf16)(acc[t][u][r] * inv);
      }
    }
#undef K4_LOAD
}

// ---------------------------------------------------------------------------
// K5: out = aout_bf @ (ow_h+ow_l)^T  2-term, fp32 out
// ---------------------------------------------------------------------------
__global__ __launch_bounds__(256, 2) void k5_out(const bf16* __restrict__ A,
                                                 const bf16* __restrict__ Bh,
                                                 const bf16* __restrict__ Bl,
                                                 float* __restrict__ C) {
  __shared__ __align__(16) bf16 sA[128 * LDT], sBh[128 * LDT], sBl[128 * LDT];
  const int tid = threadIdx.x;
  const int lane = tid & 63, wv = tid >> 6;
  const int wr = wv >> 1, wc = wv & 1;
  const int l15 = lane & 15, q8 = (lane >> 4) << 3, q4 = (lane >> 4) << 2;
  const int m0 = blockIdx.y * 128, n0 = blockIdx.x * 128;
  const int r0 = tid >> 3, c8 = (tid & 7) << 3;
  f32x4 acc[4][4];
#pragma unroll
  for (int t = 0; t < 4; ++t)
#pragma unroll
    for (int u = 0; u < 4; ++u)
#pragma unroll
      for (int r = 0; r < 4; ++r) acc[t][u][r] = 0.f;
  bf16x8 rA[4], rBh[4], rBl[4];
#define K5_LOAD(kt)                                                   \
  {                                                                   \
    _Pragma("unroll") for (int c = 0; c < 4; ++c) {                   \
      int row = c * 32 + r0;                                          \
      rA[c] = *(const bf16x8*)(A + (size_t)(m0 + row) * Dsz + (kt) + c8);   \
      rBh[c] = *(const bf16x8*)(Bh + (size_t)(n0 + row) * Dsz + (kt) + c8); \
      rBl[c] = *(const bf16x8*)(Bl + (size_t)(n0 + row) * Dsz + (kt) + c8); \
    }                                                                 \
  }
  K5_LOAD(0)
  for (int kt = 0; kt < Dsz; kt += 64) {
    __syncthreads();
#pragma unroll
    for (int c = 0; c < 4; ++c) {
      int row = c * 32 + r0;
      *(bf16x8*)&sA[row * LDT + c8] = rA[c];
      *(bf16x8*)&sBh[row * LDT + c8] = rBh[c];
      *(bf16x8*)&sBl[row * LDT + c8] = rBl[c];
    }
    __syncthreads();
    if (kt + 64 < Dsz) K5_LOAD(kt + 64)
#pragma unroll
    for (int ks = 0; ks < 64; ks += 32) {
      bf16x8 fa[4], fbh[4], fbl[4];
#pragma unroll
      for (int t = 0; t < 4; ++t) fa[t] = *(const bf16x8*)&sA[(wr * 64 + t * 16 + l15) * LDT + ks + q8];
#pragma unroll
      for (int u = 0; u < 4; ++u) {
        int n = wc * 64 + u * 16 + l15;
        fbh[u] = *(const bf16x8*)&sBh[n * LDT + ks + q8];
        fbl[u] = *(const bf16x8*)&sBl[n * LDT + ks + q8];
      }
#pragma unroll
      for (int t = 0; t < 4; ++t)
#pragma unroll
        for (int u = 0; u < 4; ++u) {
          acc[t][u] = MFMA(fa[t], fbh[u], acc[t][u]);
          acc[t][u] = MFMA(fa[t], fbl[u], acc[t][u]);
        }
    }
  }
#pragma unroll
  for (int t = 0; t < 4; ++t)
#pragma unroll
    for (int u = 0; u < 4; ++u) {
      int col = n0 + wc * 64 + u * 16 + l15;
#pragma unroll
      for (int r = 0; r < 4; ++r) {
        int row = m0 + wr * 64 + t * 16 + q4 + r;
        C[(size_t)row * Dsz + col] = acc[t][u][r];
      }
    }
#undef K5_LOAD
}

// ---------------------------------------------------------------------------
extern "C" void kernel_launch(void* const* d_in, const int* in_sizes, int n_in,
                              void* d_out, int out_size, void* d_ws, size_t ws_size,
                              hipStream_t stream) {
  const float* x      = (const float*)d_in[0];
  const float* qkv_w  = (const float*)d_in[1];
  const float* out_w  = (const float*)d_in[2];
  const float* bias_p = (const float*)d_in[3];
  const float* bias_a = (const float*)d_in[4];
  const float* w1     = (const float*)d_in[5];
  const float* b1     = (const float*)d_in[6];
  const float* w2     = (const float*)d_in[7];
  const float* b2     = (const float*)d_in[8];
  float* out = (float*)d_out;

  char* ws = (char*)d_ws;
  const size_t MB = 1ull << 20;
  bf16* x_h    = (bf16*)(ws + 0 * MB);   // 4 MB
  bf16* x_l    = (bf16*)(ws + 4 * MB);   // 4 MB
  bf16* w_h    = (bf16*)(ws + 8 * MB);   // 6 MB
  bf16* w_l    = (bf16*)(ws + 14 * MB);  // 6 MB
  bf16* ow_h   = (bf16*)(ws + 20 * MB);  // 2 MB
  bf16* ow_l   = (bf16*)(ws + 22 * MB);  // 2 MB
  bf16* qkv_bf = (bf16*)(ws + 24 * MB);  // 12 MB
  bf16* v_t    = (bf16*)(ws + 36 * MB);  // 4 MB
  bf16* sc_bf  = (bf16*)(ws + 40 * MB);  // 32 MB (per-batch scores/attn, in place)
  bf16* aout   = (bf16*)(ws + 72 * MB);  // 4 MB
  float* kbtt  = (float*)(ws + 76 * MB);                  // 64 KB  [d][h]
  float* t1t   = (float*)(ws + 76 * MB + 65536);          // 64 KB  [d][n]
  float* sums  = (float*)(ws + 76 * MB + 2 * 65536);      // 128 KB [i][h][chunk]

  cast_hilo<<<2048, 256, 0, stream>>>(x, x_h, x_l, Bsz * Ssz * Dsz);
  cast_hilo<<<3072, 256, 0, stream>>>(qkv_w, w_h, w_l, QKV3 * Dsz);
  cast_hilo<<<1024, 256, 0, stream>>>(out_w, ow_h, ow_l, Dsz * Dsz);
  kb_table<<<64, 256, 0, stream>>>(bias_p, bias_a, kbtt);
  t1_table<<<64, 256, 0, stream>>>(kbtt, w1, b1, t1t);

  k1_qkv<<<dim3(QKV3 / 128, (Bsz * Ssz) / 128), 256, 0, stream>>>(x_h, x_l, w_h, w_l, qkv_bf);
  pack_vt<<<dim3(Ssz / 64, Bsz * Hn), 256, 0, stream>>>(qkv_bf, v_t);

  for (int b = 0; b < Bsz; ++b) {
    k2_qk<<<dim3(Ssz / 128, Ssz / 128, Hn), 256, 0, stream>>>(qkv_bf, sc_bf, b);
    dape_softmax<<<dim3(2, Ssz), 256, 0, stream>>>(sc_bf, t1t, kbtt, w1, w2, b2, sums);
    k4_av<<<dim3(Ssz / 64, Hn), 256, 0, stream>>>(sc_bf, v_t, sums, aout, b);
  }

  k5_out<<<dim3(Dsz / 128, (Bsz * Ssz) / 128), 256, 0, stream>>>(aout, ow_h, ow_l, out);
}

// Round 6
// 273.600 us; speedup vs baseline: 3.4807x; 1.0912x over previous
//
#include <hip/hip_runtime.h>
#include <math.h>

#define Bsz 2
#define Ssz 1024
#define Dsz 1024
#define Hn 16
#define DHsz 64
#define QKV3 3072
#define SCALE 0.125f

typedef __bf16 bf16;
typedef bf16 bf16x8 __attribute__((ext_vector_type(8)));
typedef bf16 bf16x4 __attribute__((ext_vector_type(4)));
typedef float f32x4 __attribute__((ext_vector_type(4)));

#define MFMA(a, b, c) __builtin_amdgcn_mfma_f32_16x16x32_bf16(a, b, c, 0, 0, 0)
#define LDT 72

// ---------------------------------------------------------------------------
// casts
// ---------------------------------------------------------------------------
__global__ void cast_hilo(const float* __restrict__ src, bf16* __restrict__ hi,
                          bf16* __restrict__ lo, int n) {
  int idx = (blockIdx.x * 256 + threadIdx.x) * 4;
  if (idx >= n) return;
  float4 v = *(const float4*)(src + idx);
  bf16 h0 = (bf16)v.x, h1 = (bf16)v.y, h2 = (bf16)v.z, h3 = (bf16)v.w;
  bf16x4 hv = {h0, h1, h2, h3};
  bf16x4 lv = {(bf16)(v.x - (float)h0), (bf16)(v.y - (float)h1),
               (bf16)(v.z - (float)h2), (bf16)(v.w - (float)h3)};
  *(bf16x4*)(hi + idx) = hv;
  *(bf16x4*)(lo + idx) = lv;
}

__global__ void cast_hi(const float* __restrict__ src, bf16* __restrict__ hi, int n) {
  int idx = (blockIdx.x * 256 + threadIdx.x) * 4;
  if (idx >= n) return;
  float4 v = *(const float4*)(src + idx);
  bf16x4 hv = {(bf16)v.x, (bf16)v.y, (bf16)v.z, (bf16)v.w};
  *(bf16x4*)(hi + idx) = hv;
}

// kbtt[d][h] = -clip(p_h)*log1p(clip(a_h)*d)   (transposed: h contiguous)
__global__ void kb_table(const float* __restrict__ bias_p, const float* __restrict__ bias_a,
                         float* __restrict__ kbtt) {
  int idx = blockIdx.x * 256 + threadIdx.x;  // 16384
  int d = idx >> 4, h = idx & 15;
  float p = fmaxf(bias_p[h], 0.01f), a = fmaxf(bias_a[h], 0.01f);
  kbtt[idx] = -p * log1pf(a * (float)d);
}

// t1t[d][n] = b1[n] + sum_h w1[n][16+h] * kbtt[d][h]
__global__ void t1_table(const float* __restrict__ kbtt, const float* __restrict__ w1,
                         const float* __restrict__ b1, float* __restrict__ t1t) {
  int idx = blockIdx.x * 256 + threadIdx.x;  // 16384
  int d = idx >> 4, n = idx & 15;
  float acc = b1[n];
#pragma unroll
  for (int h = 0; h < 16; ++h) acc += w1[n * 32 + 16 + h] * kbtt[d * 16 + h];
  t1t[idx] = acc;
}

// ---------------------------------------------------------------------------
// K1: qkv_bf = bf16( x_h @ (w_h+w_l)^T )  2-term MFMA, tile 128x96 -> 512 blocks
// ---------------------------------------------------------------------------
__global__ __launch_bounds__(256, 2) void k1_qkv(const bf16* __restrict__ A,
                                                 const bf16* __restrict__ Bh,
                                                 const bf16* __restrict__ Bl,
                                                 bf16* __restrict__ C) {
  __shared__ __align__(16) bf16 sA[128 * LDT];
  __shared__ __align__(16) bf16 sBh[96 * LDT], sBl[96 * LDT];
  const int tid = threadIdx.x;
  const int lane = tid & 63, wv = tid >> 6;
  const int wr = wv >> 1, wc = wv & 1;
  const int l15 = lane & 15, q8 = (lane >> 4) << 3, q4 = (lane >> 4) << 2;
  const int m0 = blockIdx.y * 128, n0 = blockIdx.x * 96;
  const int r0 = tid >> 3, c8 = (tid & 7) << 3;

  f32x4 acc[4][3];
#pragma unroll
  for (int t = 0; t < 4; ++t)
#pragma unroll
    for (int u = 0; u < 3; ++u)
#pragma unroll
      for (int r = 0; r < 4; ++r) acc[t][u][r] = 0.f;

  bf16x8 rA[4], rBh[3], rBl[3];
#define K1_LOAD(kt)                                                         \
  {                                                                         \
    _Pragma("unroll") for (int c = 0; c < 4; ++c)                           \
      rA[c] = *(const bf16x8*)(A + (size_t)(m0 + c * 32 + r0) * Dsz + (kt) + c8);  \
    _Pragma("unroll") for (int c = 0; c < 3; ++c) {                         \
      rBh[c] = *(const bf16x8*)(Bh + (size_t)(n0 + c * 32 + r0) * Dsz + (kt) + c8); \
      rBl[c] = *(const bf16x8*)(Bl + (size_t)(n0 + c * 32 + r0) * Dsz + (kt) + c8); \
    }                                                                       \
  }

  K1_LOAD(0)
  for (int kt = 0; kt < Dsz; kt += 64) {
    __syncthreads();
#pragma unroll
    for (int c = 0; c < 4; ++c) *(bf16x8*)&sA[(c * 32 + r0) * LDT + c8] = rA[c];
#pragma unroll
    for (int c = 0; c < 3; ++c) {
      *(bf16x8*)&sBh[(c * 32 + r0) * LDT + c8] = rBh[c];
      *(bf16x8*)&sBl[(c * 32 + r0) * LDT + c8] = rBl[c];
    }
    __syncthreads();
    if (kt + 64 < Dsz) K1_LOAD(kt + 64)
#pragma unroll
    for (int ks = 0; ks < 64; ks += 32) {
      bf16x8 fa[4], fbh[3], fbl[3];
#pragma unroll
      for (int t = 0; t < 4; ++t)
        fa[t] = *(const bf16x8*)&sA[(wr * 64 + t * 16 + l15) * LDT + ks + q8];
#pragma unroll
      for (int u = 0; u < 3; ++u) {
        int n = wc * 48 + u * 16 + l15;
        fbh[u] = *(const bf16x8*)&sBh[n * LDT + ks + q8];
        fbl[u] = *(const bf16x8*)&sBl[n * LDT + ks + q8];
      }
#pragma unroll
      for (int t = 0; t < 4; ++t)
#pragma unroll
        for (int u = 0; u < 3; ++u) {
          acc[t][u] = MFMA(fa[t], fbh[u], acc[t][u]);
          acc[t][u] = MFMA(fa[t], fbl[u], acc[t][u]);
        }
    }
  }
#pragma unroll
  for (int t = 0; t < 4; ++t)
#pragma unroll
    for (int u = 0; u < 3; ++u) {
      int col = n0 + wc * 48 + u * 16 + l15;
#pragma unroll
      for (int r = 0; r < 4; ++r) {
        int row = m0 + wr * 64 + t * 16 + q4 + r;
        C[(size_t)row * QKV3 + col] = (bf16)acc[t][u][r];
      }
    }
#undef K1_LOAD
}

// ---------------------------------------------------------------------------
// pack V transposed: v_t[b][h][d][j]
// ---------------------------------------------------------------------------
__global__ void pack_vt(const bf16* __restrict__ qkv, bf16* __restrict__ vt) {
  __shared__ __align__(16) bf16 T[64 * LDT];
  const int tid = threadIdx.x;
  const int bh = blockIdx.y, b = bh >> 4, h = bh & 15;
  const int j0 = blockIdx.x * 64;
#pragma unroll
  for (int c = 0; c < 2; ++c) {
    int lin = c * 256 + tid;
    int jr = lin >> 3, d8 = (lin & 7) << 3;
    bf16x8 v = *(const bf16x8*)(qkv + (size_t)(b * Ssz + j0 + jr) * QKV3 + 2048 + h * DHsz + d8);
#pragma unroll
    for (int e = 0; e < 8; ++e) T[(d8 + e) * LDT + jr] = v[e];
  }
  __syncthreads();
#pragma unroll
  for (int c = 0; c < 2; ++c) {
    int lin = c * 256 + tid;
    int d = lin >> 3, j8 = (lin & 7) << 3;
    bf16x8 o = *(const bf16x8*)&T[d * LDT + j8];
    *(bf16x8*)(vt + ((size_t)(b * Hn + h) * DHsz + d) * Ssz + j0 + j8) = o;
  }
}

// ---------------------------------------------------------------------------
// K2: scores_bf[h][i][j] = bf16( SCALE * Q @ K^T )
// ---------------------------------------------------------------------------
__global__ __launch_bounds__(256, 3) void k2_qk(const bf16* __restrict__ qkv,
                                                bf16* __restrict__ scores, int b) {
  __shared__ __align__(16) bf16 sA[128 * LDT], sB[128 * LDT];
  const int tid = threadIdx.x;
  const int lane = tid & 63, wv = tid >> 6;
  const int wr = wv >> 1, wc = wv & 1;
  const int l15 = lane & 15, q8 = (lane >> 4) << 3, q4 = (lane >> 4) << 2;
  const int h = blockIdx.z, i0 = blockIdx.y * 128, j0 = blockIdx.x * 128;
  const bf16* Ab = qkv + (size_t)b * Ssz * QKV3 + h * DHsz;
  const bf16* Bb = Ab + Ssz;
  const int r0 = tid >> 3, c8 = (tid & 7) << 3;
#pragma unroll
  for (int c = 0; c < 4; ++c) {
    int row = c * 32 + r0;
    *(bf16x8*)&sA[row * LDT + c8] = *(const bf16x8*)(Ab + (size_t)(i0 + row) * QKV3 + c8);
    *(bf16x8*)&sB[row * LDT + c8] = *(const bf16x8*)(Bb + (size_t)(j0 + row) * QKV3 + c8);
  }
  __syncthreads();
  f32x4 acc[4][4];
#pragma unroll
  for (int t = 0; t < 4; ++t)
#pragma unroll
    for (int u = 0; u < 4; ++u)
#pragma unroll
      for (int r = 0; r < 4; ++r) acc[t][u][r] = 0.f;
#pragma unroll
  for (int ks = 0; ks < 64; ks += 32) {
    bf16x8 fa[4], fb[4];
#pragma unroll
    for (int t = 0; t < 4; ++t) fa[t] = *(const bf16x8*)&sA[(wr * 64 + t * 16 + l15) * LDT + ks + q8];
#pragma unroll
    for (int u = 0; u < 4; ++u) fb[u] = *(const bf16x8*)&sB[(wc * 64 + u * 16 + l15) * LDT + ks + q8];
#pragma unroll
    for (int t = 0; t < 4; ++t)
#pragma unroll
      for (int u = 0; u < 4; ++u) acc[t][u] = MFMA(fa[t], fb[u], acc[t][u]);
  }
#pragma unroll
  for (int t = 0; t < 4; ++t)
#pragma unroll
    for (int u = 0; u < 4; ++u) {
      int col = j0 + wc * 64 + u * 16 + l15;
#pragma unroll
      for (int r = 0; r < 4; ++r) {
        int row = i0 + wr * 64 + t * 16 + q4 + r;
        scores[((size_t)h * Ssz + row) * Ssz + col] = (bf16)(acc[t][u][r] * SCALE);
      }
    }
}

// ---------------------------------------------------------------------------
// K3: DAPE MLP via packed-k MFMA + kerple + UNNORMALIZED exp. In-place bf16.
// ---------------------------------------------------------------------------
__device__ __forceinline__ float gelu_exact(float x) {
  return 0.5f * x * (1.0f + erff(x * 0.70710678118654752f));
}

#define LGS 520

__global__ __launch_bounds__(256, 4) void dape_softmax(bf16* scores,
                                                       const float* __restrict__ t1t,
                                                       const float* __restrict__ kbtt,
                                                       const float* __restrict__ w1,
                                                       const float* __restrict__ w2,
                                                       const float* __restrict__ b2,
                                                       float* __restrict__ sums) {
  const int c = blockIdx.x;   // chunk 0/1
  const int i = blockIdx.y;   // query row
  const int tid = threadIdx.x;
  const int lane = tid & 63, wv = tid >> 6;
  const int l15 = lane & 15, q = lane >> 4;
  const int q8 = q << 3, q4 = q << 2;

  __shared__ float lgt[Hn][LGS];                 // 33280 B
  __shared__ __align__(16) bf16 hdnS[4][16][40]; // 5120 B

  bf16x8 w1d, w2a, w2b;
#pragma unroll
  for (int e = 0; e < 8; ++e) {
    int k = q8 + e;
    if (k < 16) {
      w1d[e] = (bf16)w1[l15 * 32 + k];
    } else {
      float w = w1[l15 * 32 + k - 16];
      w1d[e] = (bf16)(w - (float)(bf16)w);
    }
    float v2 = w2[l15 * 16 + (k & 15)];
    bf16 h2 = (bf16)v2;
    w2a[e] = h2;
    w2b[e] = (k < 16) ? (bf16)(v2 - (float)h2) : (bf16)0.f;
  }
  const float bias2 = b2[l15];

  const int jwc = wv * 128;
  const bf16* srow = scores + (size_t)i * Ssz + c * 512;
#pragma unroll
  for (int t = 0; t < 8; ++t) {
    int lin = t * 256 + lane * 4;
    int h = lin >> 7, jo = lin & 127;
    bf16x4 v = *(const bf16x4*)(srow + ((size_t)h << 20) + jwc + jo);
    f32x4 f = {(float)v[0], (float)v[1], (float)v[2], (float)v[3]};
    *(f32x4*)&lgt[h][jwc + jo] = f;
  }

  const int k8 = (q & 1) << 3;
  for (int jt = 0; jt < 8; ++jt) {
    const int j0c = jwc + jt * 16;
    const int j0g = c * 512 + j0c;
    bf16x8 a1;
#pragma unroll
    for (int e = 0; e < 8; ++e) a1[e] = (bf16)lgt[k8 + e][j0c + l15];
    f32x4 c1;
#pragma unroll
    for (int r = 0; r < 4; ++r) {
      int j = j0g + q4 + r;
      int d = i - j; if (d < 0) d = -d;
      c1[r] = t1t[d * 16 + l15];
    }
    c1 = MFMA(a1, w1d, c1);
#pragma unroll
    for (int r = 0; r < 4; ++r) {
      float g = gelu_exact(c1[r]);
      bf16 gh = (bf16)g;
      hdnS[wv][q4 + r][l15] = gh;
      hdnS[wv][q4 + r][16 + l15] = (bf16)(g - (float)gh);
    }
    bf16x8 a2 = *(const bf16x8*)&hdnS[wv][l15][q8];
    f32x4 c2 = {bias2, bias2, bias2, bias2};
    c2 = MFMA(a2, w2a, c2);
    c2 = MFMA(a2, w2b, c2);
    f32x4 old = *(const f32x4*)&lgt[l15][j0c + q4];
#pragma unroll
    for (int w = 0; w < 4; ++w) {
      int j = j0g + q4 + w;
      int d = i - j; if (d < 0) d = -d;
      old[w] += kbtt[d * 16 + l15] + c2[w];
    }
    *(f32x4*)&lgt[l15][j0c + q4] = old;
  }
  __syncthreads();

#pragma unroll
  for (int hh = 0; hh < 4; ++hh) {
    const int h = wv * 4 + hh;
    f32x4 v0 = *(const f32x4*)&lgt[h][lane * 4];
    f32x4 v1 = *(const f32x4*)&lgt[h][256 + lane * 4];
    float s = 0.f;
#pragma unroll
    for (int e = 0; e < 4; ++e) { v0[e] = __expf(v0[e]); s += v0[e]; }
#pragma unroll
    for (int e = 0; e < 4; ++e) { v1[e] = __expf(v1[e]); s += v1[e]; }
#pragma unroll
    for (int off = 32; off > 0; off >>= 1) s += __shfl_xor(s, off, 64);
    bf16* dst = scores + ((size_t)h << 20) + (size_t)i * Ssz + c * 512;
    bf16x4 p0 = {(bf16)v0[0], (bf16)v0[1], (bf16)v0[2], (bf16)v0[3]};
    bf16x4 p1 = {(bf16)v1[0], (bf16)v1[1], (bf16)v1[2], (bf16)v1[3]};
    *(bf16x4*)(dst + lane * 4) = p0;
    *(bf16x4*)(dst + 256 + lane * 4) = p1;
    if (lane == 0) sums[((i << 4) + h) * 2 + c] = s;
  }
}

// ---------------------------------------------------------------------------
// K4: aout = (P_un @ V) * (1/(s0+s1))   (via v_t), per (i-tile, h)
// ---------------------------------------------------------------------------
__global__ __launch_bounds__(256, 4) void k4_av(const bf16* __restrict__ attn,
                                                const bf16* __restrict__ vt,
                                                const float* __restrict__ sums,
                                                bf16* __restrict__ aout, int b) {
  __shared__ __align__(16) bf16 sA[64 * LDT], sB[64 * LDT];
  const int tid = threadIdx.x;
  const int lane = tid & 63, wv = tid >> 6;
  const int wr = wv >> 1, wc = wv & 1;
  const int l15 = lane & 15, q8 = (lane >> 4) << 3, q4 = (lane >> 4) << 2;
  const int i0 = blockIdx.x * 64, h = blockIdx.y;
  const bf16* Ab = attn + ((size_t)h * Ssz + i0) * Ssz;
  const bf16* Bb = vt + (size_t)(b * Hn + h) * DHsz * Ssz;
  const int r0 = tid >> 3, c8 = (tid & 7) << 3;
  f32x4 acc[2][2];
#pragma unroll
  for (int t = 0; t < 2; ++t)
#pragma unroll
    for (int u = 0; u < 2; ++u)
#pragma unroll
      for (int r = 0; r < 4; ++r) acc[t][u][r] = 0.f;
  bf16x8 rA[2], rB[2];
#define K4_LOAD(kt)                                               \
  {                                                               \
    _Pragma("unroll") for (int c = 0; c < 2; ++c) {               \
      int row = c * 32 + r0;                                      \
      rA[c] = *(const bf16x8*)(Ab + (size_t)row * Ssz + (kt) + c8); \
      rB[c] = *(const bf16x8*)(Bb + (size_t)row * Ssz + (kt) + c8); \
    }                                                             \
  }
  K4_LOAD(0)
  for (int kt = 0; kt < Ssz; kt += 64) {
    __syncthreads();
#pragma unroll
    for (int c = 0; c < 2; ++c) {
      int row = c * 32 + r0;
      *(bf16x8*)&sA[row * LDT + c8] = rA[c];
      *(bf16x8*)&sB[row * LDT + c8] = rB[c];
    }
    __syncthreads();
    if (kt + 64 < Ssz) K4_LOAD(kt + 64)
#pragma unroll
    for (int ks = 0; ks < 64; ks += 32) {
      bf16x8 fa[2], fb[2];
#pragma unroll
      for (int t = 0; t < 2; ++t) fa[t] = *(const bf16x8*)&sA[(wr * 32 + t * 16 + l15) * LDT + ks + q8];
#pragma unroll
      for (int u = 0; u < 2; ++u) fb[u] = *(const bf16x8*)&sB[(wc * 32 + u * 16 + l15) * LDT + ks + q8];
#pragma unroll
      for (int t = 0; t < 2; ++t)
#pragma unroll
        for (int u = 0; u < 2; ++u) acc[t][u] = MFMA(fa[t], fb[u], acc[t][u]);
    }
  }
#pragma unroll
  for (int t = 0; t < 2; ++t)
#pragma unroll
    for (int r = 0; r < 4; ++r) {
      int row = i0 + wr * 32 + t * 16 + q4 + r;
      float sden = sums[((row << 4) + h) * 2] + sums[((row << 4) + h) * 2 + 1];
      float inv = 1.f / sden;
#pragma unroll
      for (int u = 0; u < 2; ++u) {
        int d = wc * 32 + u * 16 + l15;
        aout[(size_t)(b * Ssz + row) * Dsz + h * DHsz + d] = (bf16)(acc[t][u][r] * inv);
      }
    }
#undef K4_LOAD
}

// ---------------------------------------------------------------------------
// K5: out = aout_bf @ (ow_h+ow_l)^T  2-term, fp32 out, tile 64x64 -> 512 blocks
// ---------------------------------------------------------------------------
__global__ __launch_bounds__(256, 3) void k5_out(const bf16* __restrict__ A,
                                                 const bf16* __restrict__ Bh,
                                                 const bf16* __restrict__ Bl,
                                                 float* __restrict__ C) {
  __shared__ __align__(16) bf16 sA[64 * LDT], sBh[64 * LDT], sBl[64 * LDT];
  const int tid = threadIdx.x;
  const int lane = tid & 63, wv = tid >> 6;
  const int wr = wv >> 1, wc = wv & 1;
  const int l15 = lane & 15, q8 = (lane >> 4) << 3, q4 = (lane >> 4) << 2;
  const int m0 = blockIdx.y * 64, n0 = blockIdx.x * 64;
  const int r0 = tid >> 3, c8 = (tid & 7) << 3;
  f32x4 acc[2][2];
#pragma unroll
  for (int t = 0; t < 2; ++t)
#pragma unroll
    for (int u = 0; u < 2; ++u)
#pragma unroll
      for (int r = 0; r < 4; ++r) acc[t][u][r] = 0.f;
  bf16x8 rA[2], rBh[2], rBl[2];
#define K5_LOAD(kt)                                                       \
  {                                                                       \
    _Pragma("unroll") for (int c = 0; c < 2; ++c) {                       \
      int row = c * 32 + r0;                                              \
      rA[c] = *(const bf16x8*)(A + (size_t)(m0 + row) * Dsz + (kt) + c8);   \
      rBh[c] = *(const bf16x8*)(Bh + (size_t)(n0 + row) * Dsz + (kt) + c8); \
      rBl[c] = *(const bf16x8*)(Bl + (size_t)(n0 + row) * Dsz + (kt) + c8); \
    }                                                                     \
  }
  K5_LOAD(0)
  for (int kt = 0; kt < Dsz; kt += 64) {
    __syncthreads();
#pragma unroll
    for (int c = 0; c < 2; ++c) {
      int row = c * 32 + r0;
      *(bf16x8*)&sA[row * LDT + c8] = rA[c];
      *(bf16x8*)&sBh[row * LDT + c8] = rBh[c];
      *(bf16x8*)&sBl[row * LDT + c8] = rBl[c];
    }
    __syncthreads();
    if (kt + 64 < Dsz) K5_LOAD(kt + 64)
#pragma unroll
    for (int ks = 0; ks < 64; ks += 32) {
      bf16x8 fa[2], fbh[2], fbl[2];
#pragma unroll
      for (int t = 0; t < 2; ++t) fa[t] = *(const bf16x8*)&sA[(wr * 32 + t * 16 + l15) * LDT + ks + q8];
#pragma unroll
      for (int u = 0; u < 2; ++u) {
        int n = wc * 32 + u * 16 + l15;
        fbh[u] = *(const bf16x8*)&sBh[n * LDT + ks + q8];
        fbl[u] = *(const bf16x8*)&sBl[n * LDT + ks + q8];
      }
#pragma unroll
      for (int t = 0; t < 2; ++t)
#pragma unroll
        for (int u = 0; u < 2; ++u) {
          acc[t][u] = MFMA(fa[t], fbh[u], acc[t][u]);
          acc[t][u] = MFMA(fa[t], fbl[u], acc[t][u]);
        }
    }
  }
#pragma unroll
  for (int t = 0; t < 2; ++t)
#pragma unroll
    for (int u = 0; u < 2; ++u) {
      int col = n0 + wc * 32 + u * 16 + l15;
#pragma unroll
      for (int r = 0; r < 4; ++r) {
        int row = m0 + wr * 32 + t * 16 + q4 + r;
        C[(size_t)row * Dsz + col] = acc[t][u][r];
      }
    }
#undef K5_LOAD
}

// ---------------------------------------------------------------------------
extern "C" void kernel_launch(void* const* d_in, const int* in_sizes, int n_in,
                              void* d_out, int out_size, void* d_ws, size_t ws_size,
                              hipStream_t stream) {
  const float* x      = (const float*)d_in[0];
  const float* qkv_w  = (const float*)d_in[1];
  const float* out_w  = (const float*)d_in[2];
  const float* bias_p = (const float*)d_in[3];
  const float* bias_a = (const float*)d_in[4];
  const float* w1     = (const float*)d_in[5];
  const float* b1     = (const float*)d_in[6];
  const float* w2     = (const float*)d_in[7];
  const float* b2     = (const float*)d_in[8];
  float* out = (float*)d_out;

  char* ws = (char*)d_ws;
  const size_t MB = 1ull << 20;
  bf16* x_h    = (bf16*)(ws + 0 * MB);   // 4 MB
  bf16* w_h    = (bf16*)(ws + 4 * MB);   // 6 MB
  bf16* w_l    = (bf16*)(ws + 10 * MB);  // 6 MB
  bf16* ow_h   = (bf16*)(ws + 16 * MB);  // 2 MB
  bf16* ow_l   = (bf16*)(ws + 18 * MB);  // 2 MB
  bf16* qkv_bf = (bf16*)(ws + 20 * MB);  // 12 MB
  bf16* v_t    = (bf16*)(ws + 32 * MB);  // 4 MB
  bf16* sc_bf  = (bf16*)(ws + 36 * MB);  // 32 MB (per-batch scores/attn, in place)
  bf16* aout   = (bf16*)(ws + 68 * MB);  // 4 MB
  float* kbtt  = (float*)(ws + 72 * MB);                  // 64 KB
  float* t1t   = (float*)(ws + 72 * MB + 65536);          // 64 KB
  float* sums  = (float*)(ws + 72 * MB + 2 * 65536);      // 128 KB

  cast_hi<<<2048, 256, 0, stream>>>(x, x_h, Bsz * Ssz * Dsz);
  cast_hilo<<<3072, 256, 0, stream>>>(qkv_w, w_h, w_l, QKV3 * Dsz);
  cast_hilo<<<1024, 256, 0, stream>>>(out_w, ow_h, ow_l, Dsz * Dsz);
  kb_table<<<64, 256, 0, stream>>>(bias_p, bias_a, kbtt);
  t1_table<<<64, 256, 0, stream>>>(kbtt, w1, b1, t1t);

  // K1: 128x96 tiles -> 32x16 = 512 blocks (2/CU, balanced)
  k1_qkv<<<dim3(QKV3 / 96, (Bsz * Ssz) / 128), 256, 0, stream>>>(x_h, w_h, w_l, qkv_bf);
  pack_vt<<<dim3(Ssz / 64, Bsz * Hn), 256, 0, stream>>>(qkv_bf, v_t);

  for (int b = 0; b < Bsz; ++b) {
    k2_qk<<<dim3(Ssz / 128, Ssz / 128, Hn), 256, 0, stream>>>(qkv_bf, sc_bf, b);
    dape_softmax<<<dim3(2, Ssz), 256, 0, stream>>>(sc_bf, t1t, kbtt, w1, w2, b2, sums);
    k4_av<<<dim3(Ssz / 64, Hn), 256, 0, stream>>>(sc_bf, v_t, sums, aout, b);
  }

  // K5: 64x64 tiles -> 16x32 = 512 blocks
  k5_out<<<dim3(Dsz / 64, (Bsz * Ssz) / 64), 256, 0, stream>>>(aout, ow_h, ow_l, out);
}

// Round 7
// 256.322 us; speedup vs baseline: 3.7153x; 1.0674x over previous
//
#include <hip/hip_runtime.h>
#include <math.h>

#define Bsz 2
#define Ssz 1024
#define Dsz 1024
#define Hn 16
#define DHsz 64
#define QKV3 3072
#define SCALE 0.125f

typedef __bf16 bf16;
typedef bf16 bf16x8 __attribute__((ext_vector_type(8)));
typedef bf16 bf16x4 __attribute__((ext_vector_type(4)));
typedef float f32x4 __attribute__((ext_vector_type(4)));

#define MFMA(a, b, c) __builtin_amdgcn_mfma_f32_16x16x32_bf16(a, b, c, 0, 0, 0)
#define LDT 72

// ---------------------------------------------------------------------------
// casts
// ---------------------------------------------------------------------------
__global__ void cast_hilo(const float* __restrict__ src, bf16* __restrict__ hi,
                          bf16* __restrict__ lo, int n) {
  int idx = (blockIdx.x * 256 + threadIdx.x) * 4;
  if (idx >= n) return;
  float4 v = *(const float4*)(src + idx);
  bf16 h0 = (bf16)v.x, h1 = (bf16)v.y, h2 = (bf16)v.z, h3 = (bf16)v.w;
  bf16x4 hv = {h0, h1, h2, h3};
  bf16x4 lv = {(bf16)(v.x - (float)h0), (bf16)(v.y - (float)h1),
               (bf16)(v.z - (float)h2), (bf16)(v.w - (float)h3)};
  *(bf16x4*)(hi + idx) = hv;
  *(bf16x4*)(lo + idx) = lv;
}

__global__ void cast_hi(const float* __restrict__ src, bf16* __restrict__ hi, int n) {
  int idx = (blockIdx.x * 256 + threadIdx.x) * 4;
  if (idx >= n) return;
  float4 v = *(const float4*)(src + idx);
  bf16x4 hv = {(bf16)v.x, (bf16)v.y, (bf16)v.z, (bf16)v.w};
  *(bf16x4*)(hi + idx) = hv;
}

// kbtt[d][h] = -clip(p_h)*log1p(clip(a_h)*d)   (transposed: h contiguous)
__global__ void kb_table(const float* __restrict__ bias_p, const float* __restrict__ bias_a,
                         float* __restrict__ kbtt) {
  int idx = blockIdx.x * 256 + threadIdx.x;  // 16384
  int d = idx >> 4, h = idx & 15;
  float p = fmaxf(bias_p[h], 0.01f), a = fmaxf(bias_a[h], 0.01f);
  kbtt[idx] = -p * log1pf(a * (float)d);
}

// t1t[d][n] = b1[n] + sum_h w1[n][16+h] * kbtt[d][h]
__global__ void t1_table(const float* __restrict__ kbtt, const float* __restrict__ w1,
                         const float* __restrict__ b1, float* __restrict__ t1t) {
  int idx = blockIdx.x * 256 + threadIdx.x;  // 16384
  int d = idx >> 4, n = idx & 15;
  float acc = b1[n];
#pragma unroll
  for (int h = 0; h < 16; ++h) acc += w1[n * 32 + 16 + h] * kbtt[d * 16 + h];
  t1t[idx] = acc;
}

// ---------------------------------------------------------------------------
// K1: qkv_bf = bf16( x_h @ (w_h+w_l)^T )  2-term MFMA, tile 128x96 -> 512 blocks
// ---------------------------------------------------------------------------
__global__ __launch_bounds__(256, 2) void k1_qkv(const bf16* __restrict__ A,
                                                 const bf16* __restrict__ Bh,
                                                 const bf16* __restrict__ Bl,
                                                 bf16* __restrict__ C) {
  __shared__ __align__(16) bf16 sA[128 * LDT];
  __shared__ __align__(16) bf16 sBh[96 * LDT], sBl[96 * LDT];
  const int tid = threadIdx.x;
  const int lane = tid & 63, wv = tid >> 6;
  const int wr = wv >> 1, wc = wv & 1;
  const int l15 = lane & 15, q8 = (lane >> 4) << 3, q4 = (lane >> 4) << 2;
  const int m0 = blockIdx.y * 128, n0 = blockIdx.x * 96;
  const int r0 = tid >> 3, c8 = (tid & 7) << 3;

  f32x4 acc[4][3];
#pragma unroll
  for (int t = 0; t < 4; ++t)
#pragma unroll
    for (int u = 0; u < 3; ++u)
#pragma unroll
      for (int r = 0; r < 4; ++r) acc[t][u][r] = 0.f;

  bf16x8 rA[4], rBh[3], rBl[3];
#define K1_LOAD(kt)                                                         \
  {                                                                         \
    _Pragma("unroll") for (int c = 0; c < 4; ++c)                           \
      rA[c] = *(const bf16x8*)(A + (size_t)(m0 + c * 32 + r0) * Dsz + (kt) + c8);  \
    _Pragma("unroll") for (int c = 0; c < 3; ++c) {                         \
      rBh[c] = *(const bf16x8*)(Bh + (size_t)(n0 + c * 32 + r0) * Dsz + (kt) + c8); \
      rBl[c] = *(const bf16x8*)(Bl + (size_t)(n0 + c * 32 + r0) * Dsz + (kt) + c8); \
    }                                                                       \
  }

  K1_LOAD(0)
  for (int kt = 0; kt < Dsz; kt += 64) {
    __syncthreads();
#pragma unroll
    for (int c = 0; c < 4; ++c) *(bf16x8*)&sA[(c * 32 + r0) * LDT + c8] = rA[c];
#pragma unroll
    for (int c = 0; c < 3; ++c) {
      *(bf16x8*)&sBh[(c * 32 + r0) * LDT + c8] = rBh[c];
      *(bf16x8*)&sBl[(c * 32 + r0) * LDT + c8] = rBl[c];
    }
    __syncthreads();
    if (kt + 64 < Dsz) K1_LOAD(kt + 64)
#pragma unroll
    for (int ks = 0; ks < 64; ks += 32) {
      bf16x8 fa[4], fbh[3], fbl[3];
#pragma unroll
      for (int t = 0; t < 4; ++t)
        fa[t] = *(const bf16x8*)&sA[(wr * 64 + t * 16 + l15) * LDT + ks + q8];
#pragma unroll
      for (int u = 0; u < 3; ++u) {
        int n = wc * 48 + u * 16 + l15;
        fbh[u] = *(const bf16x8*)&sBh[n * LDT + ks + q8];
        fbl[u] = *(const bf16x8*)&sBl[n * LDT + ks + q8];
      }
#pragma unroll
      for (int t = 0; t < 4; ++t)
#pragma unroll
        for (int u = 0; u < 3; ++u) {
          acc[t][u] = MFMA(fa[t], fbh[u], acc[t][u]);
          acc[t][u] = MFMA(fa[t], fbl[u], acc[t][u]);
        }
    }
  }
#pragma unroll
  for (int t = 0; t < 4; ++t)
#pragma unroll
    for (int u = 0; u < 3; ++u) {
      int col = n0 + wc * 48 + u * 16 + l15;
#pragma unroll
      for (int r = 0; r < 4; ++r) {
        int row = m0 + wr * 64 + t * 16 + q4 + r;
        C[(size_t)row * QKV3 + col] = (bf16)acc[t][u][r];
      }
    }
#undef K1_LOAD
}

// ---------------------------------------------------------------------------
// pack V transposed: v_t[b][h][d][j]
// ---------------------------------------------------------------------------
__global__ void pack_vt(const bf16* __restrict__ qkv, bf16* __restrict__ vt) {
  __shared__ __align__(16) bf16 T[64 * LDT];
  const int tid = threadIdx.x;
  const int bh = blockIdx.y, b = bh >> 4, h = bh & 15;
  const int j0 = blockIdx.x * 64;
#pragma unroll
  for (int c = 0; c < 2; ++c) {
    int lin = c * 256 + tid;
    int jr = lin >> 3, d8 = (lin & 7) << 3;
    bf16x8 v = *(const bf16x8*)(qkv + (size_t)(b * Ssz + j0 + jr) * QKV3 + 2048 + h * DHsz + d8);
#pragma unroll
    for (int e = 0; e < 8; ++e) T[(d8 + e) * LDT + jr] = v[e];
  }
  __syncthreads();
#pragma unroll
  for (int c = 0; c < 2; ++c) {
    int lin = c * 256 + tid;
    int d = lin >> 3, j8 = (lin & 7) << 3;
    bf16x8 o = *(const bf16x8*)&T[d * LDT + j8];
    *(bf16x8*)(vt + ((size_t)(b * Hn + h) * DHsz + d) * Ssz + j0 + j8) = o;
  }
}

// ---------------------------------------------------------------------------
// K2: scores_bf[b][h][i][j] = bf16( SCALE * Q @ K^T )   both batches, one launch
// ---------------------------------------------------------------------------
__global__ __launch_bounds__(256, 3) void k2_qk(const bf16* __restrict__ qkv,
                                                bf16* __restrict__ scores) {
  __shared__ __align__(16) bf16 sA[128 * LDT], sB[128 * LDT];
  const int tid = threadIdx.x;
  const int lane = tid & 63, wv = tid >> 6;
  const int wr = wv >> 1, wc = wv & 1;
  const int l15 = lane & 15, q8 = (lane >> 4) << 3, q4 = (lane >> 4) << 2;
  const int z = blockIdx.z, b = z >> 4, h = z & 15;
  const int i0 = blockIdx.y * 128, j0 = blockIdx.x * 128;
  const bf16* Ab = qkv + (size_t)b * Ssz * QKV3 + h * DHsz;
  const bf16* Bb = Ab + Ssz;
  const int r0 = tid >> 3, c8 = (tid & 7) << 3;
#pragma unroll
  for (int c = 0; c < 4; ++c) {
    int row = c * 32 + r0;
    *(bf16x8*)&sA[row * LDT + c8] = *(const bf16x8*)(Ab + (size_t)(i0 + row) * QKV3 + c8);
    *(bf16x8*)&sB[row * LDT + c8] = *(const bf16x8*)(Bb + (size_t)(j0 + row) * QKV3 + c8);
  }
  __syncthreads();
  f32x4 acc[4][4];
#pragma unroll
  for (int t = 0; t < 4; ++t)
#pragma unroll
    for (int u = 0; u < 4; ++u)
#pragma unroll
      for (int r = 0; r < 4; ++r) acc[t][u][r] = 0.f;
#pragma unroll
  for (int ks = 0; ks < 64; ks += 32) {
    bf16x8 fa[4], fb[4];
#pragma unroll
    for (int t = 0; t < 4; ++t) fa[t] = *(const bf16x8*)&sA[(wr * 64 + t * 16 + l15) * LDT + ks + q8];
#pragma unroll
    for (int u = 0; u < 4; ++u) fb[u] = *(const bf16x8*)&sB[(wc * 64 + u * 16 + l15) * LDT + ks + q8];
#pragma unroll
    for (int t = 0; t < 4; ++t)
#pragma unroll
      for (int u = 0; u < 4; ++u) acc[t][u] = MFMA(fa[t], fb[u], acc[t][u]);
  }
  bf16* dstp = scores + ((size_t)(b * Hn + h) << 20);
#pragma unroll
  for (int t = 0; t < 4; ++t)
#pragma unroll
    for (int u = 0; u < 4; ++u) {
      int col = j0 + wc * 64 + u * 16 + l15;
#pragma unroll
      for (int r = 0; r < 4; ++r) {
        int row = i0 + wr * 64 + t * 16 + q4 + r;
        dstp[((size_t)row << 10) + col] = (bf16)(acc[t][u][r] * SCALE);
      }
    }
}

// ---------------------------------------------------------------------------
// K3: DAPE MLP via packed-k MFMA + kerple + UNNORMALIZED exp. In-place bf16.
// Block = (chunk c of 256 j, row i, batch b). Wave owns 64 j. One barrier.
// ---------------------------------------------------------------------------
__device__ __forceinline__ float gelu_fast(float x) {
  // 0.5x(1+erf(x/sqrt2)), erf via Abramowitz-Stegun 7.1.26 (|err|<1.5e-7)
  float z = fabsf(x) * 0.70710678118654752f;
  float t = __builtin_amdgcn_rcpf(fmaf(0.3275911f, z, 1.0f));
  float poly = t * fmaf(t, fmaf(t, fmaf(t, fmaf(t, 1.061405429f, -1.453152027f),
                                        1.421413741f), -0.284496736f), 0.254829592f);
  float erfa = 1.0f - poly * __expf(-z * z);
  float erfs = copysignf(erfa, x);
  return 0.5f * x * (1.0f + erfs);
}

#define LGS 264  // lgt row stride (fp32): 8-bank rotate/row

__global__ __launch_bounds__(256, 7) void dape_softmax(bf16* scores,
                                                       const float* __restrict__ t1t,
                                                       const float* __restrict__ kbtt,
                                                       const float* __restrict__ w1,
                                                       const float* __restrict__ w2,
                                                       const float* __restrict__ b2,
                                                       float* __restrict__ sums) {
  const int c = blockIdx.x;   // chunk 0..3 (256 j each)
  const int i = blockIdx.y;   // query row
  const int b = blockIdx.z;   // batch
  const int tid = threadIdx.x;
  const int lane = tid & 63, wv = tid >> 6;
  const int l15 = lane & 15, q = lane >> 4;
  const int q8 = q << 3, q4 = q << 2;

  __shared__ float lgt[Hn][LGS];                 // 16896 B
  __shared__ __align__(16) bf16 hdnS[4][16][40]; // 5120 B

  // ---- weight fragments (B-layout: n=l15, k=q8+e) ----
  bf16x8 w1d, w2a, w2b;
#pragma unroll
  for (int e = 0; e < 8; ++e) {
    int k = q8 + e;
    if (k < 16) {
      w1d[e] = (bf16)w1[l15 * 32 + k];
    } else {
      float w = w1[l15 * 32 + k - 16];
      w1d[e] = (bf16)(w - (float)(bf16)w);
    }
    float v2 = w2[l15 * 16 + (k & 15)];
    bf16 h2 = (bf16)v2;
    w2a[e] = h2;
    w2b[e] = (k < 16) ? (bf16)(v2 - (float)h2) : (bf16)0.f;
  }
  const float bias2 = b2[l15];

  // ---- stage this wave's 64-j slice of all 16 head rows (coalesced) ----
  const int jw = wv * 64;
  const bf16* srow = scores + ((size_t)(b * Hn) << 20) + ((size_t)i << 10) + c * 256;
#pragma unroll
  for (int t = 0; t < 4; ++t) {
    int row = t * 4 + (lane >> 4);
    int col = jw + (lane & 15) * 4;
    bf16x4 v = *(const bf16x4*)(srow + ((size_t)row << 20) + col);
    f32x4 f = {(float)v[0], (float)v[1], (float)v[2], (float)v[3]};
    *(f32x4*)&lgt[row][col] = f;
  }
  // no barrier: each wave touches only its own j-columns until the exp phase

  const int k8 = (q & 1) << 3;
  for (int jt = 0; jt < 4; ++jt) {
    const int j0c = jw + jt * 16;     // block-local j
    const int j0g = c * 256 + j0c;    // global j
    bf16x8 a1;
#pragma unroll
    for (int e = 0; e < 8; ++e) a1[e] = (bf16)lgt[k8 + e][j0c + l15];
    f32x4 c1;
#pragma unroll
    for (int r = 0; r < 4; ++r) {
      int j = j0g + q4 + r;
      int d = i - j; if (d < 0) d = -d;
      c1[r] = t1t[d * 16 + l15];
    }
    c1 = MFMA(a1, w1d, c1);
#pragma unroll
    for (int r = 0; r < 4; ++r) {
      float g = gelu_fast(c1[r]);
      bf16 gh = (bf16)g;
      hdnS[wv][q4 + r][l15] = gh;
      hdnS[wv][q4 + r][16 + l15] = (bf16)(g - (float)gh);
    }
    bf16x8 a2 = *(const bf16x8*)&hdnS[wv][l15][q8];
    f32x4 c2 = {bias2, bias2, bias2, bias2};
    c2 = MFMA(a2, w2a, c2);
    c2 = MFMA(a2, w2b, c2);
    f32x4 old = *(const f32x4*)&lgt[l15][j0c + q4];
#pragma unroll
    for (int w = 0; w < 4; ++w) {
      int j = j0g + q4 + w;
      int d = i - j; if (d < 0) d = -d;
      old[w] += kbtt[d * 16 + l15] + c2[w];
    }
    *(f32x4*)&lgt[l15][j0c + q4] = old;
  }
  __syncthreads();

  // ---- exp (no max-sub; logits bounded) + partial sums ----
#pragma unroll
  for (int hh = 0; hh < 4; ++hh) {
    const int h = wv * 4 + hh;
    f32x4 v0 = *(const f32x4*)&lgt[h][lane * 4];
    float s = 0.f;
#pragma unroll
    for (int e = 0; e < 4; ++e) { v0[e] = __expf(v0[e]); s += v0[e]; }
#pragma unroll
    for (int off = 32; off > 0; off >>= 1) s += __shfl_xor(s, off, 64);
    bf16* dst = scores + ((size_t)(b * Hn + h) << 20) + ((size_t)i << 10) + c * 256;
    bf16x4 p0 = {(bf16)v0[0], (bf16)v0[1], (bf16)v0[2], (bf16)v0[3]};
    *(bf16x4*)(dst + lane * 4) = p0;
    if (lane == 0) sums[((((b << 10) + i) << 4) + h) * 4 + c] = s;
  }
}

// ---------------------------------------------------------------------------
// K4: aout = (P_un @ V) / sum(chunks)   (via v_t), per (i-tile, h, b)
// ---------------------------------------------------------------------------
__global__ __launch_bounds__(256, 4) void k4_av(const bf16* __restrict__ attn,
                                                const bf16* __restrict__ vt,
                                                const float* __restrict__ sums,
                                                bf16* __restrict__ aout) {
  __shared__ __align__(16) bf16 sA[64 * LDT], sB[64 * LDT];
  const int tid = threadIdx.x;
  const int lane = tid & 63, wv = tid >> 6;
  const int wr = wv >> 1, wc = wv & 1;
  const int l15 = lane & 15, q8 = (lane >> 4) << 3, q4 = (lane >> 4) << 2;
  const int i0 = blockIdx.x * 64, h = blockIdx.y, b = blockIdx.z;
  const bf16* Ab = attn + ((size_t)(b * Hn + h) << 20) + ((size_t)i0 << 10);
  const bf16* Bb = vt + (size_t)(b * Hn + h) * DHsz * Ssz;
  const int r0 = tid >> 3, c8 = (tid & 7) << 3;
  f32x4 acc[2][2];
#pragma unroll
  for (int t = 0; t < 2; ++t)
#pragma unroll
    for (int u = 0; u < 2; ++u)
#pragma unroll
      for (int r = 0; r < 4; ++r) acc[t][u][r] = 0.f;
  bf16x8 rA[2], rB[2];
#define K4_LOAD(kt)                                               \
  {                                                               \
    _Pragma("unroll") for (int c = 0; c < 2; ++c) {               \
      int row = c * 32 + r0;                                      \
      rA[c] = *(const bf16x8*)(Ab + ((size_t)row << 10) + (kt) + c8); \
      rB[c] = *(const bf16x8*)(Bb + ((size_t)row << 10) + (kt) + c8); \
    }                                                             \
  }
  K4_LOAD(0)
  for (int kt = 0; kt < Ssz; kt += 64) {
    __syncthreads();
#pragma unroll
    for (int c = 0; c < 2; ++c) {
      int row = c * 32 + r0;
      *(bf16x8*)&sA[row * LDT + c8] = rA[c];
      *(bf16x8*)&sB[row * LDT + c8] = rB[c];
    }
    __syncthreads();
    if (kt + 64 < Ssz) K4_LOAD(kt + 64)
#pragma unroll
    for (int ks = 0; ks < 64; ks += 32) {
      bf16x8 fa[2], fb[2];
#pragma unroll
      for (int t = 0; t < 2; ++t) fa[t] = *(const bf16x8*)&sA[(wr * 32 + t * 16 + l15) * LDT + ks + q8];
#pragma unroll
      for (int u = 0; u < 2; ++u) fb[u] = *(const bf16x8*)&sB[(wc * 32 + u * 16 + l15) * LDT + ks + q8];
#pragma unroll
      for (int t = 0; t < 2; ++t)
#pragma unroll
        for (int u = 0; u < 2; ++u) acc[t][u] = MFMA(fa[t], fb[u], acc[t][u]);
    }
  }
#pragma unroll
  for (int t = 0; t < 2; ++t)
#pragma unroll
    for (int r = 0; r < 4; ++r) {
      int row = i0 + wr * 32 + t * 16 + q4 + r;
      f32x4 sv = *(const f32x4*)&sums[((((b << 10) + row) << 4) + h) * 4];
      float inv = 1.f / (sv[0] + sv[1] + sv[2] + sv[3]);
#pragma unroll
      for (int u = 0; u < 2; ++u) {
        int d = wc * 32 + u * 16 + l15;
        aout[(size_t)(b * Ssz + row) * Dsz + h * DHsz + d] = (bf16)(acc[t][u][r] * inv);
      }
    }
#undef K4_LOAD
}

// ---------------------------------------------------------------------------
// K5: out = aout_bf @ (ow_h+ow_l)^T  2-term, fp32 out, tile 64x64 -> 512 blocks
// ---------------------------------------------------------------------------
__global__ __launch_bounds__(256, 3) void k5_out(const bf16* __restrict__ A,
                                                 const bf16* __restrict__ Bh,
                                                 const bf16* __restrict__ Bl,
                                                 float* __restrict__ C) {
  __shared__ __align__(16) bf16 sA[64 * LDT], sBh[64 * LDT], sBl[64 * LDT];
  const int tid = threadIdx.x;
  const int lane = tid & 63, wv = tid >> 6;
  const int wr = wv >> 1, wc = wv & 1;
  const int l15 = lane & 15, q8 = (lane >> 4) << 3, q4 = (lane >> 4) << 2;
  const int m0 = blockIdx.y * 64, n0 = blockIdx.x * 64;
  const int r0 = tid >> 3, c8 = (tid & 7) << 3;
  f32x4 acc[2][2];
#pragma unroll
  for (int t = 0; t < 2; ++t)
#pragma unroll
    for (int u = 0; u < 2; ++u)
#pragma unroll
      for (int r = 0; r < 4; ++r) acc[t][u][r] = 0.f;
  bf16x8 rA[2], rBh[2], rBl[2];
#define K5_LOAD(kt)                                                       \
  {                                                                       \
    _Pragma("unroll") for (int c = 0; c < 2; ++c) {                       \
      int row = c * 32 + r0;                                              \
      rA[c] = *(const bf16x8*)(A + (size_t)(m0 + row) * Dsz + (kt) + c8);   \
      rBh[c] = *(const bf16x8*)(Bh + (size_t)(n0 + row) * Dsz + (kt) + c8); \
      rBl[c] = *(const bf16x8*)(Bl + (size_t)(n0 + row) * Dsz + (kt) + c8); \
    }                                                                     \
  }
  K5_LOAD(0)
  for (int kt = 0; kt < Dsz; kt += 64) {
    __syncthreads();
#pragma unroll
    for (int c = 0; c < 2; ++c) {
      int row = c * 32 + r0;
      *(bf16x8*)&sA[row * LDT + c8] = rA[c];
      *(bf16x8*)&sBh[row * LDT + c8] = rBh[c];
      *(bf16x8*)&sBl[row * LDT + c8] = rBl[c];
    }
    __syncthreads();
    if (kt + 64 < Dsz) K5_LOAD(kt + 64)
#pragma unroll
    for (int ks = 0; ks < 64; ks += 32) {
      bf16x8 fa[2], fbh[2], fbl[2];
#pragma unroll
      for (int t = 0; t < 2; ++t) fa[t] = *(const bf16x8*)&sA[(wr * 32 + t * 16 + l15) * LDT + ks + q8];
#pragma unroll
      for (int u = 0; u < 2; ++u) {
        int n = wc * 32 + u * 16 + l15;
        fbh[u] = *(const bf16x8*)&sBh[n * LDT + ks + q8];
        fbl[u] = *(const bf16x8*)&sBl[n * LDT + ks + q8];
      }
#pragma unroll
      for (int t = 0; t < 2; ++t)
#pragma unroll
        for (int u = 0; u < 2; ++u) {
          acc[t][u] = MFMA(fa[t], fbh[u], acc[t][u]);
          acc[t][u] = MFMA(fa[t], fbl[u], acc[t][u]);
        }
    }
  }
#pragma unroll
  for (int t = 0; t < 2; ++t)
#pragma unroll
    for (int u = 0; u < 2; ++u) {
      int col = n0 + wc * 32 + u * 16 + l15;
#pragma unroll
      for (int r = 0; r < 4; ++r) {
        int row = m0 + wr * 32 + t * 16 + q4 + r;
        C[(size_t)row * Dsz + col] = acc[t][u][r];
      }
    }
#undef K5_LOAD
}

// ---------------------------------------------------------------------------
extern "C" void kernel_launch(void* const* d_in, const int* in_sizes, int n_in,
                              void* d_out, int out_size, void* d_ws, size_t ws_size,
                              hipStream_t stream) {
  const float* x      = (const float*)d_in[0];
  const float* qkv_w  = (const float*)d_in[1];
  const float* out_w  = (const float*)d_in[2];
  const float* bias_p = (const float*)d_in[3];
  const float* bias_a = (const float*)d_in[4];
  const float* w1     = (const float*)d_in[5];
  const float* b1     = (const float*)d_in[6];
  const float* w2     = (const float*)d_in[7];
  const float* b2     = (const float*)d_in[8];
  float* out = (float*)d_out;

  // ws layout (bytes). scores (64 MB, both batches) ALIASES x_h/w_h/w_l,
  // which are dead after k1 — stream order makes this safe.
  char* ws = (char*)d_ws;
  const size_t MB = 1ull << 20;
  bf16* ow_h   = (bf16*)(ws + 0 * MB);            // 2 MB
  bf16* ow_l   = (bf16*)(ws + 2 * MB);            // 2 MB
  bf16* qkv_bf = (bf16*)(ws + 4 * MB);            // 12 MB
  bf16* v_t    = (bf16*)(ws + 16 * MB);           // 4 MB
  bf16* aout   = (bf16*)(ws + 20 * MB);           // 4 MB
  float* kbtt  = (float*)(ws + 24 * MB);          // 64 KB
  float* t1t   = (float*)(ws + 24 * MB + 65536);  // 64 KB
  float* sums  = (float*)(ws + 24 * MB + 131072); // 512 KB [b][i][h][chunk]
  bf16* x_h    = (bf16*)(ws + 25 * MB);           // 4 MB   (dead after k1)
  bf16* w_h    = (bf16*)(ws + 29 * MB);           // 6 MB   (dead after k1)
  bf16* w_l    = (bf16*)(ws + 35 * MB);           // 6 MB   (dead after k1)
  bf16* sc_bf  = (bf16*)(ws + 25 * MB);           // 64 MB, ends at 89 MB

  cast_hi<<<2048, 256, 0, stream>>>(x, x_h, Bsz * Ssz * Dsz);
  cast_hilo<<<3072, 256, 0, stream>>>(qkv_w, w_h, w_l, QKV3 * Dsz);
  cast_hilo<<<1024, 256, 0, stream>>>(out_w, ow_h, ow_l, Dsz * Dsz);
  kb_table<<<64, 256, 0, stream>>>(bias_p, bias_a, kbtt);
  t1_table<<<64, 256, 0, stream>>>(kbtt, w1, b1, t1t);

  k1_qkv<<<dim3(QKV3 / 96, (Bsz * Ssz) / 128), 256, 0, stream>>>(x_h, w_h, w_l, qkv_bf);
  pack_vt<<<dim3(Ssz / 64, Bsz * Hn), 256, 0, stream>>>(qkv_bf, v_t);

  // both batches per launch
  k2_qk<<<dim3(Ssz / 128, Ssz / 128, Bsz * Hn), 256, 0, stream>>>(qkv_bf, sc_bf);
  dape_softmax<<<dim3(4, Ssz, Bsz), 256, 0, stream>>>(sc_bf, t1t, kbtt, w1, w2, b2, sums);
  k4_av<<<dim3(Ssz / 64, Hn, Bsz), 256, 0, stream>>>(sc_bf, v_t, sums, aout);

  k5_out<<<dim3(Dsz / 64, (Bsz * Ssz) / 64), 256, 0, stream>>>(aout, ow_h, ow_l, out);
}

// Round 8
// 218.607 us; speedup vs baseline: 4.3563x; 1.1725x over previous
//
#include <hip/hip_runtime.h>
#include <math.h>

#define Bsz 2
#define Ssz 1024
#define Dsz 1024
#define Hn 16
#define DHsz 64
#define QKV3 3072
#define SCALE 0.125f

typedef __bf16 bf16;
typedef bf16 bf16x8 __attribute__((ext_vector_type(8)));
typedef bf16 bf16x4 __attribute__((ext_vector_type(4)));
typedef float f32x4 __attribute__((ext_vector_type(4)));

#define MFMA(a, b, c) __builtin_amdgcn_mfma_f32_16x16x32_bf16(a, b, c, 0, 0, 0)
#define LDT 72

// ---------------------------------------------------------------------------
// casts
// ---------------------------------------------------------------------------
__global__ void cast_hilo(const float* __restrict__ src, bf16* __restrict__ hi,
                          bf16* __restrict__ lo, int n) {
  int idx = (blockIdx.x * 256 + threadIdx.x) * 4;
  if (idx >= n) return;
  float4 v = *(const float4*)(src + idx);
  bf16 h0 = (bf16)v.x, h1 = (bf16)v.y, h2 = (bf16)v.z, h3 = (bf16)v.w;
  bf16x4 hv = {h0, h1, h2, h3};
  bf16x4 lv = {(bf16)(v.x - (float)h0), (bf16)(v.y - (float)h1),
               (bf16)(v.z - (float)h2), (bf16)(v.w - (float)h3)};
  *(bf16x4*)(hi + idx) = hv;
  *(bf16x4*)(lo + idx) = lv;
}

__global__ void cast_hi(const float* __restrict__ src, bf16* __restrict__ hi, int n) {
  int idx = (blockIdx.x * 256 + threadIdx.x) * 4;
  if (idx >= n) return;
  float4 v = *(const float4*)(src + idx);
  bf16x4 hv = {(bf16)v.x, (bf16)v.y, (bf16)v.z, (bf16)v.w};
  *(bf16x4*)(hi + idx) = hv;
}

// kbtt[d][h] = -clip(p_h)*log1p(clip(a_h)*d)   (transposed: h contiguous)
__global__ void kb_table(const float* __restrict__ bias_p, const float* __restrict__ bias_a,
                         float* __restrict__ kbtt) {
  int idx = blockIdx.x * 256 + threadIdx.x;  // 16384
  int d = idx >> 4, h = idx & 15;
  float p = fmaxf(bias_p[h], 0.01f), a = fmaxf(bias_a[h], 0.01f);
  kbtt[idx] = -p * log1pf(a * (float)d);
}

// t1t[d][n] = b1[n] + sum_h w1[n][16+h] * kbtt[d][h]
__global__ void t1_table(const float* __restrict__ kbtt, const float* __restrict__ w1,
                         const float* __restrict__ b1, float* __restrict__ t1t) {
  int idx = blockIdx.x * 256 + threadIdx.x;  // 16384
  int d = idx >> 4, n = idx & 15;
  float acc = b1[n];
#pragma unroll
  for (int h = 0; h < 16; ++h) acc += w1[n * 32 + 16 + h] * kbtt[d * 16 + h];
  t1t[idx] = acc;
}

// Precompute dape MFMA weight fragments (per-lane): wf[0..511]=w1d, wf[512..1023]=w2a
__global__ void wfrag(const float* __restrict__ w1, const float* __restrict__ w2,
                      bf16* __restrict__ wf) {
  int lane = threadIdx.x;  // 64
  int l15 = lane & 15, q8 = (lane >> 4) << 3;
  bf16x8 w1d, w2a;
#pragma unroll
  for (int e = 0; e < 8; ++e) {
    int k = q8 + e;
    if (k < 16) {
      w1d[e] = (bf16)w1[l15 * 32 + k];
    } else {
      float w = w1[l15 * 32 + k - 16];
      w1d[e] = (bf16)(w - (float)(bf16)w);
    }
    w2a[e] = (bf16)w2[l15 * 16 + (k & 15)];
  }
  *(bf16x8*)(wf + lane * 8) = w1d;
  *(bf16x8*)(wf + 512 + lane * 8) = w2a;
}

// ---------------------------------------------------------------------------
// K1: qkv_bf = bf16( x_h @ (w_h+w_l)^T )  2-term MFMA, tile 128x96 -> 512 blocks
// ---------------------------------------------------------------------------
__global__ __launch_bounds__(256, 2) void k1_qkv(const bf16* __restrict__ A,
                                                 const bf16* __restrict__ Bh,
                                                 const bf16* __restrict__ Bl,
                                                 bf16* __restrict__ C) {
  __shared__ __align__(16) bf16 sA[128 * LDT];
  __shared__ __align__(16) bf16 sBh[96 * LDT], sBl[96 * LDT];
  const int tid = threadIdx.x;
  const int lane = tid & 63, wv = tid >> 6;
  const int wr = wv >> 1, wc = wv & 1;
  const int l15 = lane & 15, q8 = (lane >> 4) << 3, q4 = (lane >> 4) << 2;
  const int m0 = blockIdx.y * 128, n0 = blockIdx.x * 96;
  const int r0 = tid >> 3, c8 = (tid & 7) << 3;

  f32x4 acc[4][3];
#pragma unroll
  for (int t = 0; t < 4; ++t)
#pragma unroll
    for (int u = 0; u < 3; ++u)
#pragma unroll
      for (int r = 0; r < 4; ++r) acc[t][u][r] = 0.f;

  bf16x8 rA[4], rBh[3], rBl[3];
#define K1_LOAD(kt)                                                         \
  {                                                                         \
    _Pragma("unroll") for (int c = 0; c < 4; ++c)                           \
      rA[c] = *(const bf16x8*)(A + (size_t)(m0 + c * 32 + r0) * Dsz + (kt) + c8);  \
    _Pragma("unroll") for (int c = 0; c < 3; ++c) {                         \
      rBh[c] = *(const bf16x8*)(Bh + (size_t)(n0 + c * 32 + r0) * Dsz + (kt) + c8); \
      rBl[c] = *(const bf16x8*)(Bl + (size_t)(n0 + c * 32 + r0) * Dsz + (kt) + c8); \
    }                                                                       \
  }

  K1_LOAD(0)
  for (int kt = 0; kt < Dsz; kt += 64) {
    __syncthreads();
#pragma unroll
    for (int c = 0; c < 4; ++c) *(bf16x8*)&sA[(c * 32 + r0) * LDT + c8] = rA[c];
#pragma unroll
    for (int c = 0; c < 3; ++c) {
      *(bf16x8*)&sBh[(c * 32 + r0) * LDT + c8] = rBh[c];
      *(bf16x8*)&sBl[(c * 32 + r0) * LDT + c8] = rBl[c];
    }
    __syncthreads();
    if (kt + 64 < Dsz) K1_LOAD(kt + 64)
#pragma unroll
    for (int ks = 0; ks < 64; ks += 32) {
      bf16x8 fa[4], fbh[3], fbl[3];
#pragma unroll
      for (int t = 0; t < 4; ++t)
        fa[t] = *(const bf16x8*)&sA[(wr * 64 + t * 16 + l15) * LDT + ks + q8];
#pragma unroll
      for (int u = 0; u < 3; ++u) {
        int n = wc * 48 + u * 16 + l15;
        fbh[u] = *(const bf16x8*)&sBh[n * LDT + ks + q8];
        fbl[u] = *(const bf16x8*)&sBl[n * LDT + ks + q8];
      }
#pragma unroll
      for (int t = 0; t < 4; ++t)
#pragma unroll
        for (int u = 0; u < 3; ++u) {
          acc[t][u] = MFMA(fa[t], fbh[u], acc[t][u]);
          acc[t][u] = MFMA(fa[t], fbl[u], acc[t][u]);
        }
    }
  }
#pragma unroll
  for (int t = 0; t < 4; ++t)
#pragma unroll
    for (int u = 0; u < 3; ++u) {
      int col = n0 + wc * 48 + u * 16 + l15;
#pragma unroll
      for (int r = 0; r < 4; ++r) {
        int row = m0 + wr * 64 + t * 16 + q4 + r;
        C[(size_t)row * QKV3 + col] = (bf16)acc[t][u][r];
      }
    }
#undef K1_LOAD
}

// ---------------------------------------------------------------------------
// pack V transposed: v_t[b][h][d][j]
// ---------------------------------------------------------------------------
__global__ void pack_vt(const bf16* __restrict__ qkv, bf16* __restrict__ vt) {
  __shared__ __align__(16) bf16 T[64 * LDT];
  const int tid = threadIdx.x;
  const int bh = blockIdx.y, b = bh >> 4, h = bh & 15;
  const int j0 = blockIdx.x * 64;
#pragma unroll
  for (int c = 0; c < 2; ++c) {
    int lin = c * 256 + tid;
    int jr = lin >> 3, d8 = (lin & 7) << 3;
    bf16x8 v = *(const bf16x8*)(qkv + (size_t)(b * Ssz + j0 + jr) * QKV3 + 2048 + h * DHsz + d8);
#pragma unroll
    for (int e = 0; e < 8; ++e) T[(d8 + e) * LDT + jr] = v[e];
  }
  __syncthreads();
#pragma unroll
  for (int c = 0; c < 2; ++c) {
    int lin = c * 256 + tid;
    int d = lin >> 3, j8 = (lin & 7) << 3;
    bf16x8 o = *(const bf16x8*)&T[d * LDT + j8];
    *(bf16x8*)(vt + ((size_t)(b * Hn + h) * DHsz + d) * Ssz + j0 + j8) = o;
  }
}

// ---------------------------------------------------------------------------
// K2: scores_bf[b][h][i][j] = bf16( SCALE * Q @ K^T )   both batches, one launch
// ---------------------------------------------------------------------------
__global__ __launch_bounds__(256, 3) void k2_qk(const bf16* __restrict__ qkv,
                                                bf16* __restrict__ scores) {
  __shared__ __align__(16) bf16 sA[128 * LDT], sB[128 * LDT];
  const int tid = threadIdx.x;
  const int lane = tid & 63, wv = tid >> 6;
  const int wr = wv >> 1, wc = wv & 1;
  const int l15 = lane & 15, q8 = (lane >> 4) << 3, q4 = (lane >> 4) << 2;
  const int z = blockIdx.z, b = z >> 4, h = z & 15;
  const int i0 = blockIdx.y * 128, j0 = blockIdx.x * 128;
  const bf16* Ab = qkv + (size_t)b * Ssz * QKV3 + h * DHsz;
  const bf16* Bb = Ab + Ssz;
  const int r0 = tid >> 3, c8 = (tid & 7) << 3;
#pragma unroll
  for (int c = 0; c < 4; ++c) {
    int row = c * 32 + r0;
    *(bf16x8*)&sA[row * LDT + c8] = *(const bf16x8*)(Ab + (size_t)(i0 + row) * QKV3 + c8);
    *(bf16x8*)&sB[row * LDT + c8] = *(const bf16x8*)(Bb + (size_t)(j0 + row) * QKV3 + c8);
  }
  __syncthreads();
  f32x4 acc[4][4];
#pragma unroll
  for (int t = 0; t < 4; ++t)
#pragma unroll
    for (int u = 0; u < 4; ++u)
#pragma unroll
      for (int r = 0; r < 4; ++r) acc[t][u][r] = 0.f;
#pragma unroll
  for (int ks = 0; ks < 64; ks += 32) {
    bf16x8 fa[4], fb[4];
#pragma unroll
    for (int t = 0; t < 4; ++t) fa[t] = *(const bf16x8*)&sA[(wr * 64 + t * 16 + l15) * LDT + ks + q8];
#pragma unroll
    for (int u = 0; u < 4; ++u) fb[u] = *(const bf16x8*)&sB[(wc * 64 + u * 16 + l15) * LDT + ks + q8];
#pragma unroll
    for (int t = 0; t < 4; ++t)
#pragma unroll
      for (int u = 0; u < 4; ++u) acc[t][u] = MFMA(fa[t], fb[u], acc[t][u]);
  }
  bf16* dstp = scores + ((size_t)(b * Hn + h) << 20);
#pragma unroll
  for (int t = 0; t < 4; ++t)
#pragma unroll
    for (int u = 0; u < 4; ++u) {
      int col = j0 + wc * 64 + u * 16 + l15;
#pragma unroll
      for (int r = 0; r < 4; ++r) {
        int row = i0 + wr * 64 + t * 16 + q4 + r;
        dstp[((size_t)row << 10) + col] = (bf16)(acc[t][u][r] * SCALE);
      }
    }
}

// ---------------------------------------------------------------------------
// K3: DAPE MLP, instruction-lean version. In-place bf16.
// Block = (chunk c of 256 j, row i, batch b). Wave owns 64 j. One barrier.
// sH: raw bf16 score stage; weights pre-fragged (wf); layer2 hi-only (2 mfma);
// logits composed in registers -> pure LDS write; unnormalized exp + sums.
// ---------------------------------------------------------------------------
__device__ __forceinline__ float gelu_fast(float x) {
  // 0.5x(1+erf(x/sqrt2)), erf via Abramowitz-Stegun 7.1.26 (|err|<1.5e-7)
  float z = fabsf(x) * 0.70710678118654752f;
  float t = __builtin_amdgcn_rcpf(fmaf(0.3275911f, z, 1.0f));
  float poly = t * fmaf(t, fmaf(t, fmaf(t, fmaf(t, 1.061405429f, -1.453152027f),
                                        1.421413741f), -0.284496736f), 0.254829592f);
  float erfa = 1.0f - poly * __expf(-z * z);
  float erfs = copysignf(erfa, x);
  return 0.5f * x * (1.0f + erfs);
}

#define SHS 264  // sH row stride (bf16)
#define LGS 264  // lgt row stride (fp32)

__global__ __launch_bounds__(256, 5) void dape_softmax(bf16* scores,
                                                       const float* __restrict__ t1t,
                                                       const float* __restrict__ kbtt,
                                                       const bf16* __restrict__ wf,
                                                       const float* __restrict__ b2,
                                                       float* __restrict__ sums) {
  const int c = blockIdx.x;   // chunk 0..3 (256 j each)
  const int i = blockIdx.y;   // query row
  const int b = blockIdx.z;   // batch
  const int tid = threadIdx.x;
  const int lane = tid & 63, wv = tid >> 6;
  const int l15 = lane & 15, q = lane >> 4;
  const int q8 = q << 3, q4 = q << 2;

  __shared__ bf16 sH[Hn][SHS];                   // 8448 B raw bf16 scores
  __shared__ float lgt[Hn][LGS];                 // 16896 B logits
  __shared__ __align__(16) bf16 hdnS[4][16][40]; // 5120 B (cols 16..31 zeroed)

  const bf16x8 w1d = *(const bf16x8*)(wf + lane * 8);
  const bf16x8 w2a = *(const bf16x8*)(wf + 512 + lane * 8);
  const float bias2 = b2[l15];

  // zero the k=16..31 pad half once (a2 upper half reads zeros)
  if (lane < 32) {
    int row = lane >> 1, col = 16 + (lane & 1) * 8;
    *(bf16x8*)&hdnS[wv][row][col] = (bf16x8){};
  }

  // ---- stage this wave's 64-j slice of all 16 head rows (raw bf16 copy) ----
  const int jw = wv * 64;
  const bf16* srow = scores + ((size_t)(b * Hn) << 20) + ((size_t)i << 10) + c * 256;
#pragma unroll
  for (int t = 0; t < 4; ++t) {
    int h = t * 4 + q;
    int col = jw + l15 * 4;
    *(bf16x4*)&sH[h][col] = *(const bf16x4*)(srow + ((size_t)h << 20) + col);
  }
  // no barrier: each wave touches only its own j-columns until the exp phase

  for (int jt = 0; jt < 4; ++jt) {
    const int j0c = jw + jt * 16;     // block-local j
    const int j0g = c * 256 + j0c;    // global j
    // layer-1 A: raw bf16 gather; k=(q8+e)&15 is the head (dup across halves)
    bf16x8 a1;
#pragma unroll
    for (int e = 0; e < 8; ++e) a1[e] = sH[(q8 + e) & 15][j0c + l15];
    f32x4 c1;
#pragma unroll
    for (int r = 0; r < 4; ++r) {
      int j = j0g + q4 + r;
      int d = i - j; if (d < 0) d = -d;
      c1[r] = t1t[d * 16 + l15];
    }
    c1 = MFMA(a1, w1d, c1);
#pragma unroll
    for (int r = 0; r < 4; ++r) hdnS[wv][q4 + r][l15] = (bf16)gelu_fast(c1[r]);
    bf16x8 a2 = *(const bf16x8*)&hdnS[wv][l15][q8];
    f32x4 c2 = {bias2, bias2, bias2, bias2};
    c2 = MFMA(a2, w2a, c2);
    // logits: score + kb + refine, pure write (lane owns h=l15, j=j0c+q4..+3)
    f32x4 lg;
#pragma unroll
    for (int r = 0; r < 4; ++r) {
      int j = j0g + q4 + r;
      int d = i - j; if (d < 0) d = -d;
      lg[r] = (float)sH[l15][j0c + q4 + r] + kbtt[d * 16 + l15] + c2[r];
    }
    *(f32x4*)&lgt[l15][j0c + q4] = lg;
  }
  __syncthreads();

  // ---- exp (no max-sub; logits bounded) + partial sums ----
#pragma unroll
  for (int hh = 0; hh < 4; ++hh) {
    const int h = wv * 4 + hh;
    f32x4 v0 = *(const f32x4*)&lgt[h][lane * 4];
    float s = 0.f;
#pragma unroll
    for (int e = 0; e < 4; ++e) { v0[e] = __expf(v0[e]); s += v0[e]; }
#pragma unroll
    for (int off = 32; off > 0; off >>= 1) s += __shfl_xor(s, off, 64);
    bf16* dst = scores + ((size_t)(b * Hn + h) << 20) + ((size_t)i << 10) + c * 256;
    bf16x4 p0 = {(bf16)v0[0], (bf16)v0[1], (bf16)v0[2], (bf16)v0[3]};
    *(bf16x4*)(dst + lane * 4) = p0;
    if (lane == 0) sums[((((b << 10) + i) << 4) + h) * 4 + c] = s;
  }
}

// ---------------------------------------------------------------------------
// K4: aout = (P_un @ V) / sum(chunks)   (via v_t), per (i-tile, h, b)
// ---------------------------------------------------------------------------
__global__ __launch_bounds__(256, 4) void k4_av(const bf16* __restrict__ attn,
                                                const bf16* __restrict__ vt,
                                                const float* __restrict__ sums,
                                                bf16* __restrict__ aout) {
  __shared__ __align__(16) bf16 sA[64 * LDT], sB[64 * LDT];
  const int tid = threadIdx.x;
  const int lane = tid & 63, wv = tid >> 6;
  const int wr = wv >> 1, wc = wv & 1;
  const int l15 = lane & 15, q8 = (lane >> 4) << 3, q4 = (lane >> 4) << 2;
  const int i0 = blockIdx.x * 64, h = blockIdx.y, b = blockIdx.z;
  const bf16* Ab = attn + ((size_t)(b * Hn + h) << 20) + ((size_t)i0 << 10);
  const bf16* Bb = vt + (size_t)(b * Hn + h) * DHsz * Ssz;
  const int r0 = tid >> 3, c8 = (tid & 7) << 3;
  f32x4 acc[2][2];
#pragma unroll
  for (int t = 0; t < 2; ++t)
#pragma unroll
    for (int u = 0; u < 2; ++u)
#pragma unroll
      for (int r = 0; r < 4; ++r) acc[t][u][r] = 0.f;
  bf16x8 rA[2], rB[2];
#define K4_LOAD(kt)                                               \
  {                                                               \
    _Pragma("unroll") for (int c = 0; c < 2; ++c) {               \
      int row = c * 32 + r0;                                      \
      rA[c] = *(const bf16x8*)(Ab + ((size_t)row << 10) + (kt) + c8); \
      rB[c] = *(const bf16x8*)(Bb + ((size_t)row << 10) + (kt) + c8); \
    }                                                             \
  }
  K4_LOAD(0)
  for (int kt = 0; kt < Ssz; kt += 64) {
    __syncthreads();
#pragma unroll
    for (int c = 0; c < 2; ++c) {
      int row = c * 32 + r0;
      *(bf16x8*)&sA[row * LDT + c8] = rA[c];
      *(bf16x8*)&sB[row * LDT + c8] = rB[c];
    }
    __syncthreads();
    if (kt + 64 < Ssz) K4_LOAD(kt + 64)
#pragma unroll
    for (int ks = 0; ks < 64; ks += 32) {
      bf16x8 fa[2], fb[2];
#pragma unroll
      for (int t = 0; t < 2; ++t) fa[t] = *(const bf16x8*)&sA[(wr * 32 + t * 16 + l15) * LDT + ks + q8];
#pragma unroll
      for (int u = 0; u < 2; ++u) fb[u] = *(const bf16x8*)&sB[(wc * 32 + u * 16 + l15) * LDT + ks + q8];
#pragma unroll
      for (int t = 0; t < 2; ++t)
#pragma unroll
        for (int u = 0; u < 2; ++u) acc[t][u] = MFMA(fa[t], fb[u], acc[t][u]);
    }
  }
#pragma unroll
  for (int t = 0; t < 2; ++t)
#pragma unroll
    for (int r = 0; r < 4; ++r) {
      int row = i0 + wr * 32 + t * 16 + q4 + r;
      f32x4 sv = *(const f32x4*)&sums[((((b << 10) + row) << 4) + h) * 4];
      float inv = 1.f / (sv[0] + sv[1] + sv[2] + sv[3]);
#pragma unroll
      for (int u = 0; u < 2; ++u) {
        int d = wc * 32 + u * 16 + l15;
        aout[(size_t)(b * Ssz + row) * Dsz + h * DHsz + d] = (bf16)(acc[t][u][r] * inv);
      }
    }
#undef K4_LOAD
}

// ---------------------------------------------------------------------------
// K5: out = aout_bf @ (ow_h+ow_l)^T  2-term, fp32 out, tile 64x64 -> 512 blocks
// ---------------------------------------------------------------------------
__global__ __launch_bounds__(256, 3) void k5_out(const bf16* __restrict__ A,
                                                 const bf16* __restrict__ Bh,
                                                 const bf16* __restrict__ Bl,
                                                 float* __restrict__ C) {
  __shared__ __align__(16) bf16 sA[64 * LDT], sBh[64 * LDT], sBl[64 * LDT];
  const int tid = threadIdx.x;
  const int lane = tid & 63, wv = tid >> 6;
  const int wr = wv >> 1, wc = wv & 1;
  const int l15 = lane & 15, q8 = (lane >> 4) << 3, q4 = (lane >> 4) << 2;
  const int m0 = blockIdx.y * 64, n0 = blockIdx.x * 64;
  const int r0 = tid >> 3, c8 = (tid & 7) << 3;
  f32x4 acc[2][2];
#pragma unroll
  for (int t = 0; t < 2; ++t)
#pragma unroll
    for (int u = 0; u < 2; ++u)
#pragma unroll
      for (int r = 0; r < 4; ++r) acc[t][u][r] = 0.f;
  bf16x8 rA[2], rBh[2], rBl[2];
#define K5_LOAD(kt)                                                       \
  {                                                                       \
    _Pragma("unroll") for (int c = 0; c < 2; ++c) {                       \
      int row = c * 32 + r0;                                              \
      rA[c] = *(const bf16x8*)(A + (size_t)(m0 + row) * Dsz + (kt) + c8);   \
      rBh[c] = *(const bf16x8*)(Bh + (size_t)(n0 + row) * Dsz + (kt) + c8); \
      rBl[c] = *(const bf16x8*)(Bl + (size_t)(n0 + row) * Dsz + (kt) + c8); \
    }                                                                     \
  }
  K5_LOAD(0)
  for (int kt = 0; kt < Dsz; kt += 64) {
    __syncthreads();
#pragma unroll
    for (int c = 0; c < 2; ++c) {
      int row = c * 32 + r0;
      *(bf16x8*)&sA[row * LDT + c8] = rA[c];
      *(bf16x8*)&sBh[row * LDT + c8] = rBh[c];
      *(bf16x8*)&sBl[row * LDT + c8] = rBl[c];
    }
    __syncthreads();
    if (kt + 64 < Dsz) K5_LOAD(kt + 64)
#pragma unroll
    for (int ks = 0; ks < 64; ks += 32) {
      bf16x8 fa[2], fbh[2], fbl[2];
#pragma unroll
      for (int t = 0; t < 2; ++t) fa[t] = *(const bf16x8*)&sA[(wr * 32 + t * 16 + l15) * LDT + ks + q8];
#pragma unroll
      for (int u = 0; u < 2; ++u) {
        int n = wc * 32 + u * 16 + l15;
        fbh[u] = *(const bf16x8*)&sBh[n * LDT + ks + q8];
        fbl[u] = *(const bf16x8*)&sBl[n * LDT + ks + q8];
      }
#pragma unroll
      for (int t = 0; t < 2; ++t)
#pragma unroll
        for (int u = 0; u < 2; ++u) {
          acc[t][u] = MFMA(fa[t], fbh[u], acc[t][u]);
          acc[t][u] = MFMA(fa[t], fbl[u], acc[t][u]);
        }
    }
  }
#pragma unroll
  for (int t = 0; t < 2; ++t)
#pragma unroll
    for (int u = 0; u < 2; ++u) {
      int col = n0 + wc * 32 + u * 16 + l15;
#pragma unroll
      for (int r = 0; r < 4; ++r) {
        int row = m0 + wr * 32 + t * 16 + q4 + r;
        C[(size_t)row * Dsz + col] = acc[t][u][r];
      }
    }
#undef K5_LOAD
}

// ---------------------------------------------------------------------------
extern "C" void kernel_launch(void* const* d_in, const int* in_sizes, int n_in,
                              void* d_out, int out_size, void* d_ws, size_t ws_size,
                              hipStream_t stream) {
  const float* x      = (const float*)d_in[0];
  const float* qkv_w  = (const float*)d_in[1];
  const float* out_w  = (const float*)d_in[2];
  const float* bias_p = (const float*)d_in[3];
  const float* bias_a = (const float*)d_in[4];
  const float* w1     = (const float*)d_in[5];
  const float* b1     = (const float*)d_in[6];
  const float* w2     = (const float*)d_in[7];
  const float* b2     = (const float*)d_in[8];
  float* out = (float*)d_out;

  // ws layout (bytes). scores (64 MB, both batches) ALIASES x_h/w_h/w_l,
  // which are dead after k1 — stream order makes this safe.
  char* ws = (char*)d_ws;
  const size_t MB = 1ull << 20;
  bf16* ow_h   = (bf16*)(ws + 0 * MB);            // 2 MB
  bf16* ow_l   = (bf16*)(ws + 2 * MB);            // 2 MB
  bf16* qkv_bf = (bf16*)(ws + 4 * MB);            // 12 MB
  bf16* v_t    = (bf16*)(ws + 16 * MB);           // 4 MB
  bf16* aout   = (bf16*)(ws + 20 * MB);           // 4 MB
  float* kbtt  = (float*)(ws + 24 * MB);          // 64 KB
  float* t1t   = (float*)(ws + 24 * MB + 65536);  // 64 KB
  float* sums  = (float*)(ws + 24 * MB + 131072); // 512 KB [b][i][h][chunk]
  bf16* wf     = (bf16*)(ws + 24 * MB + 655360);  // 2 KB
  bf16* x_h    = (bf16*)(ws + 25 * MB);           // 4 MB   (dead after k1)
  bf16* w_h    = (bf16*)(ws + 29 * MB);           // 6 MB   (dead after k1)
  bf16* w_l    = (bf16*)(ws + 35 * MB);           // 6 MB   (dead after k1)
  bf16* sc_bf  = (bf16*)(ws + 25 * MB);           // 64 MB, ends at 89 MB

  cast_hi<<<2048, 256, 0, stream>>>(x, x_h, Bsz * Ssz * Dsz);
  cast_hilo<<<3072, 256, 0, stream>>>(qkv_w, w_h, w_l, QKV3 * Dsz);
  cast_hilo<<<1024, 256, 0, stream>>>(out_w, ow_h, ow_l, Dsz * Dsz);
  kb_table<<<64, 256, 0, stream>>>(bias_p, bias_a, kbtt);
  t1_table<<<64, 256, 0, stream>>>(kbtt, w1, b1, t1t);
  wfrag<<<1, 64, 0, stream>>>(w1, w2, wf);

  k1_qkv<<<dim3(QKV3 / 96, (Bsz * Ssz) / 128), 256, 0, stream>>>(x_h, w_h, w_l, qkv_bf);
  pack_vt<<<dim3(Ssz / 64, Bsz * Hn), 256, 0, stream>>>(qkv_bf, v_t);

  // both batches per launch
  k2_qk<<<dim3(Ssz / 128, Ssz / 128, Bsz * Hn), 256, 0, stream>>>(qkv_bf, sc_bf);
  dape_softmax<<<dim3(4, Ssz, Bsz), 256, 0, stream>>>(sc_bf, t1t, kbtt, wf, b2, sums);
  k4_av<<<dim3(Ssz / 64, Hn, Bsz), 256, 0, stream>>>(sc_bf, v_t, sums, aout);

  k5_out<<<dim3(Dsz / 64, (Bsz * Ssz) / 64), 256, 0, stream>>>(aout, ow_h, ow_l, out);
}